// Round 6
// baseline (1079.338 us; speedup 1.0000x reference)
//
#include <hip/hip_runtime.h>
#include <hip/hip_bf16.h>

using bf16 = __hip_bfloat16;

#define N_HOSTN 20000
#define N_FLOWN 200000
#define E_HFN   400000
#define E_RELN  800000
#define E_CMBN  1200000  // rel + h2f combined
#define GG      64
#define HH      128
#define FIN     97
#define NCN     10

// CSR region block counts (256 threads/block)
#define NB_REL_E 3125   // 800000/256
#define NB_HF_E  1563   // ceil(400000/256)
#define NB_CMB_N 782    // ceil(200000/256)
#define NB_F2H_N 79     // ceil(20000/256)
// class-partitioned placement: 2048-edge chunks x 8 classes
#define NCH_REL 391     // ceil(800000/2048)
#define NCH_HF  196     // ceil(400000/2048)
#define PLC_REL (NCH_REL*8)            // 3128
#define PLC_H2F (PLC_REL + NCH_HF*8)   // 4696
#define PLC_ALL (PLC_H2F + NCH_HF*8)   // 6264

// persistent-wave aggregation geometry (quarter-per-dst)
#define AGG_CAP    768   // staged indices per wave (fallback to global beyond)
#define AGGF_DPW   24    // dsts per wave (multiple of 4)
#define AGGF_BLK   2084  // 2084 blk * 4 waves * 24 = 200064 >= 200000
#define AGGH_DPW   12
#define AGGH_BLK   417   // 417 * 4 * 12 = 20016 >= 20000

static inline int cdiv(long long a, long long b){ return (int)((a + b - 1) / b); }

__device__ __forceinline__ float bf2f(unsigned short u){
    return __uint_as_float(((unsigned)u) << 16);
}
__device__ __forceinline__ unsigned short f2bf(float f){
    unsigned u = __float_as_uint(f);
    unsigned r = u + 0x7FFFu + ((u >> 16) & 1u);   // RNE
    return (unsigned short)(r >> 16);
}
__device__ __forceinline__ float loadf(const void* p, size_t i, int isbf){
    return isbf ? bf2f(((const unsigned short*)p)[i]) : ((const float*)p)[i];
}
// unpack 8 bf16 (uint4) and accumulate into 8 f32
__device__ __forceinline__ void acc8(float* a, uint4 z){
    a[0] += __uint_as_float(z.x << 16);
    a[1] += __uint_as_float(z.x & 0xFFFF0000u);
    a[2] += __uint_as_float(z.y << 16);
    a[3] += __uint_as_float(z.y & 0xFFFF0000u);
    a[4] += __uint_as_float(z.z << 16);
    a[5] += __uint_as_float(z.z & 0xFFFF0000u);
    a[6] += __uint_as_float(z.w << 16);
    a[7] += __uint_as_float(z.w & 0xFFFF0000u);
}

// ---------------- dtype detection ----------------
__global__ void k_detect(const unsigned short* x, int* flag){
    __shared__ int bad;
    if (threadIdx.x == 0) bad = 0;
    __syncthreads();
    int b = 0;
    for (int i = threadIdx.x; i < 4096; i += 256) {
        unsigned e = (x[i] >> 7) & 0xFFu;
        if (e >= 0x90u) b++;
    }
    if (b) atomicAdd(&bad, b);
    __syncthreads();
    if (threadIdx.x == 0) *flag = (bad == 0) ? 1 : 0;   // 1 = bf16, 0 = f32
}

// ---------------- misc ----------------
__global__ void k_zero(float* p, size_t n){
    size_t i = (size_t)blockIdx.x * 256 + threadIdx.x;
    if (i < n) p[i] = 0.f;
}
__global__ void k_flag_us(unsigned short* out, int n, unsigned short val){
    int i = blockIdx.x * 256 + threadIdx.x;
    if (i < n) out[i] = val;
}
__global__ void k_gather_embed(const int* ids, const void* emb, float* out, const int* flagp){
    int i = blockIdx.x * 256 + threadIdx.x;
    if (i >= N_HOSTN * HH) return;
    int isbf = *flagp;
    int node = i >> 7, f = i & 127;
    out[i] = loadf(emb, (size_t)ids[node] * HH + f, isbf);
}
// flow_x [N,97] (flag dtype) -> bf16 padded [N,128]; 8 output cols per thread
__global__ void k_pad_cast(const void* x, unsigned short* o, const int* flagp){
    int i = blockIdx.x * 256 + threadIdx.x;           // 0 .. N_FLOWN*16
    if (i >= N_FLOWN * 16) return;
    int isbf = *flagp;
    int row = i >> 4, c0 = (i & 15) * 8;
    unsigned short v[8];
    #pragma unroll
    for (int j = 0; j < 8; ++j) {
        int c = c0 + j;
        v[j] = (c < FIN) ? f2bf(loadf(x, (size_t)row * FIN + c, isbf)) : (unsigned short)0;
    }
    uint4 ov;
    ov.x = (unsigned)v[0] | ((unsigned)v[1] << 16);
    ov.y = (unsigned)v[2] | ((unsigned)v[3] << 16);
    ov.z = (unsigned)v[4] | ((unsigned)v[5] << 16);
    ov.w = (unsigned)v[6] | ((unsigned)v[7] << 16);
    *(uint4*)(o + (size_t)row * 128 + c0) = ov;
}

// ---------------- one-shot weight prep (833 blocks, region dispatch) ----------------
__global__ __launch_bounds__(256) void k_wprep_all(
    const void* Wr0_h2f, const void* br0_h2f, const void* Wo0_h2f,
    const void* Wr0_f2h, const void* br0_f2h, const void* Wo0_f2h,
    const void* Wr0_rel, const void* br0_rel, const void* Wo0_rel,
    const void* Wr_all, const void* br_all, const void* Wo_all,
    unsigned short* WBT0, unsigned short* WBT1, unsigned short* WBT2,
    float* w_h2f0, float* w_h2f1, float* w_h2f2,
    float* w_f2h0, float* w_f2h1, float* w_of2h0, float* w_of2h1,
    float* b_comb0, float* b_comb1, float* b_comb2, float* b_f2h0, float* b_f2h1,
    const int* flagp)
{
    const int bb = blockIdx.x, t = threadIdx.x;
    const int isbf = *flagp;
    if (bb < 384) {
        int layer = bb >> 7;
        int i = ((bb & 127) << 8) + t;   // 0..32767
        int nn = i >> 7, k = i & 127;
        float v = 0.f;
        if (layer == 0) {
            if (k < FIN) {
                if (nn < 128) v = loadf(Wo0_h2f, (size_t)k*128+nn, isbf) + loadf(Wo0_rel, (size_t)k*128+nn, isbf);
                else          v = loadf(Wr0_rel, (size_t)k*128+(nn-128), isbf);
            }
        } else {
            size_t oW = (size_t)((layer - 1) * 3) * 16384;
            if (nn < 128) v = loadf(Wo_all, oW + (size_t)k*128+nn, isbf)
                            + loadf(Wo_all, oW + 2*16384 + (size_t)k*128+nn, isbf);
            else          v = loadf(Wr_all, oW + 2*16384 + (size_t)k*128+(nn-128), isbf);
        }
        unsigned short* W = (layer == 0) ? WBT0 : ((layer == 1) ? WBT1 : WBT2);
        W[(size_t)nn*128 + k] = f2bf(v);
    } else if (bb < 576) {
        int r = bb - 384; int layer = r >> 6; int i = ((r & 63) << 8) + t;
        float v;
        if (layer == 0) v = loadf(Wr0_h2f, (size_t)i, isbf);
        else            v = loadf(Wr_all, (size_t)((layer-1)*3)*16384 + i, isbf);
        ((layer == 0) ? w_h2f0 : ((layer == 1) ? w_h2f1 : w_h2f2))[i] = v;
    } else if (bb < 640) {
        // w_f2h0 padded to [128][128]: rows k>=97 zero
        int i = ((bb - 576) << 8) + t;
        int k = i >> 7;
        w_f2h0[i] = (k < FIN) ? loadf(Wr0_f2h, (size_t)i, isbf) : 0.f;
    } else if (bb < 704) {
        int i = ((bb - 640) << 8) + t;
        w_f2h1[i] = loadf(Wr_all, (size_t)1*16384 + i, isbf);
    } else if (bb < 768) {
        int i = ((bb - 704) << 8) + t;
        w_of2h0[i] = loadf(Wo0_f2h, (size_t)i, isbf);
    } else if (bb < 832) {
        int i = ((bb - 768) << 8) + t;
        w_of2h1[i] = loadf(Wo_all, (size_t)1*16384 + i, isbf);
    } else {
        if (t < 128) {
            b_comb0[t] = loadf(br0_h2f, t, isbf) + loadf(br0_rel, t, isbf);
            b_comb1[t] = loadf(br_all, 0*128 + t, isbf) + loadf(br_all, 2*128 + t, isbf);
            b_comb2[t] = loadf(br_all, 3*128 + t, isbf) + loadf(br_all, 5*128 + t, isbf);
            b_f2h0[t]  = loadf(br0_f2h, t, isbf);
            b_f2h1[t]  = loadf(br_all, 1*128 + t, isbf);
        }
    }
}

// ---------------- CSR build (combined flow CSR + f2h CSR) ----------------
__global__ void k_zero2(int* c0, int* c1){
    int bb = blockIdx.x, t = threadIdx.x;
    if (bb < NB_CMB_N) { int i = bb * 256 + t; if (i < N_FLOWN) c0[i] = 0; }
    else               { int i = (bb - NB_CMB_N) * 256 + t; if (i < N_HOSTN) c1[i] = 0; }
}
// rel and h2f edges both count into c_cmb; f2h into c_f2h
__global__ void k_hist3(const int* drel, const int* dh2f, const int* df2h,
                        int* c_cmb, int* c_f2h){
    int bb = blockIdx.x, t = threadIdx.x;
    const int* dst; int* cnt; int E; int base;
    if (bb < NB_REL_E)                   { dst = drel; cnt = c_cmb; E = E_RELN; base = bb; }
    else if (bb < NB_REL_E + NB_HF_E)    { dst = dh2f; cnt = c_cmb; E = E_HFN;  base = bb - NB_REL_E; }
    else                                 { dst = df2h; cnt = c_f2h; E = E_HFN;  base = bb - NB_REL_E - NB_HF_E; }
    int e = base * 256 + t;
    if (e < E) atomicAdd(&cnt[dst[e]], 1);
}
__global__ __launch_bounds__(256) void k_scan1_2(
    const int* c0, int* rp0, int* bs0,
    const int* c1, int* rp1, int* bs1)
{
    __shared__ int s[256];
    int bb = blockIdx.x, t = threadIdx.x;
    const int* cnt; int* rp; int* bsum; int n; int base;
    if (bb < NB_CMB_N) { cnt = c0; rp = rp0; bsum = bs0; n = N_FLOWN; base = bb; }
    else               { cnt = c1; rp = rp1; bsum = bs1; n = N_HOSTN; base = bb - NB_CMB_N; }
    int i = base * 256 + t;
    int v = (i < n) ? cnt[i] : 0;
    s[t] = v; __syncthreads();
    for (int off = 1; off < 256; off <<= 1) {
        int x = (t >= off) ? s[t - off] : 0;
        __syncthreads();
        s[t] += x;
        __syncthreads();
    }
    if (i < n) rp[i] = s[t] - v;
    if (t == 255) bsum[base] = s[255];
}
__global__ __launch_bounds__(256) void k_scan2_2(int* bs0, int* bs1){
    __shared__ int s[256];
    __shared__ int carry;
    int t = threadIdx.x;
    int* bsum; int nb;
    if (blockIdx.x == 0) { bsum = bs0; nb = NB_CMB_N; }
    else                 { bsum = bs1; nb = NB_F2H_N; }
    if (t == 0) carry = 0;
    __syncthreads();
    for (int base = 0; base < nb; base += 256) {
        int i = base + t;
        int v = (i < nb) ? bsum[i] : 0;
        s[t] = v; __syncthreads();
        for (int off = 1; off < 256; off <<= 1) {
            int x = (t >= off) ? s[t - off] : 0;
            __syncthreads();
            s[t] += x;
            __syncthreads();
        }
        int excl = s[t] - v + carry;
        if (i < nb) bsum[i] = excl;
        __syncthreads();
        if (t == 255) carry += s[255];
        __syncthreads();
    }
}
__global__ void k_scan3_2(int* rp0, const int* bs0, int* w0,
                          int* rp1, const int* bs1, int* w1)
{
    int bb = blockIdx.x, t = threadIdx.x;
    int* rp; const int* bsum; int* wr; int n, E, base;
    if (bb < NB_CMB_N) { rp = rp0; bsum = bs0; wr = w0; n = N_FLOWN; E = E_CMBN; base = bb; }
    else               { rp = rp1; bsum = bs1; wr = w1; n = N_HOSTN; E = E_HFN;  base = bb - NB_CMB_N; }
    int i = base * 256 + t;
    if (i < n) { int v = rp[i] + bsum[base]; rp[i] = v; wr[i] = v; }
    if (i == 0) rp[n] = E;
}
// class-partitioned placement: class = blockIdx%8 (round-robins onto XCDs);
// rel + h2f both place into the combined flow CSR; h2f srcs get +N_FLOWN so
// the gather reads the host rows appended after the flow rows in ZALL.
__global__ __launch_bounds__(256) void k_place3c(
    const int* s0, const int* d0,
    const int* s1, const int* d1,
    const int* s2, const int* d2,
    int* w_cmb, int* e_cmb, int* w_f2h, int* e_f2h)
{
    const int bb = blockIdx.x;
    const int *src, *dst; int *wr, *ei; int E, divc, rb, soff;
    if (bb < PLC_REL)      { src=s0; dst=d0; wr=w_cmb; ei=e_cmb; E=E_RELN; divc=25000; rb=bb;          soff=0; }
    else if (bb < PLC_H2F) { src=s1; dst=d1; wr=w_cmb; ei=e_cmb; E=E_HFN;  divc=25000; rb=bb-PLC_REL;  soff=N_FLOWN; }
    else                   { src=s2; dst=d2; wr=w_f2h; ei=e_f2h; E=E_HFN;  divc=2500;  rb=bb-PLC_H2F;  soff=0; }
    const int cls  = rb & 7;
    const int base = (rb >> 3) * 2048;
    const int t = threadIdx.x;
    #pragma unroll
    for (int i = 0; i < 8; ++i) {
        const int e = base + t + i * 256;
        if (e < E) {
            const int d = dst[e];
            if (d / divc == cls) {
                const int pos = atomicAdd(&wr[d], 1);
                ei[pos] = src[e] + soff;
            }
        }
    }
}

// ---------------- host-sized VALU GEMM: Y[M,128] (+)= X[M,K]@W[K,128]+b ---------
__global__ __launch_bounds__(256) void k_gemm128(
    const void* X, int xmode, const float* W, const float* bias,
    void* Y, int ybf, int M, int K, int accum, int dorelu, const int* flagp)
{
    const int isbf = (xmode == 2) ? *flagp : xmode;
    const int tid  = threadIdx.x;
    const int row0 = blockIdx.x * 16;
    __shared__ float sX[16][130];
    const int total = 16 * K;
    for (int i = tid; i < total; i += 256) {
        int r = i / K, c = i - r * K;
        int gr = row0 + r;
        sX[r][c] = (gr < M) ? loadf(X, (size_t)gr * K + c, isbf) : 0.f;
    }
    __syncthreads();

    const int c4 = (tid & 31) * 4;
    const int rb = tid >> 5;
    float a0x=0,a0y=0,a0z=0,a0w=0, a1x=0,a1y=0,a1z=0,a1w=0;
    #pragma unroll 4
    for (int k = 0; k < K; ++k) {
        const float4 w = *(const float4*)(W + (size_t)k * 128 + c4);
        const float x0 = sX[rb][k];
        const float x1 = sX[rb + 8][k];
        a0x = fmaf(x0, w.x, a0x); a0y = fmaf(x0, w.y, a0y);
        a0z = fmaf(x0, w.z, a0z); a0w = fmaf(x0, w.w, a0w);
        a1x = fmaf(x1, w.x, a1x); a1y = fmaf(x1, w.y, a1y);
        a1z = fmaf(x1, w.z, a1z); a1w = fmaf(x1, w.w, a1w);
    }
    float bx=0, by=0, bz=0, bw=0;
    if (bias) { const float4 b = *(const float4*)(bias + c4); bx=b.x; by=b.y; bz=b.z; bw=b.w; }

    #pragma unroll
    for (int h = 0; h < 2; ++h) {
        const int rr = row0 + rb + (h ? 8 : 0);
        if (rr >= M) continue;
        float v0 = (h?a1x:a0x)+bx, v1 = (h?a1y:a0y)+by;
        float v2 = (h?a1z:a0z)+bz, v3 = (h?a1w:a0w)+bw;
        if (ybf) {
            unsigned short* p = (unsigned short*)Y + (size_t)rr * 128 + c4;
            ushort4 o; o.x=f2bf(v0); o.y=f2bf(v1); o.z=f2bf(v2); o.w=f2bf(v3);
            *(ushort4*)p = o;
        } else {
            float* p = (float*)Y + (size_t)rr * 128 + c4;
            if (accum) { v0+=p[0]; v1+=p[1]; v2+=p[2]; v3+=p[3]; }
            if (dorelu) { v0=fmaxf(v0,0.f); v1=fmaxf(v1,0.f); v2=fmaxf(v2,0.f); v3=fmaxf(v3,0.f); }
            float4 o; o.x=v0; o.y=v1; o.z=v2; o.w=v3;
            *(float4*)p = o;
        }
    }
}

// ---------------- fused dual-input host GEMM: Y = relu(X1@W1 + X2@W2 + b) ------
__global__ __launch_bounds__(256) void k_gemm2in(
    const float* __restrict__ X1, const float* __restrict__ X2,
    const float* __restrict__ W1, const float* __restrict__ W2,
    const float* __restrict__ bias, float* __restrict__ Y, int M)
{
    const int tid  = threadIdx.x;
    const int row0 = blockIdx.x * 16;
    __shared__ float sX1[16][130];
    __shared__ float sX2[16][130];
    for (int i = tid; i < 16 * 128; i += 256) {
        int r = i >> 7, c = i & 127;
        int gr = row0 + r;
        sX1[r][c] = (gr < M) ? X1[(size_t)gr * 128 + c] : 0.f;
        sX2[r][c] = (gr < M) ? X2[(size_t)gr * 128 + c] : 0.f;
    }
    __syncthreads();

    const int c4 = (tid & 31) * 4;
    const int rb = tid >> 5;
    float a0x=0,a0y=0,a0z=0,a0w=0, a1x=0,a1y=0,a1z=0,a1w=0;
    #pragma unroll 4
    for (int k = 0; k < 128; ++k) {
        const float4 w = *(const float4*)(W1 + (size_t)k * 128 + c4);
        const float x0 = sX1[rb][k];
        const float x1 = sX1[rb + 8][k];
        a0x = fmaf(x0, w.x, a0x); a0y = fmaf(x0, w.y, a0y);
        a0z = fmaf(x0, w.z, a0z); a0w = fmaf(x0, w.w, a0w);
        a1x = fmaf(x1, w.x, a1x); a1y = fmaf(x1, w.y, a1y);
        a1z = fmaf(x1, w.z, a1z); a1w = fmaf(x1, w.w, a1w);
    }
    #pragma unroll 4
    for (int k = 0; k < 128; ++k) {
        const float4 w = *(const float4*)(W2 + (size_t)k * 128 + c4);
        const float x0 = sX2[rb][k];
        const float x1 = sX2[rb + 8][k];
        a0x = fmaf(x0, w.x, a0x); a0y = fmaf(x0, w.y, a0y);
        a0z = fmaf(x0, w.z, a0z); a0w = fmaf(x0, w.w, a0w);
        a1x = fmaf(x1, w.x, a1x); a1y = fmaf(x1, w.y, a1y);
        a1z = fmaf(x1, w.z, a1z); a1w = fmaf(x1, w.w, a1w);
    }
    const float4 b = *(const float4*)(bias + c4);
    #pragma unroll
    for (int h = 0; h < 2; ++h) {
        const int rr = row0 + rb + (h ? 8 : 0);
        if (rr >= M) continue;
        float4 o;
        o.x = fmaxf((h?a1x:a0x) + b.x, 0.f);
        o.y = fmaxf((h?a1y:a0y) + b.y, 0.f);
        o.z = fmaxf((h?a1z:a0z) + b.z, 0.f);
        o.w = fmaxf((h?a1w:a0w) + b.w, 0.f);
        *(float4*)(Y + (size_t)rr * 128 + c4) = o;
    }
}

// ---------------- MFMA dual flow GEMM: both outputs bf16, no bias ----------------
// v6: occupancy fix. Round-5 counters showed Occupancy=24% (2 waves/SIMD): the
// 4-wave/64-col layout held B(64) + A(32) + acc(32) ~ 170 unified regs -> the
// >128 occupancy cliff. Now 8 waves x 32 WBT-rows each: B = 8 bfrags (32 regs),
// acc = 16 regs, A = 32 regs -> ~100 unified regs, __launch_bounds__(512,4)
// enforces the <=128 cap -> 4 waves/SIMD. A-frag loads duplicate across the two
// col-waves but are L1-served. Operands swapped (mfma(b,a) == D^T) -> ushort4
// stores; no LDS, no barriers.
typedef __attribute__((ext_vector_type(8))) short bfrag;
typedef __attribute__((ext_vector_type(4))) float f32x4;

#define GEMM_CHUNKS 4
#define GEMM_MROWS  (32 * GEMM_CHUNKS)   // 128 rows per block

__global__ __launch_bounds__(512, 4) void k_gemm_mfma(
    const unsigned short* __restrict__ Abf, const unsigned short* __restrict__ WBT,
    unsigned short* __restrict__ Y1, unsigned short* __restrict__ Y2, int M)
{
    const int tid  = threadIdx.x;
    const int wave = tid >> 6;        // 0..7
    const int lane = tid & 63;
    const int quad = lane >> 4;
    const int l16  = lane & 15;
    const int nbase = wave * 32;      // 32 WBT rows per wave

    // B slice for this wave's 32 output cols: breg[c][j] (8 bfrags = 32 regs)
    bfrag breg[4][2];
    #pragma unroll
    for (int c = 0; c < 4; ++c)
        #pragma unroll
        for (int j = 0; j < 2; ++j)
            breg[c][j] = *(const bfrag*)(WBT + (size_t)(nbase + j * 16 + l16) * 128
                                              + c * 32 + quad * 8);

    unsigned short* __restrict__ Yd = (nbase < 128) ? Y1 : Y2;
    const int colb = nbase & 127;
    const f32x4 zero = {0.f, 0.f, 0.f, 0.f};

    #pragma unroll
    for (int chunk = 0; chunk < GEMM_CHUNKS; ++chunk) {
        const int m0 = blockIdx.x * GEMM_MROWS + chunk * 32;
        if (m0 < M) {
            // A fragments direct from global (16 rows x 64B per load instruction)
            bfrag a0[4], a1[4];
            #pragma unroll
            for (int c = 0; c < 4; ++c) {
                a0[c] = *(const bfrag*)(Abf + (size_t)(m0      + l16) * 128 + c * 32 + quad * 8);
                a1[c] = *(const bfrag*)(Abf + (size_t)(m0 + 16 + l16) * 128 + c * 32 + quad * 8);
            }
            f32x4 acc[2][2];
            #pragma unroll
            for (int j = 0; j < 2; ++j) {
                acc[0][j] = __builtin_amdgcn_mfma_f32_16x16x32_bf16(breg[0][j], a0[0], zero, 0, 0, 0);
                acc[1][j] = __builtin_amdgcn_mfma_f32_16x16x32_bf16(breg[0][j], a1[0], zero, 0, 0, 0);
            }
            #pragma unroll
            for (int c = 1; c < 4; ++c)
                #pragma unroll
                for (int j = 0; j < 2; ++j) {
                    acc[0][j] = __builtin_amdgcn_mfma_f32_16x16x32_bf16(breg[c][j], a0[c], acc[0][j], 0, 0, 0);
                    acc[1][j] = __builtin_amdgcn_mfma_f32_16x16x32_bf16(breg[c][j], a1[c], acc[1][j], 0, 0, 0);
                }
            // D' layout: col(lane&15) = X-row m (within 16-block i), row(quad*4+r) = WBT-row n
            #pragma unroll
            for (int i = 0; i < 2; ++i) {
                const int row = m0 + i * 16 + l16;
                #pragma unroll
                for (int j = 0; j < 2; ++j) {
                    const int col = colb + j * 16 + quad * 4;
                    ushort4 o;
                    o.x = f2bf(acc[i][j][0]); o.y = f2bf(acc[i][j][1]);
                    o.z = f2bf(acc[i][j][2]); o.w = f2bf(acc[i][j][3]);
                    *(ushort4*)(Yd + (size_t)row * 128 + col) = o;
                }
            }
        }
    }
}

// ---------------- persistent-wave combined CSR aggregation (flow dsts) ----------
// QUARTER-PER-DST: each 16-lane quarter owns one dst entirely (16 lanes x 8
// features = 128). Per outer iteration the wave processes 4 CONSECUTIVE dsts in
// parallel: no cross-quarter reduce (shfl_xor eliminated), epilogue amortized 4x,
// root loads / stores are 4 consecutive rows = 1 KiB contiguous per instruction.
// Edge-index window staged to LDS once per wave (contiguous CSR range).
__global__ __launch_bounds__(256) void k_agg_flow(
    const unsigned short* __restrict__ Z,
    const int* __restrict__ rp, const int* __restrict__ ei,
    const unsigned short* __restrict__ root, const float* __restrict__ bias,
    unsigned short* __restrict__ Xout, int do_relu)
{
    __shared__ int sIdx[4][AGG_CAP];
    const int wave = threadIdx.x >> 6;
    const int lane = threadIdx.x & 63;
    const int q    = lane >> 4;
    const int l16  = lane & 15;
    const int f8   = l16 * 8;
    const int gw   = blockIdx.x * 4 + wave;
    const int d0   = gw * AGGF_DPW;
    const int nd   = min(AGGF_DPW, N_FLOWN - d0);   // may be <= 0 for tail waves

    int rpv = 0, W0 = 0, Wcap = 0;
    if (nd > 0) {
        rpv = (lane <= nd) ? rp[d0 + lane] : 0;
        W0 = __shfl(rpv, 0, 64);
        const int Wn = __shfl(rpv, nd, 64);
        const int cw = min(Wn - W0, AGG_CAP);
        for (int i = lane; i < cw; i += 64) sIdx[wave][i] = ei[W0 + i];
        Wcap = W0 + cw;
    }
    __syncthreads();
    if (nd <= 0) return;

    // loop-invariant bias slice
    const float4 bva = *(const float4*)(bias + f8);
    const float4 bvb = *(const float4*)(bias + f8 + 4);

    #pragma unroll 2
    for (int i = 0; i < AGGF_DPW / 4; ++i) {
        const int dqi = i * 4 + q;              // this quarter's dst offset
        const bool act = dqi < nd;
        const int srcl = act ? dqi : 0;
        const int b0 = __shfl(rpv, srcl, 64);
        const int b1 = __shfl(rpv, srcl + 1, 64);
        const int d  = d0 + dqi;

        uint4 rv = {0, 0, 0, 0};
        if (act) rv = *(const uint4*)(root + (size_t)d * 128 + f8);

        float a[8] = {0.f, 0.f, 0.f, 0.f, 0.f, 0.f, 0.f, 0.f};
        int n = act ? (b1 - b0) : 0;
        int e = b0;
        while (n >= 4) {
            const int s0 = (e     < Wcap) ? sIdx[wave][e     - W0] : ei[e];
            const int s1 = (e + 1 < Wcap) ? sIdx[wave][e + 1 - W0] : ei[e + 1];
            const int s2 = (e + 2 < Wcap) ? sIdx[wave][e + 2 - W0] : ei[e + 2];
            const int s3 = (e + 3 < Wcap) ? sIdx[wave][e + 3 - W0] : ei[e + 3];
            const uint4 z0 = *(const uint4*)(Z + (size_t)s0 * 128 + f8);
            const uint4 z1 = *(const uint4*)(Z + (size_t)s1 * 128 + f8);
            const uint4 z2 = *(const uint4*)(Z + (size_t)s2 * 128 + f8);
            const uint4 z3 = *(const uint4*)(Z + (size_t)s3 * 128 + f8);
            acc8(a, z0); acc8(a, z1); acc8(a, z2); acc8(a, z3);
            e += 4; n -= 4;
        }
        if (n & 2) {
            const int s0 = (e     < Wcap) ? sIdx[wave][e     - W0] : ei[e];
            const int s1 = (e + 1 < Wcap) ? sIdx[wave][e + 1 - W0] : ei[e + 1];
            const uint4 z0 = *(const uint4*)(Z + (size_t)s0 * 128 + f8);
            const uint4 z1 = *(const uint4*)(Z + (size_t)s1 * 128 + f8);
            acc8(a, z0); acc8(a, z1);
            e += 2;
        }
        if (n & 1) {
            const int s0 = (e < Wcap) ? sIdx[wave][e - W0] : ei[e];
            const uint4 z0 = *(const uint4*)(Z + (size_t)s0 * 128 + f8);
            acc8(a, z0);
        }

        if (act) {
            float v0 = a[0] + __uint_as_float(rv.x << 16)         + bva.x;
            float v1 = a[1] + __uint_as_float(rv.x & 0xFFFF0000u) + bva.y;
            float v2 = a[2] + __uint_as_float(rv.y << 16)         + bva.z;
            float v3 = a[3] + __uint_as_float(rv.y & 0xFFFF0000u) + bva.w;
            float v4 = a[4] + __uint_as_float(rv.z << 16)         + bvb.x;
            float v5 = a[5] + __uint_as_float(rv.z & 0xFFFF0000u) + bvb.y;
            float v6 = a[6] + __uint_as_float(rv.w << 16)         + bvb.z;
            float v7 = a[7] + __uint_as_float(rv.w & 0xFFFF0000u) + bvb.w;
            if (do_relu) {
                v0 = fmaxf(v0, 0.f); v1 = fmaxf(v1, 0.f); v2 = fmaxf(v2, 0.f); v3 = fmaxf(v3, 0.f);
                v4 = fmaxf(v4, 0.f); v5 = fmaxf(v5, 0.f); v6 = fmaxf(v6, 0.f); v7 = fmaxf(v7, 0.f);
            }
            uint4 o;
            o.x = (unsigned)f2bf(v0) | ((unsigned)f2bf(v1) << 16);
            o.y = (unsigned)f2bf(v2) | ((unsigned)f2bf(v3) << 16);
            o.z = (unsigned)f2bf(v4) | ((unsigned)f2bf(v5) << 16);
            o.w = (unsigned)f2bf(v6) | ((unsigned)f2bf(v7) << 16);
            *(uint4*)(Xout + (size_t)d * 128 + f8) = o;
        }
    }
}

// host dst: out[d][0:128] = sum f2h Z[src][0:128]  (f32 out)
// Same quarter-per-dst persistent structure.
__global__ __launch_bounds__(256) void k_agg_host(
    const unsigned short* __restrict__ Z, const int* __restrict__ rp,
    const int* __restrict__ ei, float* __restrict__ out)
{
    __shared__ int sIdx[4][AGG_CAP];
    const int wave = threadIdx.x >> 6;
    const int lane = threadIdx.x & 63;
    const int q    = lane >> 4;
    const int l16  = lane & 15;
    const int f8   = l16 * 8;
    const int gw   = blockIdx.x * 4 + wave;
    const int d0   = gw * AGGH_DPW;
    const int nd   = min(AGGH_DPW, N_HOSTN - d0);

    int rpv = 0, W0 = 0, Wcap = 0;
    if (nd > 0) {
        rpv = (lane <= nd) ? rp[d0 + lane] : 0;
        W0 = __shfl(rpv, 0, 64);
        const int Wn = __shfl(rpv, nd, 64);
        const int cw = min(Wn - W0, AGG_CAP);
        for (int i = lane; i < cw; i += 64) sIdx[wave][i] = ei[W0 + i];
        Wcap = W0 + cw;
    }
    __syncthreads();
    if (nd <= 0) return;

    #pragma unroll
    for (int i = 0; i < AGGH_DPW / 4; ++i) {
        const int dqi = i * 4 + q;
        const bool act = dqi < nd;
        const int srcl = act ? dqi : 0;
        const int b0 = __shfl(rpv, srcl, 64);
        const int b1 = __shfl(rpv, srcl + 1, 64);
        const int d  = d0 + dqi;

        float a[8] = {0.f, 0.f, 0.f, 0.f, 0.f, 0.f, 0.f, 0.f};
        int n = act ? (b1 - b0) : 0;
        int e = b0;
        while (n >= 4) {
            const int s0 = (e     < Wcap) ? sIdx[wave][e     - W0] : ei[e];
            const int s1 = (e + 1 < Wcap) ? sIdx[wave][e + 1 - W0] : ei[e + 1];
            const int s2 = (e + 2 < Wcap) ? sIdx[wave][e + 2 - W0] : ei[e + 2];
            const int s3 = (e + 3 < Wcap) ? sIdx[wave][e + 3 - W0] : ei[e + 3];
            const uint4 z0 = *(const uint4*)(Z + (size_t)s0 * 128 + f8);
            const uint4 z1 = *(const uint4*)(Z + (size_t)s1 * 128 + f8);
            const uint4 z2 = *(const uint4*)(Z + (size_t)s2 * 128 + f8);
            const uint4 z3 = *(const uint4*)(Z + (size_t)s3 * 128 + f8);
            acc8(a, z0); acc8(a, z1); acc8(a, z2); acc8(a, z3);
            e += 4; n -= 4;
        }
        if (n & 2) {
            const int s0 = (e     < Wcap) ? sIdx[wave][e     - W0] : ei[e];
            const int s1 = (e + 1 < Wcap) ? sIdx[wave][e + 1 - W0] : ei[e + 1];
            const uint4 z0 = *(const uint4*)(Z + (size_t)s0 * 128 + f8);
            const uint4 z1 = *(const uint4*)(Z + (size_t)s1 * 128 + f8);
            acc8(a, z0); acc8(a, z1);
            e += 2;
        }
        if (n & 1) {
            const int s0 = (e < Wcap) ? sIdx[wave][e - W0] : ei[e];
            const uint4 z0 = *(const uint4*)(Z + (size_t)s0 * 128 + f8);
            acc8(a, z0);
        }

        if (act) {
            float4 oa, ob;
            oa.x = a[0]; oa.y = a[1]; oa.z = a[2]; oa.w = a[3];
            ob.x = a[4]; ob.y = a[5]; ob.z = a[6]; ob.w = a[7];
            *(float4*)(out + (size_t)d * 128 + f8)     = oa;
            *(float4*)(out + (size_t)d * 128 + f8 + 4) = ob;
        }
    }
}

// ---------------- pooling over sorted batch (bf16 input) ----------------
#define PCHUNK 128
__global__ __launch_bounds__(128) void k_pool2(const unsigned short* xf, const int* batch,
                                               unsigned* bits){
    const int t = threadIdx.x;
    const int i0 = blockIdx.x * PCHUNK;
    const int iend = min(i0 + PCHUNK, N_FLOWN);
    if (i0 >= N_FLOWN) return;
    float cur = -3.4e38f;
    int curg = batch[i0];
    for (int i = i0; i < iend; ++i) {
        int g = batch[i];
        if (g != curg) {
            unsigned u = __float_as_uint(cur);
            unsigned ord = (u & 0x80000000u) ? ~u : (u | 0x80000000u);
            atomicMax(&bits[(size_t)curg * 128 + t], ord);
            cur = -3.4e38f; curg = g;
        }
        cur = fmaxf(cur, bf2f(xf[(size_t)i * 128 + t]));
    }
    unsigned u = __float_as_uint(cur);
    unsigned ord = (u & 0x80000000u) ? ~u : (u | 0x80000000u);
    atomicMax(&bits[(size_t)curg * 128 + t], ord);
}

// ---------------- classifier ----------------
__global__ __launch_bounds__(128) void k_classifier(
    const unsigned* bits,
    const void* Wc1, const void* bc1, const void* Wc2, const void* bc2,
    const void* Wc3, const void* bc3, void* out, const int* flagp)
{
    const int g = blockIdx.x, t = threadIdx.x;
    const int isbf = *flagp;
    __shared__ float sp[128], sh1[64], sh2[128];
    {
        unsigned ord = bits[(size_t)g * HH + t];
        unsigned u = (ord & 0x80000000u) ? (ord & 0x7FFFFFFFu) : ~ord;
        sp[t] = __uint_as_float(u);
    }
    __syncthreads();
    if (t < 64) {
        float a = loadf(bc1, t, isbf);
        #pragma unroll 4
        for (int k = 0; k < 128; ++k) a = fmaf(sp[k], loadf(Wc1, k * 64 + t, isbf), a);
        sh1[t] = fmaxf(a, 0.f);
    }
    __syncthreads();
    {
        float a = loadf(bc2, t, isbf);
        #pragma unroll 4
        for (int k = 0; k < 64; ++k) a = fmaf(sh1[k], loadf(Wc2, k * 128 + t, isbf), a);
        sh2[t] = fmaxf(a, 0.f);
    }
    __syncthreads();
    if (t < NCN) {
        float a = loadf(bc3, t, isbf);
        #pragma unroll 4
        for (int k = 0; k < 128; ++k) a = fmaf(sh2[k], loadf(Wc3, k * NCN + t, isbf), a);
        if (isbf) ((unsigned short*)out)[(size_t)g * NCN + t] = f2bf(a);
        else      ((float*)out)[(size_t)g * NCN + t] = a;
    }
}

extern "C" void kernel_launch(void* const* d_in, const int* in_sizes, int n_in,
                              void* d_out, int out_size, void* d_ws, size_t ws_size,
                              hipStream_t stream)
{
    const int*  host_ids   = (const int*) d_in[0];
    const void* flow_x     = d_in[1];
    const int*  h2f_src    = (const int*) d_in[2];
    const int*  h2f_dst    = (const int*) d_in[3];
    const int*  f2h_src    = (const int*) d_in[4];
    const int*  f2h_dst    = (const int*) d_in[5];
    const int*  rel_src    = (const int*) d_in[6];
    const int*  rel_dst    = (const int*) d_in[7];
    const int*  flow_batch = (const int*) d_in[8];
    const void* host_embed = d_in[9];
    const void* Wr0_h2f = d_in[10]; const void* br0_h2f = d_in[11]; const void* Wo0_h2f = d_in[12];
    const void* Wr0_f2h = d_in[13]; const void* br0_f2h = d_in[14]; const void* Wo0_f2h = d_in[15];
    const void* Wr0_rel = d_in[16]; const void* br0_rel = d_in[17]; const void* Wo0_rel = d_in[18];
    const void* Wr_all  = d_in[19];
    const void* br_all  = d_in[20];
    const void* Wo_all  = d_in[21];
    const void* Wc1 = d_in[22]; const void* bc1 = d_in[23];
    const void* Wc2 = d_in[24]; const void* bc2 = d_in[25];
    const void* Wc3 = d_in[26]; const void* bc3 = d_in[27];

    // -------- workspace (~199 MB) --------
    size_t off = 0;
    auto alloc = [&](size_t bytes) -> char* {
        char* p = (char*)d_ws + off;
        off += (bytes + 255) & ~(size_t)255;
        return p;
    };
    unsigned short* F1bf  = (unsigned short*)alloc((size_t)N_FLOWN * HH * 2);  // state
    unsigned short* Froot = (unsigned short*)alloc((size_t)N_FLOWN * HH * 2);  // root term
    // ZALL: flow-transformed rows [0,200k) followed by host-transformed rows [200k,220k)
    unsigned short* ZALL  = (unsigned short*)alloc((size_t)(N_FLOWN + N_HOSTN) * HH * 2);
    unsigned short* F2bf  = ZALL;                                   // z_rel
    unsigned short* HCbf  = ZALL + (size_t)N_FLOWN * HH;            // z_h
    float* HA = (float*)alloc((size_t)N_HOSTN * HH * 4);
    float* HB = (float*)alloc((size_t)N_HOSTN * HH * 4);
    float* HD = (float*)alloc((size_t)N_HOSTN * HH * 4);
    unsigned short* WBT0 = (unsigned short*)alloc(256 * 128 * 2);
    unsigned short* WBT1 = (unsigned short*)alloc(256 * 128 * 2);
    unsigned short* WBT2 = (unsigned short*)alloc(256 * 128 * 2);
    float* w_h2f0  = (float*)alloc(128 * 128 * 4);
    float* w_h2f1  = (float*)alloc(128 * 128 * 4);
    float* w_h2f2  = (float*)alloc(128 * 128 * 4);
    float* w_f2h0  = (float*)alloc(128 * 128 * 4);
    float* w_f2h1  = (float*)alloc(128 * 128 * 4);
    float* w_of2h0 = (float*)alloc(128 * 128 * 4);
    float* w_of2h1 = (float*)alloc(128 * 128 * 4);
    float* b_comb0 = (float*)alloc(128 * 4);
    float* b_comb1 = (float*)alloc(128 * 4);
    float* b_comb2 = (float*)alloc(128 * 4);
    float* b_f2h0  = (float*)alloc(128 * 4);
    float* b_f2h1  = (float*)alloc(128 * 4);
    unsigned* poolbits = (unsigned*)alloc(GG * HH * 4);
    int* flagp = (int*)alloc(256);
    int* rp_cmb = (int*)alloc((N_FLOWN + 1) * 4);
    int* ei_cmb = (int*)alloc((size_t)E_CMBN * 4);
    int* rp_f2h = (int*)alloc((N_HOSTN + 1) * 4);
    int* ei_f2h = (int*)alloc((size_t)E_HFN * 4);
    int* wr_cmb = (int*)alloc((size_t)N_FLOWN * 4);
    int* wr_f2h = (int*)alloc((size_t)N_HOSTN * 4);
    int* bs0 = (int*)alloc(1024 * 4);
    int* bs2 = (int*)alloc(256 * 4);

    const int T = 256;
    #define GRID1(n) dim3(cdiv((long long)(n), T)), dim3(T), 0, stream

    if (off > ws_size) {
        k_flag_us<<<GRID1(out_size)>>>((unsigned short*)d_out, out_size, (unsigned short)0x4000);
        return;
    }

    k_detect<<<dim3(1), dim3(256), 0, stream>>>((const unsigned short*)flow_x, flagp);

    // -------- CSR builds (combined flow CSR + f2h CSR) --------
    k_zero2 <<<dim3(NB_CMB_N + NB_F2H_N), dim3(256), 0, stream>>>(wr_cmb, wr_f2h);
    k_hist3 <<<dim3(NB_REL_E + 2*NB_HF_E), dim3(256), 0, stream>>>(rel_dst, h2f_dst, f2h_dst,
                                                                    wr_cmb, wr_f2h);
    k_scan1_2<<<dim3(NB_CMB_N + NB_F2H_N), dim3(256), 0, stream>>>(
        wr_cmb, rp_cmb, bs0, wr_f2h, rp_f2h, bs2);
    k_scan2_2<<<dim3(2), dim3(256), 0, stream>>>(bs0, bs2);
    k_scan3_2<<<dim3(NB_CMB_N + NB_F2H_N), dim3(256), 0, stream>>>(
        rp_cmb, bs0, wr_cmb, rp_f2h, bs2, wr_f2h);
    k_place3c<<<dim3(PLC_ALL), dim3(256), 0, stream>>>(
        rel_src, rel_dst, h2f_src, h2f_dst, f2h_src, f2h_dst,
        wr_cmb, ei_cmb, wr_f2h, ei_f2h);

    // -------- weight prep (1 launch) --------
    k_wprep_all<<<dim3(833), dim3(256), 0, stream>>>(
        Wr0_h2f, br0_h2f, Wo0_h2f, Wr0_f2h, br0_f2h, Wo0_f2h, Wr0_rel, br0_rel, Wo0_rel,
        Wr_all, br_all, Wo_all,
        WBT0, WBT1, WBT2, w_h2f0, w_h2f1, w_h2f2,
        w_f2h0, w_f2h1, w_of2h0, w_of2h1,
        b_comb0, b_comb1, b_comb2, b_f2h0, b_f2h1, flagp);

    // ================= layer 0 =================
    k_gather_embed<<<GRID1(N_HOSTN * HH)>>>(host_ids, host_embed, HA, flagp);
    k_pad_cast<<<GRID1(N_FLOWN * 16)>>>(flow_x, F1bf, flagp);
    // host path: gather bf16 input features (K padded to 128); fused dual GEMM + relu
    k_agg_host<<<dim3(AGGH_BLK), dim3(256), 0, stream>>>(F1bf, rp_f2h, ei_f2h, HD);
    k_gemm2in<<<dim3(cdiv(N_HOSTN,16)), dim3(256), 0, stream>>>(HD, HA, w_f2h0, w_of2h0, b_f2h0, HB, N_HOSTN);
    // flow path
    k_gemm128<<<dim3(cdiv(N_HOSTN,16)), dim3(256), 0, stream>>>(HA, 0, w_h2f0, nullptr, HCbf, 1, N_HOSTN, 128, 0, 0, flagp);
    k_gemm_mfma<<<dim3(cdiv(N_FLOWN, GEMM_MROWS)), dim3(512), 0, stream>>>(F1bf, WBT0, Froot, F2bf, N_FLOWN);
    k_agg_flow<<<dim3(AGGF_BLK), dim3(256), 0, stream>>>(ZALL, rp_cmb, ei_cmb,
                                                         Froot, b_comb0, F1bf, 1);

    // ================= stacked layer 0 =================
    k_agg_host<<<dim3(AGGH_BLK), dim3(256), 0, stream>>>(F1bf, rp_f2h, ei_f2h, HD);
    k_gemm128<<<dim3(cdiv(N_HOSTN,16)), dim3(256), 0, stream>>>(HB, 0, w_h2f1, nullptr, HCbf, 1, N_HOSTN, 128, 0, 0, flagp);
    k_gemm_mfma<<<dim3(cdiv(N_FLOWN, GEMM_MROWS)), dim3(512), 0, stream>>>(F1bf, WBT1, Froot, F2bf, N_FLOWN);
    k_agg_flow<<<dim3(AGGF_BLK), dim3(256), 0, stream>>>(ZALL, rp_cmb, ei_cmb,
                                                         Froot, b_comb1, F1bf, 1);
    k_gemm2in<<<dim3(cdiv(N_HOSTN,16)), dim3(256), 0, stream>>>(HD, HB, w_f2h1, w_of2h1, b_f2h1, HA, N_HOSTN);

    // ================= stacked layer 1 (last; no host update, no relu) =================
    k_gemm128<<<dim3(cdiv(N_HOSTN,16)), dim3(256), 0, stream>>>(HA, 0, w_h2f2, nullptr, HCbf, 1, N_HOSTN, 128, 0, 0, flagp);
    k_gemm_mfma<<<dim3(cdiv(N_FLOWN, GEMM_MROWS)), dim3(512), 0, stream>>>(F1bf, WBT2, Froot, F2bf, N_FLOWN);
    k_agg_flow<<<dim3(AGGF_BLK), dim3(256), 0, stream>>>(ZALL, rp_cmb, ei_cmb,
                                                         Froot, b_comb2, F1bf, 0);

    // ================= pool + classifier =================
    k_zero<<<GRID1(GG * HH)>>>((float*)poolbits, (size_t)GG * HH);
    k_pool2<<<dim3(cdiv(N_FLOWN, PCHUNK)), dim3(128), 0, stream>>>(F1bf, flow_batch, poolbits);
    k_classifier<<<dim3(GG), dim3(128), 0, stream>>>(poolbits, Wc1, bc1, Wc2, bc2, Wc3, bc3,
                                                     d_out, flagp);
    #undef GRID1
}

// Round 7
// 941.416 us; speedup vs baseline: 1.1465x; 1.1465x over previous
//
#include <hip/hip_runtime.h>
#include <hip/hip_bf16.h>

using bf16 = __hip_bfloat16;

#define N_HOSTN 20000
#define N_FLOWN 200000
#define E_HFN   400000
#define E_RELN  800000
#define E_CMBN  1200000  // rel + h2f combined
#define GG      64
#define HH      128
#define FIN     97
#define NCN     10

// CSR region block counts (256 threads/block)
#define NB_REL_E 3125   // 800000/256
#define NB_HF_E  1563   // ceil(400000/256)
#define NB_CMB_N 782    // ceil(200000/256)
#define NB_F2H_N 79     // ceil(20000/256)
// class-partitioned placement: 2048-edge chunks x 8 classes
#define NCH_REL 391     // ceil(800000/2048)
#define NCH_HF  196     // ceil(400000/2048)
#define PLC_REL (NCH_REL*8)            // 3128
#define PLC_H2F (PLC_REL + NCH_HF*8)   // 4696
#define PLC_ALL (PLC_H2F + NCH_HF*8)   // 6264

// persistent-wave aggregation geometry (quarter-per-dst)
#define AGG_CAP    768   // staged indices per wave (fallback to global beyond)
#define AGGF_DPW   24    // dsts per wave (multiple of 4)
#define AGGF_BLK   2084  // 2084 blk * 4 waves * 24 = 200064 >= 200000
#define AGGH_DPW   12
#define AGGH_BLK   417   // 417 * 4 * 12 = 20016 >= 20000

static inline int cdiv(long long a, long long b){ return (int)((a + b - 1) / b); }

__device__ __forceinline__ float bf2f(unsigned short u){
    return __uint_as_float(((unsigned)u) << 16);
}
__device__ __forceinline__ unsigned short f2bf(float f){
    unsigned u = __float_as_uint(f);
    unsigned r = u + 0x7FFFu + ((u >> 16) & 1u);   // RNE
    return (unsigned short)(r >> 16);
}
__device__ __forceinline__ float loadf(const void* p, size_t i, int isbf){
    return isbf ? bf2f(((const unsigned short*)p)[i]) : ((const float*)p)[i];
}
// unpack 8 bf16 (uint4) and accumulate into 8 f32
__device__ __forceinline__ void acc8(float* a, uint4 z){
    a[0] += __uint_as_float(z.x << 16);
    a[1] += __uint_as_float(z.x & 0xFFFF0000u);
    a[2] += __uint_as_float(z.y << 16);
    a[3] += __uint_as_float(z.y & 0xFFFF0000u);
    a[4] += __uint_as_float(z.z << 16);
    a[5] += __uint_as_float(z.z & 0xFFFF0000u);
    a[6] += __uint_as_float(z.w << 16);
    a[7] += __uint_as_float(z.w & 0xFFFF0000u);
}

// ---------------- dtype detection ----------------
__global__ void k_detect(const unsigned short* x, int* flag){
    __shared__ int bad;
    if (threadIdx.x == 0) bad = 0;
    __syncthreads();
    int b = 0;
    for (int i = threadIdx.x; i < 4096; i += 256) {
        unsigned e = (x[i] >> 7) & 0xFFu;
        if (e >= 0x90u) b++;
    }
    if (b) atomicAdd(&bad, b);
    __syncthreads();
    if (threadIdx.x == 0) *flag = (bad == 0) ? 1 : 0;   // 1 = bf16, 0 = f32
}

// ---------------- misc ----------------
__global__ void k_zero(float* p, size_t n){
    size_t i = (size_t)blockIdx.x * 256 + threadIdx.x;
    if (i < n) p[i] = 0.f;
}
__global__ void k_flag_us(unsigned short* out, int n, unsigned short val){
    int i = blockIdx.x * 256 + threadIdx.x;
    if (i < n) out[i] = val;
}
__global__ void k_gather_embed(const int* ids, const void* emb, float* out, const int* flagp){
    int i = blockIdx.x * 256 + threadIdx.x;
    if (i >= N_HOSTN * HH) return;
    int isbf = *flagp;
    int node = i >> 7, f = i & 127;
    out[i] = loadf(emb, (size_t)ids[node] * HH + f, isbf);
}
// flow_x [N,97] (flag dtype) -> bf16 padded [N,128]; 8 output cols per thread
__global__ void k_pad_cast(const void* x, unsigned short* o, const int* flagp){
    int i = blockIdx.x * 256 + threadIdx.x;           // 0 .. N_FLOWN*16
    if (i >= N_FLOWN * 16) return;
    int isbf = *flagp;
    int row = i >> 4, c0 = (i & 15) * 8;
    unsigned short v[8];
    #pragma unroll
    for (int j = 0; j < 8; ++j) {
        int c = c0 + j;
        v[j] = (c < FIN) ? f2bf(loadf(x, (size_t)row * FIN + c, isbf)) : (unsigned short)0;
    }
    uint4 ov;
    ov.x = (unsigned)v[0] | ((unsigned)v[1] << 16);
    ov.y = (unsigned)v[2] | ((unsigned)v[3] << 16);
    ov.z = (unsigned)v[4] | ((unsigned)v[5] << 16);
    ov.w = (unsigned)v[6] | ((unsigned)v[7] << 16);
    *(uint4*)(o + (size_t)row * 128 + c0) = ov;
}

// ---------------- one-shot weight prep (833 blocks, region dispatch) ----------------
__global__ __launch_bounds__(256) void k_wprep_all(
    const void* Wr0_h2f, const void* br0_h2f, const void* Wo0_h2f,
    const void* Wr0_f2h, const void* br0_f2h, const void* Wo0_f2h,
    const void* Wr0_rel, const void* br0_rel, const void* Wo0_rel,
    const void* Wr_all, const void* br_all, const void* Wo_all,
    unsigned short* WBT0, unsigned short* WBT1, unsigned short* WBT2,
    float* w_h2f0, float* w_h2f1, float* w_h2f2,
    float* w_f2h0, float* w_f2h1, float* w_of2h0, float* w_of2h1,
    float* b_comb0, float* b_comb1, float* b_comb2, float* b_f2h0, float* b_f2h1,
    const int* flagp)
{
    const int bb = blockIdx.x, t = threadIdx.x;
    const int isbf = *flagp;
    if (bb < 384) {
        int layer = bb >> 7;
        int i = ((bb & 127) << 8) + t;   // 0..32767
        int nn = i >> 7, k = i & 127;
        float v = 0.f;
        if (layer == 0) {
            if (k < FIN) {
                if (nn < 128) v = loadf(Wo0_h2f, (size_t)k*128+nn, isbf) + loadf(Wo0_rel, (size_t)k*128+nn, isbf);
                else          v = loadf(Wr0_rel, (size_t)k*128+(nn-128), isbf);
            }
        } else {
            size_t oW = (size_t)((layer - 1) * 3) * 16384;
            if (nn < 128) v = loadf(Wo_all, oW + (size_t)k*128+nn, isbf)
                            + loadf(Wo_all, oW + 2*16384 + (size_t)k*128+nn, isbf);
            else          v = loadf(Wr_all, oW + 2*16384 + (size_t)k*128+(nn-128), isbf);
        }
        unsigned short* W = (layer == 0) ? WBT0 : ((layer == 1) ? WBT1 : WBT2);
        W[(size_t)nn*128 + k] = f2bf(v);
    } else if (bb < 576) {
        int r = bb - 384; int layer = r >> 6; int i = ((r & 63) << 8) + t;
        float v;
        if (layer == 0) v = loadf(Wr0_h2f, (size_t)i, isbf);
        else            v = loadf(Wr_all, (size_t)((layer-1)*3)*16384 + i, isbf);
        ((layer == 0) ? w_h2f0 : ((layer == 1) ? w_h2f1 : w_h2f2))[i] = v;
    } else if (bb < 640) {
        // w_f2h0 padded to [128][128]: rows k>=97 zero
        int i = ((bb - 576) << 8) + t;
        int k = i >> 7;
        w_f2h0[i] = (k < FIN) ? loadf(Wr0_f2h, (size_t)i, isbf) : 0.f;
    } else if (bb < 704) {
        int i = ((bb - 640) << 8) + t;
        w_f2h1[i] = loadf(Wr_all, (size_t)1*16384 + i, isbf);
    } else if (bb < 768) {
        int i = ((bb - 704) << 8) + t;
        w_of2h0[i] = loadf(Wo0_f2h, (size_t)i, isbf);
    } else if (bb < 832) {
        int i = ((bb - 768) << 8) + t;
        w_of2h1[i] = loadf(Wo_all, (size_t)1*16384 + i, isbf);
    } else {
        if (t < 128) {
            b_comb0[t] = loadf(br0_h2f, t, isbf) + loadf(br0_rel, t, isbf);
            b_comb1[t] = loadf(br_all, 0*128 + t, isbf) + loadf(br_all, 2*128 + t, isbf);
            b_comb2[t] = loadf(br_all, 3*128 + t, isbf) + loadf(br_all, 5*128 + t, isbf);
            b_f2h0[t]  = loadf(br0_f2h, t, isbf);
            b_f2h1[t]  = loadf(br_all, 1*128 + t, isbf);
        }
    }
}

// ---------------- CSR build (combined flow CSR + f2h CSR) ----------------
__global__ void k_zero2(int* c0, int* c1){
    int bb = blockIdx.x, t = threadIdx.x;
    if (bb < NB_CMB_N) { int i = bb * 256 + t; if (i < N_FLOWN) c0[i] = 0; }
    else               { int i = (bb - NB_CMB_N) * 256 + t; if (i < N_HOSTN) c1[i] = 0; }
}
// rel and h2f edges both count into c_cmb; f2h into c_f2h
__global__ void k_hist3(const int* drel, const int* dh2f, const int* df2h,
                        int* c_cmb, int* c_f2h){
    int bb = blockIdx.x, t = threadIdx.x;
    const int* dst; int* cnt; int E; int base;
    if (bb < NB_REL_E)                   { dst = drel; cnt = c_cmb; E = E_RELN; base = bb; }
    else if (bb < NB_REL_E + NB_HF_E)    { dst = dh2f; cnt = c_cmb; E = E_HFN;  base = bb - NB_REL_E; }
    else                                 { dst = df2h; cnt = c_f2h; E = E_HFN;  base = bb - NB_REL_E - NB_HF_E; }
    int e = base * 256 + t;
    if (e < E) atomicAdd(&cnt[dst[e]], 1);
}
__global__ __launch_bounds__(256) void k_scan1_2(
    const int* c0, int* rp0, int* bs0,
    const int* c1, int* rp1, int* bs1)
{
    __shared__ int s[256];
    int bb = blockIdx.x, t = threadIdx.x;
    const int* cnt; int* rp; int* bsum; int n; int base;
    if (bb < NB_CMB_N) { cnt = c0; rp = rp0; bsum = bs0; n = N_FLOWN; base = bb; }
    else               { cnt = c1; rp = rp1; bsum = bs1; n = N_HOSTN; base = bb - NB_CMB_N; }
    int i = base * 256 + t;
    int v = (i < n) ? cnt[i] : 0;
    s[t] = v; __syncthreads();
    for (int off = 1; off < 256; off <<= 1) {
        int x = (t >= off) ? s[t - off] : 0;
        __syncthreads();
        s[t] += x;
        __syncthreads();
    }
    if (i < n) rp[i] = s[t] - v;
    if (t == 255) bsum[base] = s[255];
}
__global__ __launch_bounds__(256) void k_scan2_2(int* bs0, int* bs1){
    __shared__ int s[256];
    __shared__ int carry;
    int t = threadIdx.x;
    int* bsum; int nb;
    if (blockIdx.x == 0) { bsum = bs0; nb = NB_CMB_N; }
    else                 { bsum = bs1; nb = NB_F2H_N; }
    if (t == 0) carry = 0;
    __syncthreads();
    for (int base = 0; base < nb; base += 256) {
        int i = base + t;
        int v = (i < nb) ? bsum[i] : 0;
        s[t] = v; __syncthreads();
        for (int off = 1; off < 256; off <<= 1) {
            int x = (t >= off) ? s[t - off] : 0;
            __syncthreads();
            s[t] += x;
            __syncthreads();
        }
        int excl = s[t] - v + carry;
        if (i < nb) bsum[i] = excl;
        __syncthreads();
        if (t == 255) carry += s[255];
        __syncthreads();
    }
}
__global__ void k_scan3_2(int* rp0, const int* bs0, int* w0,
                          int* rp1, const int* bs1, int* w1)
{
    int bb = blockIdx.x, t = threadIdx.x;
    int* rp; const int* bsum; int* wr; int n, E, base;
    if (bb < NB_CMB_N) { rp = rp0; bsum = bs0; wr = w0; n = N_FLOWN; E = E_CMBN; base = bb; }
    else               { rp = rp1; bsum = bs1; wr = w1; n = N_HOSTN; E = E_HFN;  base = bb - NB_CMB_N; }
    int i = base * 256 + t;
    if (i < n) { int v = rp[i] + bsum[base]; rp[i] = v; wr[i] = v; }
    if (i == 0) rp[n] = E;
}
// class-partitioned placement: class = blockIdx%8 (round-robins onto XCDs);
// rel + h2f both place into the combined flow CSR; h2f srcs get +N_FLOWN so
// the gather reads the host rows appended after the flow rows in ZALL.
__global__ __launch_bounds__(256) void k_place3c(
    const int* s0, const int* d0,
    const int* s1, const int* d1,
    const int* s2, const int* d2,
    int* w_cmb, int* e_cmb, int* w_f2h, int* e_f2h)
{
    const int bb = blockIdx.x;
    const int *src, *dst; int *wr, *ei; int E, divc, rb, soff;
    if (bb < PLC_REL)      { src=s0; dst=d0; wr=w_cmb; ei=e_cmb; E=E_RELN; divc=25000; rb=bb;          soff=0; }
    else if (bb < PLC_H2F) { src=s1; dst=d1; wr=w_cmb; ei=e_cmb; E=E_HFN;  divc=25000; rb=bb-PLC_REL;  soff=N_FLOWN; }
    else                   { src=s2; dst=d2; wr=w_f2h; ei=e_f2h; E=E_HFN;  divc=2500;  rb=bb-PLC_H2F;  soff=0; }
    const int cls  = rb & 7;
    const int base = (rb >> 3) * 2048;
    const int t = threadIdx.x;
    #pragma unroll
    for (int i = 0; i < 8; ++i) {
        const int e = base + t + i * 256;
        if (e < E) {
            const int d = dst[e];
            if (d / divc == cls) {
                const int pos = atomicAdd(&wr[d], 1);
                ei[pos] = src[e] + soff;
            }
        }
    }
}

// ---------------- host-sized VALU GEMM: Y[M,128] (+)= X[M,K]@W[K,128]+b ---------
__global__ __launch_bounds__(256) void k_gemm128(
    const void* X, int xmode, const float* W, const float* bias,
    void* Y, int ybf, int M, int K, int accum, int dorelu, const int* flagp)
{
    const int isbf = (xmode == 2) ? *flagp : xmode;
    const int tid  = threadIdx.x;
    const int row0 = blockIdx.x * 16;
    __shared__ float sX[16][132];
    if (!isbf && (K & 3) == 0) {
        // vectorized f32 staging (all current call sites)
        const int kq = K >> 2;
        for (int i = tid; i < 16 * kq; i += 256) {
            int r = i / kq, c4 = (i - r * kq) * 4;
            int gr = row0 + r;
            float4 v = {0.f, 0.f, 0.f, 0.f};
            if (gr < M) v = *(const float4*)((const float*)X + (size_t)gr * K + c4);
            *(float4*)&sX[r][c4] = v;
        }
    } else {
        const int total = 16 * K;
        for (int i = tid; i < total; i += 256) {
            int r = i / K, c = i - r * K;
            int gr = row0 + r;
            sX[r][c] = (gr < M) ? loadf(X, (size_t)gr * K + c, isbf) : 0.f;
        }
    }
    __syncthreads();

    const int c4 = (tid & 31) * 4;
    const int rb = tid >> 5;
    float a0x=0,a0y=0,a0z=0,a0w=0, a1x=0,a1y=0,a1z=0,a1w=0;
    #pragma unroll 4
    for (int k = 0; k < K; ++k) {
        const float4 w = *(const float4*)(W + (size_t)k * 128 + c4);
        const float x0 = sX[rb][k];
        const float x1 = sX[rb + 8][k];
        a0x = fmaf(x0, w.x, a0x); a0y = fmaf(x0, w.y, a0y);
        a0z = fmaf(x0, w.z, a0z); a0w = fmaf(x0, w.w, a0w);
        a1x = fmaf(x1, w.x, a1x); a1y = fmaf(x1, w.y, a1y);
        a1z = fmaf(x1, w.z, a1z); a1w = fmaf(x1, w.w, a1w);
    }
    float bx=0, by=0, bz=0, bw=0;
    if (bias) { const float4 b = *(const float4*)(bias + c4); bx=b.x; by=b.y; bz=b.z; bw=b.w; }

    #pragma unroll
    for (int h = 0; h < 2; ++h) {
        const int rr = row0 + rb + (h ? 8 : 0);
        if (rr >= M) continue;
        float v0 = (h?a1x:a0x)+bx, v1 = (h?a1y:a0y)+by;
        float v2 = (h?a1z:a0z)+bz, v3 = (h?a1w:a0w)+bw;
        if (ybf) {
            unsigned short* p = (unsigned short*)Y + (size_t)rr * 128 + c4;
            ushort4 o; o.x=f2bf(v0); o.y=f2bf(v1); o.z=f2bf(v2); o.w=f2bf(v3);
            *(ushort4*)p = o;
        } else {
            float* p = (float*)Y + (size_t)rr * 128 + c4;
            if (accum) { v0+=p[0]; v1+=p[1]; v2+=p[2]; v3+=p[3]; }
            if (dorelu) { v0=fmaxf(v0,0.f); v1=fmaxf(v1,0.f); v2=fmaxf(v2,0.f); v3=fmaxf(v3,0.f); }
            float4 o; o.x=v0; o.y=v1; o.z=v2; o.w=v3;
            *(float4*)p = o;
        }
    }
}

// ---------------- fused dual-input host GEMM: Y = relu(X1@W1 + X2@W2 + b) ------
__global__ __launch_bounds__(256) void k_gemm2in(
    const float* __restrict__ X1, const float* __restrict__ X2,
    const float* __restrict__ W1, const float* __restrict__ W2,
    const float* __restrict__ bias, float* __restrict__ Y, int M)
{
    const int tid  = threadIdx.x;
    const int row0 = blockIdx.x * 16;
    __shared__ float sX1[16][132];
    __shared__ float sX2[16][132];
    for (int i = tid; i < 16 * 32; i += 256) {
        int r = i >> 5, c4 = (i & 31) * 4;
        int gr = row0 + r;
        float4 v1 = {0.f, 0.f, 0.f, 0.f}, v2 = {0.f, 0.f, 0.f, 0.f};
        if (gr < M) {
            v1 = *(const float4*)(X1 + (size_t)gr * 128 + c4);
            v2 = *(const float4*)(X2 + (size_t)gr * 128 + c4);
        }
        *(float4*)&sX1[r][c4] = v1;
        *(float4*)&sX2[r][c4] = v2;
    }
    __syncthreads();

    const int c4 = (tid & 31) * 4;
    const int rb = tid >> 5;
    float a0x=0,a0y=0,a0z=0,a0w=0, a1x=0,a1y=0,a1z=0,a1w=0;
    #pragma unroll 4
    for (int k = 0; k < 128; ++k) {
        const float4 w = *(const float4*)(W1 + (size_t)k * 128 + c4);
        const float x0 = sX1[rb][k];
        const float x1 = sX1[rb + 8][k];
        a0x = fmaf(x0, w.x, a0x); a0y = fmaf(x0, w.y, a0y);
        a0z = fmaf(x0, w.z, a0z); a0w = fmaf(x0, w.w, a0w);
        a1x = fmaf(x1, w.x, a1x); a1y = fmaf(x1, w.y, a1y);
        a1z = fmaf(x1, w.z, a1z); a1w = fmaf(x1, w.w, a1w);
    }
    #pragma unroll 4
    for (int k = 0; k < 128; ++k) {
        const float4 w = *(const float4*)(W2 + (size_t)k * 128 + c4);
        const float x0 = sX2[rb][k];
        const float x1 = sX2[rb + 8][k];
        a0x = fmaf(x0, w.x, a0x); a0y = fmaf(x0, w.y, a0y);
        a0z = fmaf(x0, w.z, a0z); a0w = fmaf(x0, w.w, a0w);
        a1x = fmaf(x1, w.x, a1x); a1y = fmaf(x1, w.y, a1y);
        a1z = fmaf(x1, w.z, a1z); a1w = fmaf(x1, w.w, a1w);
    }
    const float4 b = *(const float4*)(bias + c4);
    #pragma unroll
    for (int h = 0; h < 2; ++h) {
        const int rr = row0 + rb + (h ? 8 : 0);
        if (rr >= M) continue;
        float4 o;
        o.x = fmaxf((h?a1x:a0x) + b.x, 0.f);
        o.y = fmaxf((h?a1y:a0y) + b.y, 0.f);
        o.z = fmaxf((h?a1z:a0z) + b.z, 0.f);
        o.w = fmaxf((h?a1w:a0w) + b.w, 0.f);
        *(float4*)(Y + (size_t)rr * 128 + c4) = o;
    }
}

// ---------------- MFMA dual flow GEMM: both outputs bf16, no bias ----------------
// v7: ALL global traffic linearized. R3/R5/R6 all plateaued at 73-83us with
// MfmaUtil ~6% regardless of occupancy (24->50%) -- the invariant was the
// 16-segment scattered A-loads (x8 redundant across waves) and 16-segment
// scattered D-stores. Now: (1) A staged ONCE per block into XOR-swizzled LDS
// via linear uint4 loads (1 per thread per chunk); fragments read from LDS
// (2-way bank = free); (2) output bounced through LDS (sO, padded rows) and
// stored with LINEAR uint4 stores (consecutive lanes -> consecutive addr).
// 8 waves x 32 WBT rows (B = 8 bfrags in regs), __launch_bounds__(512,4).
typedef __attribute__((ext_vector_type(8))) short bfrag;
typedef __attribute__((ext_vector_type(4))) float f32x4;

#define GEMM_CHUNKS 4
#define GEMM_MROWS  (32 * GEMM_CHUNKS)   // 128 rows per block

__global__ __launch_bounds__(512, 4) void k_gemm_mfma(
    const unsigned short* __restrict__ Abf, const unsigned short* __restrict__ WBT,
    unsigned short* __restrict__ Y1, unsigned short* __restrict__ Y2, int M)
{
    __shared__ unsigned short sA[32 * 128];      // 8 KB, XOR-swizzled 16B units
    __shared__ unsigned short sO[2][32][136];    // 17.4 KB out-stage (pad 8 shorts)

    const int tid  = threadIdx.x;
    const int wave = tid >> 6;        // 0..7
    const int lane = tid & 63;
    const int quad = lane >> 4;
    const int l16  = lane & 15;
    const int nbase = wave * 32;      // 32 WBT rows per wave

    // B slice for this wave's 32 output cols: breg[c][j] (8 bfrags = 32 regs)
    bfrag breg[4][2];
    #pragma unroll
    for (int c = 0; c < 4; ++c)
        #pragma unroll
        for (int j = 0; j < 2; ++j)
            breg[c][j] = *(const bfrag*)(WBT + (size_t)(nbase + j * 16 + l16) * 128
                                              + c * 32 + quad * 8);

    const int ybuf = (nbase < 128) ? 0 : 1;
    const int colb = nbase & 127;
    const f32x4 zero = {0.f, 0.f, 0.f, 0.f};

    const int srow = tid >> 4;        // staging row 0..31
    const int su   = tid & 15;        // staging 16B unit 0..15

    for (int chunk = 0; chunk < GEMM_CHUNKS; ++chunk) {
        const int m0 = blockIdx.x * GEMM_MROWS + chunk * 32;
        if (m0 >= M) break;           // block-uniform (M % 32 == 0)

        // ---- stage A chunk (32x128 bf16 = 8KB): linear load, swizzled LDS ----
        {
            const uint4* gsrc = (const uint4*)(Abf + (size_t)m0 * 128);
            uint4* sdst = (uint4*)sA;
            sdst[srow * 16 + (su ^ (srow & 15))] = gsrc[tid];
        }
        __syncthreads();

        // ---- fragments from LDS + MFMA ----
        bfrag a0[4], a1[4];
        #pragma unroll
        for (int c = 0; c < 4; ++c) {
            const int un = (c * 4 + quad) ^ l16;
            a0[c] = *(const bfrag*)(sA + (size_t)(l16)      * 128 + un * 8);
            a1[c] = *(const bfrag*)(sA + (size_t)(16 + l16) * 128 + un * 8);
        }
        f32x4 acc[2][2];
        #pragma unroll
        for (int j = 0; j < 2; ++j) {
            acc[0][j] = __builtin_amdgcn_mfma_f32_16x16x32_bf16(breg[0][j], a0[0], zero, 0, 0, 0);
            acc[1][j] = __builtin_amdgcn_mfma_f32_16x16x32_bf16(breg[0][j], a1[0], zero, 0, 0, 0);
        }
        #pragma unroll
        for (int c = 1; c < 4; ++c)
            #pragma unroll
            for (int j = 0; j < 2; ++j) {
                acc[0][j] = __builtin_amdgcn_mfma_f32_16x16x32_bf16(breg[c][j], a0[c], acc[0][j], 0, 0, 0);
                acc[1][j] = __builtin_amdgcn_mfma_f32_16x16x32_bf16(breg[c][j], a1[c], acc[1][j], 0, 0, 0);
            }

        // ---- stage D' to LDS (D' layout: col(l16)=row m, row(quad*4+r)=col n) ----
        #pragma unroll
        for (int i = 0; i < 2; ++i) {
            const int row = i * 16 + l16;
            #pragma unroll
            for (int j = 0; j < 2; ++j) {
                const int col = colb + j * 16 + quad * 4;
                uint2 o;
                o.x = (unsigned)f2bf(acc[i][j][0]) | ((unsigned)f2bf(acc[i][j][1]) << 16);
                o.y = (unsigned)f2bf(acc[i][j][2]) | ((unsigned)f2bf(acc[i][j][3]) << 16);
                *(uint2*)&sO[ybuf][row][col] = o;
            }
        }
        __syncthreads();

        // ---- linear coalesced stores: 1KB-contiguous per wave instruction ----
        {
            const size_t goff = (size_t)(m0 + srow) * 128 + su * 8;
            *(uint4*)(Y1 + goff) = *(const uint4*)&sO[0][srow][su * 8];
            *(uint4*)(Y2 + goff) = *(const uint4*)&sO[1][srow][su * 8];
        }
        __syncthreads();
    }
}

// ---------------- persistent-wave combined CSR aggregation (flow dsts) ----------
// QUARTER-PER-DST: each 16-lane quarter owns one dst entirely (16 lanes x 8
// features = 128). Per outer iteration the wave processes 4 CONSECUTIVE dsts in
// parallel: no cross-quarter reduce, epilogue amortized 4x, root loads / stores
// are 4 consecutive rows = 1 KiB contiguous per instruction.
// Edge-index window staged to LDS once per wave (contiguous CSR range).
__global__ __launch_bounds__(256) void k_agg_flow(
    const unsigned short* __restrict__ Z,
    const int* __restrict__ rp, const int* __restrict__ ei,
    const unsigned short* __restrict__ root, const float* __restrict__ bias,
    unsigned short* __restrict__ Xout, int do_relu)
{
    __shared__ int sIdx[4][AGG_CAP];
    const int wave = threadIdx.x >> 6;
    const int lane = threadIdx.x & 63;
    const int q    = lane >> 4;
    const int l16  = lane & 15;
    const int f8   = l16 * 8;
    const int gw   = blockIdx.x * 4 + wave;
    const int d0   = gw * AGGF_DPW;
    const int nd   = min(AGGF_DPW, N_FLOWN - d0);   // may be <= 0 for tail waves

    int rpv = 0, W0 = 0, Wcap = 0;
    if (nd > 0) {
        rpv = (lane <= nd) ? rp[d0 + lane] : 0;
        W0 = __shfl(rpv, 0, 64);
        const int Wn = __shfl(rpv, nd, 64);
        const int cw = min(Wn - W0, AGG_CAP);
        for (int i = lane; i < cw; i += 64) sIdx[wave][i] = ei[W0 + i];
        Wcap = W0 + cw;
    }
    __syncthreads();
    if (nd <= 0) return;

    // loop-invariant bias slice
    const float4 bva = *(const float4*)(bias + f8);
    const float4 bvb = *(const float4*)(bias + f8 + 4);

    #pragma unroll 2
    for (int i = 0; i < AGGF_DPW / 4; ++i) {
        const int dqi = i * 4 + q;              // this quarter's dst offset
        const bool act = dqi < nd;
        const int srcl = act ? dqi : 0;
        const int b0 = __shfl(rpv, srcl, 64);
        const int b1 = __shfl(rpv, srcl + 1, 64);
        const int d  = d0 + dqi;

        uint4 rv = {0, 0, 0, 0};
        if (act) rv = *(const uint4*)(root + (size_t)d * 128 + f8);

        float a[8] = {0.f, 0.f, 0.f, 0.f, 0.f, 0.f, 0.f, 0.f};
        int n = act ? (b1 - b0) : 0;
        int e = b0;
        while (n >= 4) {
            const int s0 = (e     < Wcap) ? sIdx[wave][e     - W0] : ei[e];
            const int s1 = (e + 1 < Wcap) ? sIdx[wave][e + 1 - W0] : ei[e + 1];
            const int s2 = (e + 2 < Wcap) ? sIdx[wave][e + 2 - W0] : ei[e + 2];
            const int s3 = (e + 3 < Wcap) ? sIdx[wave][e + 3 - W0] : ei[e + 3];
            const uint4 z0 = *(const uint4*)(Z + (size_t)s0 * 128 + f8);
            const uint4 z1 = *(const uint4*)(Z + (size_t)s1 * 128 + f8);
            const uint4 z2 = *(const uint4*)(Z + (size_t)s2 * 128 + f8);
            const uint4 z3 = *(const uint4*)(Z + (size_t)s3 * 128 + f8);
            acc8(a, z0); acc8(a, z1); acc8(a, z2); acc8(a, z3);
            e += 4; n -= 4;
        }
        if (n & 2) {
            const int s0 = (e     < Wcap) ? sIdx[wave][e     - W0] : ei[e];
            const int s1 = (e + 1 < Wcap) ? sIdx[wave][e + 1 - W0] : ei[e + 1];
            const uint4 z0 = *(const uint4*)(Z + (size_t)s0 * 128 + f8);
            const uint4 z1 = *(const uint4*)(Z + (size_t)s1 * 128 + f8);
            acc8(a, z0); acc8(a, z1);
            e += 2;
        }
        if (n & 1) {
            const int s0 = (e < Wcap) ? sIdx[wave][e - W0] : ei[e];
            const uint4 z0 = *(const uint4*)(Z + (size_t)s0 * 128 + f8);
            acc8(a, z0);
        }

        if (act) {
            float v0 = a[0] + __uint_as_float(rv.x << 16)         + bva.x;
            float v1 = a[1] + __uint_as_float(rv.x & 0xFFFF0000u) + bva.y;
            float v2 = a[2] + __uint_as_float(rv.y << 16)         + bva.z;
            float v3 = a[3] + __uint_as_float(rv.y & 0xFFFF0000u) + bva.w;
            float v4 = a[4] + __uint_as_float(rv.z << 16)         + bvb.x;
            float v5 = a[5] + __uint_as_float(rv.z & 0xFFFF0000u) + bvb.y;
            float v6 = a[6] + __uint_as_float(rv.w << 16)         + bvb.z;
            float v7 = a[7] + __uint_as_float(rv.w & 0xFFFF0000u) + bvb.w;
            if (do_relu) {
                v0 = fmaxf(v0, 0.f); v1 = fmaxf(v1, 0.f); v2 = fmaxf(v2, 0.f); v3 = fmaxf(v3, 0.f);
                v4 = fmaxf(v4, 0.f); v5 = fmaxf(v5, 0.f); v6 = fmaxf(v6, 0.f); v7 = fmaxf(v7, 0.f);
            }
            uint4 o;
            o.x = (unsigned)f2bf(v0) | ((unsigned)f2bf(v1) << 16);
            o.y = (unsigned)f2bf(v2) | ((unsigned)f2bf(v3) << 16);
            o.z = (unsigned)f2bf(v4) | ((unsigned)f2bf(v5) << 16);
            o.w = (unsigned)f2bf(v6) | ((unsigned)f2bf(v7) << 16);
            *(uint4*)(Xout + (size_t)d * 128 + f8) = o;
        }
    }
}

// host dst: out[d][0:128] = sum f2h Z[src][0:128]  (f32 out)
// Same quarter-per-dst persistent structure.
__global__ __launch_bounds__(256) void k_agg_host(
    const unsigned short* __restrict__ Z, const int* __restrict__ rp,
    const int* __restrict__ ei, float* __restrict__ out)
{
    __shared__ int sIdx[4][AGG_CAP];
    const int wave = threadIdx.x >> 6;
    const int lane = threadIdx.x & 63;
    const int q    = lane >> 4;
    const int l16  = lane & 15;
    const int f8   = l16 * 8;
    const int gw   = blockIdx.x * 4 + wave;
    const int d0   = gw * AGGH_DPW;
    const int nd   = min(AGGH_DPW, N_HOSTN - d0);

    int rpv = 0, W0 = 0, Wcap = 0;
    if (nd > 0) {
        rpv = (lane <= nd) ? rp[d0 + lane] : 0;
        W0 = __shfl(rpv, 0, 64);
        const int Wn = __shfl(rpv, nd, 64);
        const int cw = min(Wn - W0, AGG_CAP);
        for (int i = lane; i < cw; i += 64) sIdx[wave][i] = ei[W0 + i];
        Wcap = W0 + cw;
    }
    __syncthreads();
    if (nd <= 0) return;

    #pragma unroll
    for (int i = 0; i < AGGH_DPW / 4; ++i) {
        const int dqi = i * 4 + q;
        const bool act = dqi < nd;
        const int srcl = act ? dqi : 0;
        const int b0 = __shfl(rpv, srcl, 64);
        const int b1 = __shfl(rpv, srcl + 1, 64);
        const int d  = d0 + dqi;

        float a[8] = {0.f, 0.f, 0.f, 0.f, 0.f, 0.f, 0.f, 0.f};
        int n = act ? (b1 - b0) : 0;
        int e = b0;
        while (n >= 4) {
            const int s0 = (e     < Wcap) ? sIdx[wave][e     - W0] : ei[e];
            const int s1 = (e + 1 < Wcap) ? sIdx[wave][e + 1 - W0] : ei[e + 1];
            const int s2 = (e + 2 < Wcap) ? sIdx[wave][e + 2 - W0] : ei[e + 2];
            const int s3 = (e + 3 < Wcap) ? sIdx[wave][e + 3 - W0] : ei[e + 3];
            const uint4 z0 = *(const uint4*)(Z + (size_t)s0 * 128 + f8);
            const uint4 z1 = *(const uint4*)(Z + (size_t)s1 * 128 + f8);
            const uint4 z2 = *(const uint4*)(Z + (size_t)s2 * 128 + f8);
            const uint4 z3 = *(const uint4*)(Z + (size_t)s3 * 128 + f8);
            acc8(a, z0); acc8(a, z1); acc8(a, z2); acc8(a, z3);
            e += 4; n -= 4;
        }
        if (n & 2) {
            const int s0 = (e     < Wcap) ? sIdx[wave][e     - W0] : ei[e];
            const int s1 = (e + 1 < Wcap) ? sIdx[wave][e + 1 - W0] : ei[e + 1];
            const uint4 z0 = *(const uint4*)(Z + (size_t)s0 * 128 + f8);
            const uint4 z1 = *(const uint4*)(Z + (size_t)s1 * 128 + f8);
            acc8(a, z0); acc8(a, z1);
            e += 2;
        }
        if (n & 1) {
            const int s0 = (e < Wcap) ? sIdx[wave][e - W0] : ei[e];
            const uint4 z0 = *(const uint4*)(Z + (size_t)s0 * 128 + f8);
            acc8(a, z0);
        }

        if (act) {
            float4 oa, ob;
            oa.x = a[0]; oa.y = a[1]; oa.z = a[2]; oa.w = a[3];
            ob.x = a[4]; ob.y = a[5]; ob.z = a[6]; ob.w = a[7];
            *(float4*)(out + (size_t)d * 128 + f8)     = oa;
            *(float4*)(out + (size_t)d * 128 + f8 + 4) = ob;
        }
    }
}

// ---------------- pooling over sorted batch (bf16 input) ----------------
#define PCHUNK 128
__global__ __launch_bounds__(128) void k_pool2(const unsigned short* xf, const int* batch,
                                               unsigned* bits){
    const int t = threadIdx.x;
    const int i0 = blockIdx.x * PCHUNK;
    const int iend = min(i0 + PCHUNK, N_FLOWN);
    if (i0 >= N_FLOWN) return;
    float cur = -3.4e38f;
    int curg = batch[i0];
    for (int i = i0; i < iend; ++i) {
        int g = batch[i];
        if (g != curg) {
            unsigned u = __float_as_uint(cur);
            unsigned ord = (u & 0x80000000u) ? ~u : (u | 0x80000000u);
            atomicMax(&bits[(size_t)curg * 128 + t], ord);
            cur = -3.4e38f; curg = g;
        }
        cur = fmaxf(cur, bf2f(xf[(size_t)i * 128 + t]));
    }
    unsigned u = __float_as_uint(cur);
    unsigned ord = (u & 0x80000000u) ? ~u : (u | 0x80000000u);
    atomicMax(&bits[(size_t)curg * 128 + t], ord);
}

// ---------------- classifier ----------------
__global__ __launch_bounds__(128) void k_classifier(
    const unsigned* bits,
    const void* Wc1, const void* bc1, const void* Wc2, const void* bc2,
    const void* Wc3, const void* bc3, void* out, const int* flagp)
{
    const int g = blockIdx.x, t = threadIdx.x;
    const int isbf = *flagp;
    __shared__ float sp[128], sh1[64], sh2[128];
    {
        unsigned ord = bits[(size_t)g * HH + t];
        unsigned u = (ord & 0x80000000u) ? (ord & 0x7FFFFFFFu) : ~ord;
        sp[t] = __uint_as_float(u);
    }
    __syncthreads();
    if (t < 64) {
        float a = loadf(bc1, t, isbf);
        #pragma unroll 4
        for (int k = 0; k < 128; ++k) a = fmaf(sp[k], loadf(Wc1, k * 64 + t, isbf), a);
        sh1[t] = fmaxf(a, 0.f);
    }
    __syncthreads();
    {
        float a = loadf(bc2, t, isbf);
        #pragma unroll 4
        for (int k = 0; k < 64; ++k) a = fmaf(sh1[k], loadf(Wc2, k * 128 + t, isbf), a);
        sh2[t] = fmaxf(a, 0.f);
    }
    __syncthreads();
    if (t < NCN) {
        float a = loadf(bc3, t, isbf);
        #pragma unroll 4
        for (int k = 0; k < 128; ++k) a = fmaf(sh2[k], loadf(Wc3, k * NCN + t, isbf), a);
        if (isbf) ((unsigned short*)out)[(size_t)g * NCN + t] = f2bf(a);
        else      ((float*)out)[(size_t)g * NCN + t] = a;
    }
}

extern "C" void kernel_launch(void* const* d_in, const int* in_sizes, int n_in,
                              void* d_out, int out_size, void* d_ws, size_t ws_size,
                              hipStream_t stream)
{
    const int*  host_ids   = (const int*) d_in[0];
    const void* flow_x     = d_in[1];
    const int*  h2f_src    = (const int*) d_in[2];
    const int*  h2f_dst    = (const int*) d_in[3];
    const int*  f2h_src    = (const int*) d_in[4];
    const int*  f2h_dst    = (const int*) d_in[5];
    const int*  rel_src    = (const int*) d_in[6];
    const int*  rel_dst    = (const int*) d_in[7];
    const int*  flow_batch = (const int*) d_in[8];
    const void* host_embed = d_in[9];
    const void* Wr0_h2f = d_in[10]; const void* br0_h2f = d_in[11]; const void* Wo0_h2f = d_in[12];
    const void* Wr0_f2h = d_in[13]; const void* br0_f2h = d_in[14]; const void* Wo0_f2h = d_in[15];
    const void* Wr0_rel = d_in[16]; const void* br0_rel = d_in[17]; const void* Wo0_rel = d_in[18];
    const void* Wr_all  = d_in[19];
    const void* br_all  = d_in[20];
    const void* Wo_all  = d_in[21];
    const void* Wc1 = d_in[22]; const void* bc1 = d_in[23];
    const void* Wc2 = d_in[24]; const void* bc2 = d_in[25];
    const void* Wc3 = d_in[26]; const void* bc3 = d_in[27];

    // -------- workspace (~199 MB) --------
    size_t off = 0;
    auto alloc = [&](size_t bytes) -> char* {
        char* p = (char*)d_ws + off;
        off += (bytes + 255) & ~(size_t)255;
        return p;
    };
    unsigned short* F1bf  = (unsigned short*)alloc((size_t)N_FLOWN * HH * 2);  // state
    unsigned short* Froot = (unsigned short*)alloc((size_t)N_FLOWN * HH * 2);  // root term
    // ZALL: flow-transformed rows [0,200k) followed by host-transformed rows [200k,220k)
    unsigned short* ZALL  = (unsigned short*)alloc((size_t)(N_FLOWN + N_HOSTN) * HH * 2);
    unsigned short* F2bf  = ZALL;                                   // z_rel
    unsigned short* HCbf  = ZALL + (size_t)N_FLOWN * HH;            // z_h
    float* HA = (float*)alloc((size_t)N_HOSTN * HH * 4);
    float* HB = (float*)alloc((size_t)N_HOSTN * HH * 4);
    float* HD = (float*)alloc((size_t)N_HOSTN * HH * 4);
    unsigned short* WBT0 = (unsigned short*)alloc(256 * 128 * 2);
    unsigned short* WBT1 = (unsigned short*)alloc(256 * 128 * 2);
    unsigned short* WBT2 = (unsigned short*)alloc(256 * 128 * 2);
    float* w_h2f0  = (float*)alloc(128 * 128 * 4);
    float* w_h2f1  = (float*)alloc(128 * 128 * 4);
    float* w_h2f2  = (float*)alloc(128 * 128 * 4);
    float* w_f2h0  = (float*)alloc(128 * 128 * 4);
    float* w_f2h1  = (float*)alloc(128 * 128 * 4);
    float* w_of2h0 = (float*)alloc(128 * 128 * 4);
    float* w_of2h1 = (float*)alloc(128 * 128 * 4);
    float* b_comb0 = (float*)alloc(128 * 4);
    float* b_comb1 = (float*)alloc(128 * 4);
    float* b_comb2 = (float*)alloc(128 * 4);
    float* b_f2h0  = (float*)alloc(128 * 4);
    float* b_f2h1  = (float*)alloc(128 * 4);
    unsigned* poolbits = (unsigned*)alloc(GG * HH * 4);
    int* flagp = (int*)alloc(256);
    int* rp_cmb = (int*)alloc((N_FLOWN + 1) * 4);
    int* ei_cmb = (int*)alloc((size_t)E_CMBN * 4);
    int* rp_f2h = (int*)alloc((N_HOSTN + 1) * 4);
    int* ei_f2h = (int*)alloc((size_t)E_HFN * 4);
    int* wr_cmb = (int*)alloc((size_t)N_FLOWN * 4);
    int* wr_f2h = (int*)alloc((size_t)N_HOSTN * 4);
    int* bs0 = (int*)alloc(1024 * 4);
    int* bs2 = (int*)alloc(256 * 4);

    const int T = 256;
    #define GRID1(n) dim3(cdiv((long long)(n), T)), dim3(T), 0, stream

    if (off > ws_size) {
        k_flag_us<<<GRID1(out_size)>>>((unsigned short*)d_out, out_size, (unsigned short)0x4000);
        return;
    }

    k_detect<<<dim3(1), dim3(256), 0, stream>>>((const unsigned short*)flow_x, flagp);

    // -------- CSR builds (combined flow CSR + f2h CSR) --------
    k_zero2 <<<dim3(NB_CMB_N + NB_F2H_N), dim3(256), 0, stream>>>(wr_cmb, wr_f2h);
    k_hist3 <<<dim3(NB_REL_E + 2*NB_HF_E), dim3(256), 0, stream>>>(rel_dst, h2f_dst, f2h_dst,
                                                                    wr_cmb, wr_f2h);
    k_scan1_2<<<dim3(NB_CMB_N + NB_F2H_N), dim3(256), 0, stream>>>(
        wr_cmb, rp_cmb, bs0, wr_f2h, rp_f2h, bs2);
    k_scan2_2<<<dim3(2), dim3(256), 0, stream>>>(bs0, bs2);
    k_scan3_2<<<dim3(NB_CMB_N + NB_F2H_N), dim3(256), 0, stream>>>(
        rp_cmb, bs0, wr_cmb, rp_f2h, bs2, wr_f2h);
    k_place3c<<<dim3(PLC_ALL), dim3(256), 0, stream>>>(
        rel_src, rel_dst, h2f_src, h2f_dst, f2h_src, f2h_dst,
        wr_cmb, ei_cmb, wr_f2h, ei_f2h);

    // -------- weight prep (1 launch) --------
    k_wprep_all<<<dim3(833), dim3(256), 0, stream>>>(
        Wr0_h2f, br0_h2f, Wo0_h2f, Wr0_f2h, br0_f2h, Wo0_f2h, Wr0_rel, br0_rel, Wo0_rel,
        Wr_all, br_all, Wo_all,
        WBT0, WBT1, WBT2, w_h2f0, w_h2f1, w_h2f2,
        w_f2h0, w_f2h1, w_of2h0, w_of2h1,
        b_comb0, b_comb1, b_comb2, b_f2h0, b_f2h1, flagp);

    // ================= layer 0 =================
    k_gather_embed<<<GRID1(N_HOSTN * HH)>>>(host_ids, host_embed, HA, flagp);
    k_pad_cast<<<GRID1(N_FLOWN * 16)>>>(flow_x, F1bf, flagp);
    // host path: gather bf16 input features (K padded to 128); fused dual GEMM + relu
    k_agg_host<<<dim3(AGGH_BLK), dim3(256), 0, stream>>>(F1bf, rp_f2h, ei_f2h, HD);
    k_gemm2in<<<dim3(cdiv(N_HOSTN,16)), dim3(256), 0, stream>>>(HD, HA, w_f2h0, w_of2h0, b_f2h0, HB, N_HOSTN);
    // flow path
    k_gemm128<<<dim3(cdiv(N_HOSTN,16)), dim3(256), 0, stream>>>(HA, 0, w_h2f0, nullptr, HCbf, 1, N_HOSTN, 128, 0, 0, flagp);
    k_gemm_mfma<<<dim3(cdiv(N_FLOWN, GEMM_MROWS)), dim3(512), 0, stream>>>(F1bf, WBT0, Froot, F2bf, N_FLOWN);
    k_agg_flow<<<dim3(AGGF_BLK), dim3(256), 0, stream>>>(ZALL, rp_cmb, ei_cmb,
                                                         Froot, b_comb0, F1bf, 1);

    // ================= stacked layer 0 =================
    k_agg_host<<<dim3(AGGH_BLK), dim3(256), 0, stream>>>(F1bf, rp_f2h, ei_f2h, HD);
    k_gemm128<<<dim3(cdiv(N_HOSTN,16)), dim3(256), 0, stream>>>(HB, 0, w_h2f1, nullptr, HCbf, 1, N_HOSTN, 128, 0, 0, flagp);
    k_gemm_mfma<<<dim3(cdiv(N_FLOWN, GEMM_MROWS)), dim3(512), 0, stream>>>(F1bf, WBT1, Froot, F2bf, N_FLOWN);
    k_agg_flow<<<dim3(AGGF_BLK), dim3(256), 0, stream>>>(ZALL, rp_cmb, ei_cmb,
                                                         Froot, b_comb1, F1bf, 1);
    k_gemm2in<<<dim3(cdiv(N_HOSTN,16)), dim3(256), 0, stream>>>(HD, HB, w_f2h1, w_of2h1, b_f2h1, HA, N_HOSTN);

    // ================= stacked layer 1 (last; no host update, no relu) =================
    k_gemm128<<<dim3(cdiv(N_HOSTN,16)), dim3(256), 0, stream>>>(HA, 0, w_h2f2, nullptr, HCbf, 1, N_HOSTN, 128, 0, 0, flagp);
    k_gemm_mfma<<<dim3(cdiv(N_FLOWN, GEMM_MROWS)), dim3(512), 0, stream>>>(F1bf, WBT2, Froot, F2bf, N_FLOWN);
    k_agg_flow<<<dim3(AGGF_BLK), dim3(256), 0, stream>>>(ZALL, rp_cmb, ei_cmb,
                                                         Froot, b_comb2, F1bf, 0);

    // ================= pool + classifier =================
    k_zero<<<GRID1(GG * HH)>>>((float*)poolbits, (size_t)GG * HH);
    k_pool2<<<dim3(cdiv(N_FLOWN, PCHUNK)), dim3(128), 0, stream>>>(F1bf, flow_batch, poolbits);
    k_classifier<<<dim3(GG), dim3(128), 0, stream>>>(poolbits, Wc1, bc1, Wc2, bc2, Wc3, bc3,
                                                     d_out, flagp);
    #undef GRID1
}

// Round 9
// 914.437 us; speedup vs baseline: 1.1803x; 1.0295x over previous
//
#include <hip/hip_runtime.h>
#include <hip/hip_bf16.h>

using bf16 = __hip_bfloat16;

#define N_HOSTN 20000
#define N_FLOWN 200000
#define E_HFN   400000
#define E_RELN  800000
#define E_CMBN  1200000  // rel + h2f combined
#define GG      64
#define HH      128
#define FIN     97
#define NCN     10

// CSR region block counts (256 threads/block)
#define NB_REL_E 3125   // 800000/256
#define NB_HF_E  1563   // ceil(400000/256)
#define NB_CMB_N 782    // ceil(200000/256)
#define NB_F2H_N 79     // ceil(20000/256)
// rank-based placement (4 edges/thread, 1024 edges/block)
#define PB_REL 782      // ceil(800000/1024)
#define PB_HF  391      // ceil(400000/1024)
#define PB_ALL (PB_REL + 2*PB_HF)   // 1564

// persistent-wave aggregation geometry (quarter-per-dst)
#define AGG_CAP    768   // staged indices per wave (fallback to global beyond)
#define AGGF_DPW   24    // dsts per wave (multiple of 4)
#define AGGF_BLK   2084  // 2084 blk * 4 waves * 24 = 200064 >= 200000
#define AGGH_DPW   12
#define AGGH_BLK   417   // 417 * 4 * 12 = 20016 >= 20000

static inline int cdiv(long long a, long long b){ return (int)((a + b - 1) / b); }

__device__ __forceinline__ float bf2f(unsigned short u){
    return __uint_as_float(((unsigned)u) << 16);
}
__device__ __forceinline__ unsigned short f2bf(float f){
    unsigned u = __float_as_uint(f);
    unsigned r = u + 0x7FFFu + ((u >> 16) & 1u);   // RNE
    return (unsigned short)(r >> 16);
}
__device__ __forceinline__ float loadf(const void* p, size_t i, int isbf){
    return isbf ? bf2f(((const unsigned short*)p)[i]) : ((const float*)p)[i];
}
// unpack 8 bf16 (uint4) and accumulate into 8 f32
__device__ __forceinline__ void acc8(float* a, uint4 z){
    a[0] += __uint_as_float(z.x << 16);
    a[1] += __uint_as_float(z.x & 0xFFFF0000u);
    a[2] += __uint_as_float(z.y << 16);
    a[3] += __uint_as_float(z.y & 0xFFFF0000u);
    a[4] += __uint_as_float(z.z << 16);
    a[5] += __uint_as_float(z.z & 0xFFFF0000u);
    a[6] += __uint_as_float(z.w << 16);
    a[7] += __uint_as_float(z.w & 0xFFFF0000u);
}

// ---------------- dtype detection ----------------
__global__ void k_detect(const unsigned short* x, int* flag){
    __shared__ int bad;
    if (threadIdx.x == 0) bad = 0;
    __syncthreads();
    int b = 0;
    for (int i = threadIdx.x; i < 4096; i += 256) {
        unsigned e = (x[i] >> 7) & 0xFFu;
        if (e >= 0x90u) b++;
    }
    if (b) atomicAdd(&bad, b);
    __syncthreads();
    if (threadIdx.x == 0) *flag = (bad == 0) ? 1 : 0;   // 1 = bf16, 0 = f32
}

// ---------------- misc ----------------
__global__ void k_zero(float* p, size_t n){
    size_t i = (size_t)blockIdx.x * 256 + threadIdx.x;
    if (i < n) p[i] = 0.f;
}
__global__ void k_flag_us(unsigned short* out, int n, unsigned short val){
    int i = blockIdx.x * 256 + threadIdx.x;
    if (i < n) out[i] = val;
}
__global__ void k_gather_embed(const int* ids, const void* emb, float* out, const int* flagp){
    int i = blockIdx.x * 256 + threadIdx.x;
    if (i >= N_HOSTN * HH) return;
    int isbf = *flagp;
    int node = i >> 7, f = i & 127;
    out[i] = loadf(emb, (size_t)ids[node] * HH + f, isbf);
}
// flow_x [N,97] (flag dtype) -> bf16 padded [N,128]; 8 output cols per thread
__global__ void k_pad_cast(const void* x, unsigned short* o, const int* flagp){
    int i = blockIdx.x * 256 + threadIdx.x;           // 0 .. N_FLOWN*16
    if (i >= N_FLOWN * 16) return;
    int isbf = *flagp;
    int row = i >> 4, c0 = (i & 15) * 8;
    unsigned short v[8];
    #pragma unroll
    for (int j = 0; j < 8; ++j) {
        int c = c0 + j;
        v[j] = (c < FIN) ? f2bf(loadf(x, (size_t)row * FIN + c, isbf)) : (unsigned short)0;
    }
    uint4 ov;
    ov.x = (unsigned)v[0] | ((unsigned)v[1] << 16);
    ov.y = (unsigned)v[2] | ((unsigned)v[3] << 16);
    ov.z = (unsigned)v[4] | ((unsigned)v[5] << 16);
    ov.w = (unsigned)v[6] | ((unsigned)v[7] << 16);
    *(uint4*)(o + (size_t)row * 128 + c0) = ov;
}

// ---------------- one-shot weight prep (833 blocks, region dispatch) ----------------
__global__ __launch_bounds__(256) void k_wprep_all(
    const void* Wr0_h2f, const void* br0_h2f, const void* Wo0_h2f,
    const void* Wr0_f2h, const void* br0_f2h, const void* Wo0_f2h,
    const void* Wr0_rel, const void* br0_rel, const void* Wo0_rel,
    const void* Wr_all, const void* br_all, const void* Wo_all,
    unsigned short* WBT0, unsigned short* WBT1, unsigned short* WBT2,
    float* w_h2f0, float* w_h2f1, float* w_h2f2,
    float* w_f2h0, float* w_f2h1, float* w_of2h0, float* w_of2h1,
    float* b_comb0, float* b_comb1, float* b_comb2, float* b_f2h0, float* b_f2h1,
    const int* flagp)
{
    const int bb = blockIdx.x, t = threadIdx.x;
    const int isbf = *flagp;
    if (bb < 384) {
        int layer = bb >> 7;
        int i = ((bb & 127) << 8) + t;   // 0..32767
        int nn = i >> 7, k = i & 127;
        float v = 0.f;
        if (layer == 0) {
            if (k < FIN) {
                if (nn < 128) v = loadf(Wo0_h2f, (size_t)k*128+nn, isbf) + loadf(Wo0_rel, (size_t)k*128+nn, isbf);
                else          v = loadf(Wr0_rel, (size_t)k*128+(nn-128), isbf);
            }
        } else {
            size_t oW = (size_t)((layer - 1) * 3) * 16384;
            if (nn < 128) v = loadf(Wo_all, oW + (size_t)k*128+nn, isbf)
                            + loadf(Wo_all, oW + 2*16384 + (size_t)k*128+nn, isbf);
            else          v = loadf(Wr_all, oW + 2*16384 + (size_t)k*128+(nn-128), isbf);
        }
        unsigned short* W = (layer == 0) ? WBT0 : ((layer == 1) ? WBT1 : WBT2);
        W[(size_t)nn*128 + k] = f2bf(v);
    } else if (bb < 576) {
        int r = bb - 384; int layer = r >> 6; int i = ((r & 63) << 8) + t;
        float v;
        if (layer == 0) v = loadf(Wr0_h2f, (size_t)i, isbf);
        else            v = loadf(Wr_all, (size_t)((layer-1)*3)*16384 + i, isbf);
        ((layer == 0) ? w_h2f0 : ((layer == 1) ? w_h2f1 : w_h2f2))[i] = v;
    } else if (bb < 640) {
        // w_f2h0 padded to [128][128]: rows k>=97 zero
        int i = ((bb - 576) << 8) + t;
        int k = i >> 7;
        w_f2h0[i] = (k < FIN) ? loadf(Wr0_f2h, (size_t)i, isbf) : 0.f;
    } else if (bb < 704) {
        int i = ((bb - 640) << 8) + t;
        w_f2h1[i] = loadf(Wr_all, (size_t)1*16384 + i, isbf);
    } else if (bb < 768) {
        int i = ((bb - 704) << 8) + t;
        w_of2h0[i] = loadf(Wo0_f2h, (size_t)i, isbf);
    } else if (bb < 832) {
        int i = ((bb - 768) << 8) + t;
        w_of2h1[i] = loadf(Wo_all, (size_t)1*16384 + i, isbf);
    } else {
        if (t < 128) {
            b_comb0[t] = loadf(br0_h2f, t, isbf) + loadf(br0_rel, t, isbf);
            b_comb1[t] = loadf(br_all, 0*128 + t, isbf) + loadf(br_all, 2*128 + t, isbf);
            b_comb2[t] = loadf(br_all, 3*128 + t, isbf) + loadf(br_all, 5*128 + t, isbf);
            b_f2h0[t]  = loadf(br0_f2h, t, isbf);
            b_f2h1[t]  = loadf(br_all, 1*128 + t, isbf);
        }
    }
}

// ---------------- CSR build (combined flow CSR + f2h CSR) ----------------
__global__ void k_zero2(int* c0, int* c1){
    int bb = blockIdx.x, t = threadIdx.x;
    if (bb < NB_CMB_N) { int i = bb * 256 + t; if (i < N_FLOWN) c0[i] = 0; }
    else               { int i = (bb - NB_CMB_N) * 256 + t; if (i < N_HOSTN) c1[i] = 0; }
}
// rel and h2f edges both count into c_cmb; f2h into c_f2h.
// The atomicAdd return value (edge's rank within its dst) is captured -- it is
// free at HW level and lets the placement kernel run WITHOUT atomics.
__global__ void k_hist3(const int* drel, const int* dh2f, const int* df2h,
                        int* c_cmb, int* c_f2h,
                        int* rk_rel, int* rk_h2f, int* rk_f2h){
    int bb = blockIdx.x, t = threadIdx.x;
    const int* dst; int* cnt; int* rk; int E; int base;
    if (bb < NB_REL_E)                   { dst = drel; cnt = c_cmb; rk = rk_rel; E = E_RELN; base = bb; }
    else if (bb < NB_REL_E + NB_HF_E)    { dst = dh2f; cnt = c_cmb; rk = rk_h2f; E = E_HFN;  base = bb - NB_REL_E; }
    else                                 { dst = df2h; cnt = c_f2h; rk = rk_f2h; E = E_HFN;  base = bb - NB_REL_E - NB_HF_E; }
    int e = base * 256 + t;
    if (e < E) rk[e] = atomicAdd(&cnt[dst[e]], 1);
}
__global__ __launch_bounds__(256) void k_scan1_2(
    const int* c0, int* rp0, int* bs0,
    const int* c1, int* rp1, int* bs1)
{
    __shared__ int s[256];
    int bb = blockIdx.x, t = threadIdx.x;
    const int* cnt; int* rp; int* bsum; int n; int base;
    if (bb < NB_CMB_N) { cnt = c0; rp = rp0; bsum = bs0; n = N_FLOWN; base = bb; }
    else               { cnt = c1; rp = rp1; bsum = bs1; n = N_HOSTN; base = bb - NB_CMB_N; }
    int i = base * 256 + t;
    int v = (i < n) ? cnt[i] : 0;
    s[t] = v; __syncthreads();
    for (int off = 1; off < 256; off <<= 1) {
        int x = (t >= off) ? s[t - off] : 0;
        __syncthreads();
        s[t] += x;
        __syncthreads();
    }
    if (i < n) rp[i] = s[t] - v;
    if (t == 255) bsum[base] = s[255];
}
__global__ __launch_bounds__(256) void k_scan2_2(int* bs0, int* bs1){
    __shared__ int s[256];
    __shared__ int carry;
    int t = threadIdx.x;
    int* bsum; int nb;
    if (blockIdx.x == 0) { bsum = bs0; nb = NB_CMB_N; }
    else                 { bsum = bs1; nb = NB_F2H_N; }
    if (t == 0) carry = 0;
    __syncthreads();
    for (int base = 0; base < nb; base += 256) {
        int i = base + t;
        int v = (i < nb) ? bsum[i] : 0;
        s[t] = v; __syncthreads();
        for (int off = 1; off < 256; off <<= 1) {
            int x = (t >= off) ? s[t - off] : 0;
            __syncthreads();
            s[t] += x;
            __syncthreads();
        }
        int excl = s[t] - v + carry;
        if (i < nb) bsum[i] = excl;
        __syncthreads();
        if (t == 255) carry += s[255];
        __syncthreads();
    }
}
__global__ void k_scan3_2(int* rp0, const int* bs0,
                          int* rp1, const int* bs1)
{
    int bb = blockIdx.x, t = threadIdx.x;
    int* rp; const int* bsum; int n, E, base;
    if (bb < NB_CMB_N) { rp = rp0; bsum = bs0; n = N_FLOWN; E = E_CMBN; base = bb; }
    else               { rp = rp1; bsum = bs1; n = N_HOSTN; E = E_HFN;  base = bb - NB_CMB_N; }
    int i = base * 256 + t;
    if (i < n) rp[i] += bsum[base];
    if (i == 0) rp[n] = E;
}
// rank-based placement: pos = rp[dst] + rank (precomputed in hist) -- NO atomics,
// no class replication. Reads everything once; 2-load dependent chain only.
// h2f srcs get +N_FLOWN so the gather reads host rows appended in ZALL.
__global__ __launch_bounds__(256) void k_place3(
    const int* s0, const int* d0, const int* r0,
    const int* s1, const int* d1, const int* r1,
    const int* s2, const int* d2, const int* r2,
    const int* rp_cmb, const int* rp_f2h,
    int* e_cmb, int* e_f2h)
{
    const int bb = blockIdx.x;
    const int *src, *dst, *rank, *rp; int* ei; int E, base, soff;
    if (bb < PB_REL)             { src=s0; dst=d0; rank=r0; rp=rp_cmb; ei=e_cmb; E=E_RELN; base=bb;               soff=0; }
    else if (bb < PB_REL+PB_HF)  { src=s1; dst=d1; rank=r1; rp=rp_cmb; ei=e_cmb; E=E_HFN;  base=bb-PB_REL;        soff=N_FLOWN; }
    else                         { src=s2; dst=d2; rank=r2; rp=rp_f2h; ei=e_f2h; E=E_HFN;  base=bb-PB_REL-PB_HF;  soff=0; }
    const int t = threadIdx.x;
    #pragma unroll
    for (int i = 0; i < 4; ++i) {
        const int e = base * 1024 + i * 256 + t;
        if (e < E) {
            const int d = dst[e];
            ei[rp[d] + rank[e]] = src[e] + soff;
        }
    }
}

// ---------------- host-sized VALU GEMM: Y[M,128] (+)= X[M,K]@W[K,128]+b ---------
__global__ __launch_bounds__(256) void k_gemm128(
    const void* X, int xmode, const float* W, const float* bias,
    void* Y, int ybf, int M, int K, int accum, int dorelu, const int* flagp)
{
    const int isbf = (xmode == 2) ? *flagp : xmode;
    const int tid  = threadIdx.x;
    const int row0 = blockIdx.x * 16;
    __shared__ float sX[16][132];
    if (!isbf && (K & 3) == 0) {
        // vectorized f32 staging (all current call sites)
        const int kq = K >> 2;
        for (int i = tid; i < 16 * kq; i += 256) {
            int r = i / kq, c4 = (i - r * kq) * 4;
            int gr = row0 + r;
            float4 v = {0.f, 0.f, 0.f, 0.f};
            if (gr < M) v = *(const float4*)((const float*)X + (size_t)gr * K + c4);
            *(float4*)&sX[r][c4] = v;
        }
    } else {
        const int total = 16 * K;
        for (int i = tid; i < total; i += 256) {
            int r = i / K, c = i - r * K;
            int gr = row0 + r;
            sX[r][c] = (gr < M) ? loadf(X, (size_t)gr * K + c, isbf) : 0.f;
        }
    }
    __syncthreads();

    const int c4 = (tid & 31) * 4;
    const int rb = tid >> 5;
    float a0x=0,a0y=0,a0z=0,a0w=0, a1x=0,a1y=0,a1z=0,a1w=0;
    #pragma unroll 4
    for (int k = 0; k < K; ++k) {
        const float4 w = *(const float4*)(W + (size_t)k * 128 + c4);
        const float x0 = sX[rb][k];
        const float x1 = sX[rb + 8][k];
        a0x = fmaf(x0, w.x, a0x); a0y = fmaf(x0, w.y, a0y);
        a0z = fmaf(x0, w.z, a0z); a0w = fmaf(x0, w.w, a0w);
        a1x = fmaf(x1, w.x, a1x); a1y = fmaf(x1, w.y, a1y);
        a1z = fmaf(x1, w.z, a1z); a1w = fmaf(x1, w.w, a1w);
    }
    float bx=0, by=0, bz=0, bw=0;
    if (bias) { const float4 b = *(const float4*)(bias + c4); bx=b.x; by=b.y; bz=b.z; bw=b.w; }

    #pragma unroll
    for (int h = 0; h < 2; ++h) {
        const int rr = row0 + rb + (h ? 8 : 0);
        if (rr >= M) continue;
        float v0 = (h?a1x:a0x)+bx, v1 = (h?a1y:a0y)+by;
        float v2 = (h?a1z:a0z)+bz, v3 = (h?a1w:a0w)+bw;
        if (ybf) {
            unsigned short* p = (unsigned short*)Y + (size_t)rr * 128 + c4;
            ushort4 o; o.x=f2bf(v0); o.y=f2bf(v1); o.z=f2bf(v2); o.w=f2bf(v3);
            *(ushort4*)p = o;
        } else {
            float* p = (float*)Y + (size_t)rr * 128 + c4;
            if (accum) { v0+=p[0]; v1+=p[1]; v2+=p[2]; v3+=p[3]; }
            if (dorelu) { v0=fmaxf(v0,0.f); v1=fmaxf(v1,0.f); v2=fmaxf(v2,0.f); v3=fmaxf(v3,0.f); }
            float4 o; o.x=v0; o.y=v1; o.z=v2; o.w=v3;
            *(float4*)p = o;
        }
    }
}

// ---------------- fused dual-input host GEMM: Y = relu(X1@W1 + X2@W2 + b) ------
__global__ __launch_bounds__(256) void k_gemm2in(
    const float* __restrict__ X1, const float* __restrict__ X2,
    const float* __restrict__ W1, const float* __restrict__ W2,
    const float* __restrict__ bias, float* __restrict__ Y, int M)
{
    const int tid  = threadIdx.x;
    const int row0 = blockIdx.x * 16;
    __shared__ float sX1[16][132];
    __shared__ float sX2[16][132];
    for (int i = tid; i < 16 * 32; i += 256) {
        int r = i >> 5, c4 = (i & 31) * 4;
        int gr = row0 + r;
        float4 v1 = {0.f, 0.f, 0.f, 0.f}, v2 = {0.f, 0.f, 0.f, 0.f};
        if (gr < M) {
            v1 = *(const float4*)(X1 + (size_t)gr * 128 + c4);
            v2 = *(const float4*)(X2 + (size_t)gr * 128 + c4);
        }
        *(float4*)&sX1[r][c4] = v1;
        *(float4*)&sX2[r][c4] = v2;
    }
    __syncthreads();

    const int c4 = (tid & 31) * 4;
    const int rb = tid >> 5;
    float a0x=0,a0y=0,a0z=0,a0w=0, a1x=0,a1y=0,a1z=0,a1w=0;
    #pragma unroll 4
    for (int k = 0; k < 128; ++k) {
        const float4 w = *(const float4*)(W1 + (size_t)k * 128 + c4);
        const float x0 = sX1[rb][k];
        const float x1 = sX1[rb + 8][k];
        a0x = fmaf(x0, w.x, a0x); a0y = fmaf(x0, w.y, a0y);
        a0z = fmaf(x0, w.z, a0z); a0w = fmaf(x0, w.w, a0w);
        a1x = fmaf(x1, w.x, a1x); a1y = fmaf(x1, w.y, a1y);
        a1z = fmaf(x1, w.z, a1z); a1w = fmaf(x1, w.w, a1w);
    }
    #pragma unroll 4
    for (int k = 0; k < 128; ++k) {
        const float4 w = *(const float4*)(W2 + (size_t)k * 128 + c4);
        const float x0 = sX2[rb][k];
        const float x1 = sX2[rb + 8][k];
        a0x = fmaf(x0, w.x, a0x); a0y = fmaf(x0, w.y, a0y);
        a0z = fmaf(x0, w.z, a0z); a0w = fmaf(x0, w.w, a0w);
        a1x = fmaf(x1, w.x, a1x); a1y = fmaf(x1, w.y, a1y);
        a1z = fmaf(x1, w.z, a1z); a1w = fmaf(x1, w.w, a1w);
    }
    const float4 b = *(const float4*)(bias + c4);
    #pragma unroll
    for (int h = 0; h < 2; ++h) {
        const int rr = row0 + rb + (h ? 8 : 0);
        if (rr >= M) continue;
        float4 o;
        o.x = fmaxf((h?a1x:a0x) + b.x, 0.f);
        o.y = fmaxf((h?a1y:a0y) + b.y, 0.f);
        o.z = fmaxf((h?a1z:a0z) + b.z, 0.f);
        o.w = fmaxf((h?a1w:a0w) + b.w, 0.f);
        *(float4*)(Y + (size_t)rr * 128 + c4) = o;
    }
}

// ---------------- MFMA dual flow GEMM: both outputs bf16, no bias ----------------
// All global traffic linearized: A staged once per block into XOR-swizzled LDS
// via linear uint4 loads; output bounced through LDS and stored with linear
// uint4 stores. 8 waves x 32 WBT rows (B = 8 bfrags in regs), LB(512,4).
typedef __attribute__((ext_vector_type(8))) short bfrag;
typedef __attribute__((ext_vector_type(4))) float f32x4;

#define GEMM_CHUNKS 4
#define GEMM_MROWS  (32 * GEMM_CHUNKS)   // 128 rows per block

__global__ __launch_bounds__(512, 4) void k_gemm_mfma(
    const unsigned short* __restrict__ Abf, const unsigned short* __restrict__ WBT,
    unsigned short* __restrict__ Y1, unsigned short* __restrict__ Y2, int M)
{
    __shared__ unsigned short sA[32 * 128];      // 8 KB, XOR-swizzled 16B units
    __shared__ unsigned short sO[2][32][136];    // 17.4 KB out-stage (pad 8 shorts)

    const int tid  = threadIdx.x;
    const int wave = tid >> 6;        // 0..7
    const int lane = tid & 63;
    const int quad = lane >> 4;
    const int l16  = lane & 15;
    const int nbase = wave * 32;      // 32 WBT rows per wave

    // B slice for this wave's 32 output cols: breg[c][j] (8 bfrags = 32 regs)
    bfrag breg[4][2];
    #pragma unroll
    for (int c = 0; c < 4; ++c)
        #pragma unroll
        for (int j = 0; j < 2; ++j)
            breg[c][j] = *(const bfrag*)(WBT + (size_t)(nbase + j * 16 + l16) * 128
                                              + c * 32 + quad * 8);

    const int ybuf = (nbase < 128) ? 0 : 1;
    const int colb = nbase & 127;
    const f32x4 zero = {0.f, 0.f, 0.f, 0.f};

    const int srow = tid >> 4;        // staging row 0..31
    const int su   = tid & 15;        // staging 16B unit 0..15

    for (int chunk = 0; chunk < GEMM_CHUNKS; ++chunk) {
        const int m0 = blockIdx.x * GEMM_MROWS + chunk * 32;
        if (m0 >= M) break;           // block-uniform (M % 32 == 0)

        // ---- stage A chunk (32x128 bf16 = 8KB): linear load, swizzled LDS ----
        {
            const uint4* gsrc = (const uint4*)(Abf + (size_t)m0 * 128);
            uint4* sdst = (uint4*)sA;
            sdst[srow * 16 + (su ^ (srow & 15))] = gsrc[tid];
        }
        __syncthreads();

        // ---- fragments from LDS + MFMA ----
        bfrag a0[4], a1[4];
        #pragma unroll
        for (int c = 0; c < 4; ++c) {
            const int un = (c * 4 + quad) ^ l16;
            a0[c] = *(const bfrag*)(sA + (size_t)(l16)      * 128 + un * 8);
            a1[c] = *(const bfrag*)(sA + (size_t)(16 + l16) * 128 + un * 8);
        }
        f32x4 acc[2][2];
        #pragma unroll
        for (int j = 0; j < 2; ++j) {
            acc[0][j] = __builtin_amdgcn_mfma_f32_16x16x32_bf16(breg[0][j], a0[0], zero, 0, 0, 0);
            acc[1][j] = __builtin_amdgcn_mfma_f32_16x16x32_bf16(breg[0][j], a1[0], zero, 0, 0, 0);
        }
        #pragma unroll
        for (int c = 1; c < 4; ++c)
            #pragma unroll
            for (int j = 0; j < 2; ++j) {
                acc[0][j] = __builtin_amdgcn_mfma_f32_16x16x32_bf16(breg[c][j], a0[c], acc[0][j], 0, 0, 0);
                acc[1][j] = __builtin_amdgcn_mfma_f32_16x16x32_bf16(breg[c][j], a1[c], acc[1][j], 0, 0, 0);
            }

        // ---- stage D' to LDS (D' layout: col(l16)=row m, row(quad*4+r)=col n) ----
        #pragma unroll
        for (int i = 0; i < 2; ++i) {
            const int row = i * 16 + l16;
            #pragma unroll
            for (int j = 0; j < 2; ++j) {
                const int col = colb + j * 16 + quad * 4;
                uint2 o;
                o.x = (unsigned)f2bf(acc[i][j][0]) | ((unsigned)f2bf(acc[i][j][1]) << 16);
                o.y = (unsigned)f2bf(acc[i][j][2]) | ((unsigned)f2bf(acc[i][j][3]) << 16);
                *(uint2*)&sO[ybuf][row][col] = o;
            }
        }
        __syncthreads();

        // ---- linear coalesced stores: 1KB-contiguous per wave instruction ----
        {
            const size_t goff = (size_t)(m0 + srow) * 128 + su * 8;
            *(uint4*)(Y1 + goff) = *(const uint4*)&sO[0][srow][su * 8];
            *(uint4*)(Y2 + goff) = *(const uint4*)&sO[1][srow][su * 8];
        }
        __syncthreads();
    }
}

// ---------------- persistent-wave combined CSR aggregation (flow dsts) ----------
// QUARTER-PER-DST: each 16-lane quarter owns one dst entirely (16 lanes x 8
// features = 128). Per outer iteration the wave processes 4 CONSECUTIVE dsts in
// parallel: no cross-quarter reduce, epilogue amortized 4x, root loads / stores
// are 4 consecutive rows = 1 KiB contiguous per instruction.
// Edge-index window staged to LDS once per wave (contiguous CSR range).
__global__ __launch_bounds__(256) void k_agg_flow(
    const unsigned short* __restrict__ Z,
    const int* __restrict__ rp, const int* __restrict__ ei,
    const unsigned short* __restrict__ root, const float* __restrict__ bias,
    unsigned short* __restrict__ Xout, int do_relu)
{
    __shared__ int sIdx[4][AGG_CAP];
    const int wave = threadIdx.x >> 6;
    const int lane = threadIdx.x & 63;
    const int q    = lane >> 4;
    const int l16  = lane & 15;
    const int f8   = l16 * 8;
    const int gw   = blockIdx.x * 4 + wave;
    const int d0   = gw * AGGF_DPW;
    const int nd   = min(AGGF_DPW, N_FLOWN - d0);   // may be <= 0 for tail waves

    int rpv = 0, W0 = 0, Wcap = 0;
    if (nd > 0) {
        rpv = (lane <= nd) ? rp[d0 + lane] : 0;
        W0 = __shfl(rpv, 0, 64);
        const int Wn = __shfl(rpv, nd, 64);
        const int cw = min(Wn - W0, AGG_CAP);
        for (int i = lane; i < cw; i += 64) sIdx[wave][i] = ei[W0 + i];
        Wcap = W0 + cw;
    }
    __syncthreads();
    if (nd <= 0) return;

    // loop-invariant bias slice
    const float4 bva = *(const float4*)(bias + f8);
    const float4 bvb = *(const float4*)(bias + f8 + 4);

    #pragma unroll 2
    for (int i = 0; i < AGGF_DPW / 4; ++i) {
        const int dqi = i * 4 + q;              // this quarter's dst offset
        const bool act = dqi < nd;
        const int srcl = act ? dqi : 0;
        const int b0 = __shfl(rpv, srcl, 64);
        const int b1 = __shfl(rpv, srcl + 1, 64);
        const int d  = d0 + dqi;

        uint4 rv = {0, 0, 0, 0};
        if (act) rv = *(const uint4*)(root + (size_t)d * 128 + f8);

        float a[8] = {0.f, 0.f, 0.f, 0.f, 0.f, 0.f, 0.f, 0.f};
        int n = act ? (b1 - b0) : 0;
        int e = b0;
        while (n >= 4) {
            const int s0 = (e     < Wcap) ? sIdx[wave][e     - W0] : ei[e];
            const int s1 = (e + 1 < Wcap) ? sIdx[wave][e + 1 - W0] : ei[e + 1];
            const int s2 = (e + 2 < Wcap) ? sIdx[wave][e + 2 - W0] : ei[e + 2];
            const int s3 = (e + 3 < Wcap) ? sIdx[wave][e + 3 - W0] : ei[e + 3];
            const uint4 z0 = *(const uint4*)(Z + (size_t)s0 * 128 + f8);
            const uint4 z1 = *(const uint4*)(Z + (size_t)s1 * 128 + f8);
            const uint4 z2 = *(const uint4*)(Z + (size_t)s2 * 128 + f8);
            const uint4 z3 = *(const uint4*)(Z + (size_t)s3 * 128 + f8);
            acc8(a, z0); acc8(a, z1); acc8(a, z2); acc8(a, z3);
            e += 4; n -= 4;
        }
        if (n & 2) {
            const int s0 = (e     < Wcap) ? sIdx[wave][e     - W0] : ei[e];
            const int s1 = (e + 1 < Wcap) ? sIdx[wave][e + 1 - W0] : ei[e + 1];
            const uint4 z0 = *(const uint4*)(Z + (size_t)s0 * 128 + f8);
            const uint4 z1 = *(const uint4*)(Z + (size_t)s1 * 128 + f8);
            acc8(a, z0); acc8(a, z1);
            e += 2;
        }
        if (n & 1) {
            const int s0 = (e < Wcap) ? sIdx[wave][e - W0] : ei[e];
            const uint4 z0 = *(const uint4*)(Z + (size_t)s0 * 128 + f8);
            acc8(a, z0);
        }

        if (act) {
            float v0 = a[0] + __uint_as_float(rv.x << 16)         + bva.x;
            float v1 = a[1] + __uint_as_float(rv.x & 0xFFFF0000u) + bva.y;
            float v2 = a[2] + __uint_as_float(rv.y << 16)         + bva.z;
            float v3 = a[3] + __uint_as_float(rv.y & 0xFFFF0000u) + bva.w;
            float v4 = a[4] + __uint_as_float(rv.z << 16)         + bvb.x;
            float v5 = a[5] + __uint_as_float(rv.z & 0xFFFF0000u) + bvb.y;
            float v6 = a[6] + __uint_as_float(rv.w << 16)         + bvb.z;
            float v7 = a[7] + __uint_as_float(rv.w & 0xFFFF0000u) + bvb.w;
            if (do_relu) {
                v0 = fmaxf(v0, 0.f); v1 = fmaxf(v1, 0.f); v2 = fmaxf(v2, 0.f); v3 = fmaxf(v3, 0.f);
                v4 = fmaxf(v4, 0.f); v5 = fmaxf(v5, 0.f); v6 = fmaxf(v6, 0.f); v7 = fmaxf(v7, 0.f);
            }
            uint4 o;
            o.x = (unsigned)f2bf(v0) | ((unsigned)f2bf(v1) << 16);
            o.y = (unsigned)f2bf(v2) | ((unsigned)f2bf(v3) << 16);
            o.z = (unsigned)f2bf(v4) | ((unsigned)f2bf(v5) << 16);
            o.w = (unsigned)f2bf(v6) | ((unsigned)f2bf(v7) << 16);
            *(uint4*)(Xout + (size_t)d * 128 + f8) = o;
        }
    }
}

// host dst: out[d][0:128] = sum f2h Z[src][0:128]  (f32 out)
// Same quarter-per-dst persistent structure.
__global__ __launch_bounds__(256) void k_agg_host(
    const unsigned short* __restrict__ Z, const int* __restrict__ rp,
    const int* __restrict__ ei, float* __restrict__ out)
{
    __shared__ int sIdx[4][AGG_CAP];
    const int wave = threadIdx.x >> 6;
    const int lane = threadIdx.x & 63;
    const int q    = lane >> 4;
    const int l16  = lane & 15;
    const int f8   = l16 * 8;
    const int gw   = blockIdx.x * 4 + wave;
    const int d0   = gw * AGGH_DPW;
    const int nd   = min(AGGH_DPW, N_HOSTN - d0);

    int rpv = 0, W0 = 0, Wcap = 0;
    if (nd > 0) {
        rpv = (lane <= nd) ? rp[d0 + lane] : 0;
        W0 = __shfl(rpv, 0, 64);
        const int Wn = __shfl(rpv, nd, 64);
        const int cw = min(Wn - W0, AGG_CAP);
        for (int i = lane; i < cw; i += 64) sIdx[wave][i] = ei[W0 + i];
        Wcap = W0 + cw;
    }
    __syncthreads();
    if (nd <= 0) return;

    #pragma unroll
    for (int i = 0; i < AGGH_DPW / 4; ++i) {
        const int dqi = i * 4 + q;
        const bool act = dqi < nd;
        const int srcl = act ? dqi : 0;
        const int b0 = __shfl(rpv, srcl, 64);
        const int b1 = __shfl(rpv, srcl + 1, 64);
        const int d  = d0 + dqi;

        float a[8] = {0.f, 0.f, 0.f, 0.f, 0.f, 0.f, 0.f, 0.f};
        int n = act ? (b1 - b0) : 0;
        int e = b0;
        while (n >= 4) {
            const int s0 = (e     < Wcap) ? sIdx[wave][e     - W0] : ei[e];
            const int s1 = (e + 1 < Wcap) ? sIdx[wave][e + 1 - W0] : ei[e + 1];
            const int s2 = (e + 2 < Wcap) ? sIdx[wave][e + 2 - W0] : ei[e + 2];
            const int s3 = (e + 3 < Wcap) ? sIdx[wave][e + 3 - W0] : ei[e + 3];
            const uint4 z0 = *(const uint4*)(Z + (size_t)s0 * 128 + f8);
            const uint4 z1 = *(const uint4*)(Z + (size_t)s1 * 128 + f8);
            const uint4 z2 = *(const uint4*)(Z + (size_t)s2 * 128 + f8);
            const uint4 z3 = *(const uint4*)(Z + (size_t)s3 * 128 + f8);
            acc8(a, z0); acc8(a, z1); acc8(a, z2); acc8(a, z3);
            e += 4; n -= 4;
        }
        if (n & 2) {
            const int s0 = (e     < Wcap) ? sIdx[wave][e     - W0] : ei[e];
            const int s1 = (e + 1 < Wcap) ? sIdx[wave][e + 1 - W0] : ei[e + 1];
            const uint4 z0 = *(const uint4*)(Z + (size_t)s0 * 128 + f8);
            const uint4 z1 = *(const uint4*)(Z + (size_t)s1 * 128 + f8);
            acc8(a, z0); acc8(a, z1);
            e += 2;
        }
        if (n & 1) {
            const int s0 = (e < Wcap) ? sIdx[wave][e - W0] : ei[e];
            const uint4 z0 = *(const uint4*)(Z + (size_t)s0 * 128 + f8);
            acc8(a, z0);
        }

        if (act) {
            float4 oa, ob;
            oa.x = a[0]; oa.y = a[1]; oa.z = a[2]; oa.w = a[3];
            ob.x = a[4]; ob.y = a[5]; ob.z = a[6]; ob.w = a[7];
            *(float4*)(out + (size_t)d * 128 + f8)     = oa;
            *(float4*)(out + (size_t)d * 128 + f8 + 4) = ob;
        }
    }
}

// ---------------- pooling over sorted batch (bf16 input) ----------------
#define PCHUNK 128
__global__ __launch_bounds__(128) void k_pool2(const unsigned short* xf, const int* batch,
                                               unsigned* bits){
    const int t = threadIdx.x;
    const int i0 = blockIdx.x * PCHUNK;
    const int iend = min(i0 + PCHUNK, N_FLOWN);
    if (i0 >= N_FLOWN) return;
    float cur = -3.4e38f;
    int curg = batch[i0];
    for (int i = i0; i < iend; ++i) {
        int g = batch[i];
        if (g != curg) {
            unsigned u = __float_as_uint(cur);
            unsigned ord = (u & 0x80000000u) ? ~u : (u | 0x80000000u);
            atomicMax(&bits[(size_t)curg * 128 + t], ord);
            cur = -3.4e38f; curg = g;
        }
        cur = fmaxf(cur, bf2f(xf[(size_t)i * 128 + t]));
    }
    unsigned u = __float_as_uint(cur);
    unsigned ord = (u & 0x80000000u) ? ~u : (u | 0x80000000u);
    atomicMax(&bits[(size_t)curg * 128 + t], ord);
}

// ---------------- classifier ----------------
__global__ __launch_bounds__(128) void k_classifier(
    const unsigned* bits,
    const void* Wc1, const void* bc1, const void* Wc2, const void* bc2,
    const void* Wc3, const void* bc3, void* out, const int* flagp)
{
    const int g = blockIdx.x, t = threadIdx.x;
    const int isbf = *flagp;
    __shared__ float sp[128], sh1[64], sh2[128];
    {
        unsigned ord = bits[(size_t)g * HH + t];
        unsigned u = (ord & 0x80000000u) ? (ord & 0x7FFFFFFFu) : ~ord;
        sp[t] = __uint_as_float(u);
    }
    __syncthreads();
    if (t < 64) {
        float a = loadf(bc1, t, isbf);
        #pragma unroll 4
        for (int k = 0; k < 128; ++k) a = fmaf(sp[k], loadf(Wc1, k * 64 + t, isbf), a);
        sh1[t] = fmaxf(a, 0.f);
    }
    __syncthreads();
    {
        float a = loadf(bc2, t, isbf);
        #pragma unroll 4
        for (int k = 0; k < 64; ++k) a = fmaf(sh1[k], loadf(Wc2, k * 128 + t, isbf), a);
        sh2[t] = fmaxf(a, 0.f);
    }
    __syncthreads();
    if (t < NCN) {
        float a = loadf(bc3, t, isbf);
        #pragma unroll 4
        for (int k = 0; k < 128; ++k) a = fmaf(sh2[k], loadf(Wc3, k * NCN + t, isbf), a);
        if (isbf) ((unsigned short*)out)[(size_t)g * NCN + t] = f2bf(a);
        else      ((float*)out)[(size_t)g * NCN + t] = a;
    }
}

extern "C" void kernel_launch(void* const* d_in, const int* in_sizes, int n_in,
                              void* d_out, int out_size, void* d_ws, size_t ws_size,
                              hipStream_t stream)
{
    const int*  host_ids   = (const int*) d_in[0];
    const void* flow_x     = d_in[1];
    const int*  h2f_src    = (const int*) d_in[2];
    const int*  h2f_dst    = (const int*) d_in[3];
    const int*  f2h_src    = (const int*) d_in[4];
    const int*  f2h_dst    = (const int*) d_in[5];
    const int*  rel_src    = (const int*) d_in[6];
    const int*  rel_dst    = (const int*) d_in[7];
    const int*  flow_batch = (const int*) d_in[8];
    const void* host_embed = d_in[9];
    const void* Wr0_h2f = d_in[10]; const void* br0_h2f = d_in[11]; const void* Wo0_h2f = d_in[12];
    const void* Wr0_f2h = d_in[13]; const void* br0_f2h = d_in[14]; const void* Wo0_f2h = d_in[15];
    const void* Wr0_rel = d_in[16]; const void* br0_rel = d_in[17]; const void* Wo0_rel = d_in[18];
    const void* Wr_all  = d_in[19];
    const void* br_all  = d_in[20];
    const void* Wo_all  = d_in[21];
    const void* Wc1 = d_in[22]; const void* bc1 = d_in[23];
    const void* Wc2 = d_in[24]; const void* bc2 = d_in[25];
    const void* Wc3 = d_in[26]; const void* bc3 = d_in[27];

    // -------- workspace (~198 MB; CSR scratch aliased onto HA/HB) --------
    size_t off = 0;
    auto alloc = [&](size_t bytes) -> char* {
        char* p = (char*)d_ws + off;
        off += (bytes + 255) & ~(size_t)255;
        return p;
    };
    unsigned short* F1bf  = (unsigned short*)alloc((size_t)N_FLOWN * HH * 2);  // state
    unsigned short* Froot = (unsigned short*)alloc((size_t)N_FLOWN * HH * 2);  // root term
    // ZALL: flow-transformed rows [0,200k) followed by host-transformed rows [200k,220k)
    unsigned short* ZALL  = (unsigned short*)alloc((size_t)(N_FLOWN + N_HOSTN) * HH * 2);
    unsigned short* F2bf  = ZALL;                                   // z_rel
    unsigned short* HCbf  = ZALL + (size_t)N_FLOWN * HH;            // z_h
    float* HA = (float*)alloc((size_t)N_HOSTN * HH * 4);
    float* HB = (float*)alloc((size_t)N_HOSTN * HH * 4);
    float* HD = (float*)alloc((size_t)N_HOSTN * HH * 4);
    unsigned short* WBT0 = (unsigned short*)alloc(256 * 128 * 2);
    unsigned short* WBT1 = (unsigned short*)alloc(256 * 128 * 2);
    unsigned short* WBT2 = (unsigned short*)alloc(256 * 128 * 2);
    float* w_h2f0  = (float*)alloc(128 * 128 * 4);
    float* w_h2f1  = (float*)alloc(128 * 128 * 4);
    float* w_h2f2  = (float*)alloc(128 * 128 * 4);
    float* w_f2h0  = (float*)alloc(128 * 128 * 4);
    float* w_f2h1  = (float*)alloc(128 * 128 * 4);
    float* w_of2h0 = (float*)alloc(128 * 128 * 4);
    float* w_of2h1 = (float*)alloc(128 * 128 * 4);
    float* b_comb0 = (float*)alloc(128 * 4);
    float* b_comb1 = (float*)alloc(128 * 4);
    float* b_comb2 = (float*)alloc(128 * 4);
    float* b_f2h0  = (float*)alloc(128 * 4);
    float* b_f2h1  = (float*)alloc(128 * 4);
    unsigned* poolbits = (unsigned*)alloc(GG * HH * 4);
    int* flagp = (int*)alloc(256);
    int* rp_cmb = (int*)alloc((N_FLOWN + 1) * 4);
    int* ei_cmb = (int*)alloc((size_t)E_CMBN * 4);
    int* rp_f2h = (int*)alloc((N_HOSTN + 1) * 4);
    int* ei_f2h = (int*)alloc((size_t)E_HFN * 4);
    int* bs0 = (int*)alloc(1024 * 4);
    int* bs2 = (int*)alloc(256 * 4);
    // CSR-build scratch aliased onto buffers first written AFTER the build
    // (stream-ordered): ranks (6.4 MB) live in HA (10.24 MB, first write =
    // k_gather_embed); counters (880 KB) live in HB (first write = k_gemm2in).
    int* rk_rel = (int*)HA;                 // E_RELN ints = 3.2 MB
    int* rk_h2f = rk_rel + E_RELN;          // 1.6 MB
    int* rk_f2h = rk_h2f + E_HFN;           // 1.6 MB  (total 6.4 MB <= 10.24)
    int* c_cmb  = (int*)HB;                 // N_FLOWN ints = 800 KB
    int* c_f2h  = c_cmb + N_FLOWN;          // 80 KB   (total 880 KB <= 10.24 MB)

    const int T = 256;
    #define GRID1(n) dim3(cdiv((long long)(n), T)), dim3(T), 0, stream

    if (off > ws_size) {
        k_flag_us<<<GRID1(out_size)>>>((unsigned short*)d_out, out_size, (unsigned short)0x4000);
        return;
    }

    k_detect<<<dim3(1), dim3(256), 0, stream>>>((const unsigned short*)flow_x, flagp);

    // -------- CSR builds (combined flow CSR + f2h CSR; rank-based placement) --------
    k_zero2 <<<dim3(NB_CMB_N + NB_F2H_N), dim3(256), 0, stream>>>(c_cmb, c_f2h);
    k_hist3 <<<dim3(NB_REL_E + 2*NB_HF_E), dim3(256), 0, stream>>>(rel_dst, h2f_dst, f2h_dst,
                                                                    c_cmb, c_f2h,
                                                                    rk_rel, rk_h2f, rk_f2h);
    k_scan1_2<<<dim3(NB_CMB_N + NB_F2H_N), dim3(256), 0, stream>>>(
        c_cmb, rp_cmb, bs0, c_f2h, rp_f2h, bs2);
    k_scan2_2<<<dim3(2), dim3(256), 0, stream>>>(bs0, bs2);
    k_scan3_2<<<dim3(NB_CMB_N + NB_F2H_N), dim3(256), 0, stream>>>(
        rp_cmb, bs0, rp_f2h, bs2);
    k_place3<<<dim3(PB_ALL), dim3(256), 0, stream>>>(
        rel_src, rel_dst, rk_rel,
        h2f_src, h2f_dst, rk_h2f,
        f2h_src, f2h_dst, rk_f2h,
        rp_cmb, rp_f2h, ei_cmb, ei_f2h);

    // -------- weight prep (1 launch) --------
    k_wprep_all<<<dim3(833), dim3(256), 0, stream>>>(
        Wr0_h2f, br0_h2f, Wo0_h2f, Wr0_f2h, br0_f2h, Wo0_f2h, Wr0_rel, br0_rel, Wo0_rel,
        Wr_all, br_all, Wo_all,
        WBT0, WBT1, WBT2, w_h2f0, w_h2f1, w_h2f2,
        w_f2h0, w_f2h1, w_of2h0, w_of2h1,
        b_comb0, b_comb1, b_comb2, b_f2h0, b_f2h1, flagp);

    // ================= layer 0 =================
    k_gather_embed<<<GRID1(N_HOSTN * HH)>>>(host_ids, host_embed, HA, flagp);
    k_pad_cast<<<GRID1(N_FLOWN * 16)>>>(flow_x, F1bf, flagp);
    // host path: gather bf16 input features (K padded to 128); fused dual GEMM + relu
    k_agg_host<<<dim3(AGGH_BLK), dim3(256), 0, stream>>>(F1bf, rp_f2h, ei_f2h, HD);
    k_gemm2in<<<dim3(cdiv(N_HOSTN,16)), dim3(256), 0, stream>>>(HD, HA, w_f2h0, w_of2h0, b_f2h0, HB, N_HOSTN);
    // flow path
    k_gemm128<<<dim3(cdiv(N_HOSTN,16)), dim3(256), 0, stream>>>(HA, 0, w_h2f0, nullptr, HCbf, 1, N_HOSTN, 128, 0, 0, flagp);
    k_gemm_mfma<<<dim3(cdiv(N_FLOWN, GEMM_MROWS)), dim3(512), 0, stream>>>(F1bf, WBT0, Froot, F2bf, N_FLOWN);
    k_agg_flow<<<dim3(AGGF_BLK), dim3(256), 0, stream>>>(ZALL, rp_cmb, ei_cmb,
                                                         Froot, b_comb0, F1bf, 1);

    // ================= stacked layer 0 =================
    k_agg_host<<<dim3(AGGH_BLK), dim3(256), 0, stream>>>(F1bf, rp_f2h, ei_f2h, HD);
    k_gemm128<<<dim3(cdiv(N_HOSTN,16)), dim3(256), 0, stream>>>(HB, 0, w_h2f1, nullptr, HCbf, 1, N_HOSTN, 128, 0, 0, flagp);
    k_gemm_mfma<<<dim3(cdiv(N_FLOWN, GEMM_MROWS)), dim3(512), 0, stream>>>(F1bf, WBT1, Froot, F2bf, N_FLOWN);
    k_agg_flow<<<dim3(AGGF_BLK), dim3(256), 0, stream>>>(ZALL, rp_cmb, ei_cmb,
                                                         Froot, b_comb1, F1bf, 1);
    k_gemm2in<<<dim3(cdiv(N_HOSTN,16)), dim3(256), 0, stream>>>(HD, HB, w_f2h1, w_of2h1, b_f2h1, HA, N_HOSTN);

    // ================= stacked layer 1 (last; no host update, no relu) =================
    k_gemm128<<<dim3(cdiv(N_HOSTN,16)), dim3(256), 0, stream>>>(HA, 0, w_h2f2, nullptr, HCbf, 1, N_HOSTN, 128, 0, 0, flagp);
    k_gemm_mfma<<<dim3(cdiv(N_FLOWN, GEMM_MROWS)), dim3(512), 0, stream>>>(F1bf, WBT2, Froot, F2bf, N_FLOWN);
    k_agg_flow<<<dim3(AGGF_BLK), dim3(256), 0, stream>>>(ZALL, rp_cmb, ei_cmb,
                                                         Froot, b_comb2, F1bf, 0);

    // ================= pool + classifier =================
    k_zero<<<GRID1(GG * HH)>>>((float*)poolbits, (size_t)GG * HH);
    k_pool2<<<dim3(cdiv(N_FLOWN, PCHUNK)), dim3(128), 0, stream>>>(F1bf, flow_batch, poolbits);
    k_classifier<<<dim3(GG), dim3(128), 0, stream>>>(poolbits, Wc1, bc1, Wc2, bc2, Wc3, bc3,
                                                     d_out, flagp);
    #undef GRID1
}

// Round 10
// 885.263 us; speedup vs baseline: 1.2192x; 1.0330x over previous
//
#include <hip/hip_runtime.h>
#include <hip/hip_bf16.h>

using bf16 = __hip_bfloat16;

#define N_HOSTN 20000
#define N_FLOWN 200000
#define E_HFN   400000
#define E_RELN  800000
#define E_CMBN  1200000  // rel + h2f combined
#define GG      64
#define HH      128
#define FIN     97
#define NCN     10

// binned CSR build geometry (bins of 256 dsts)
#define NBIN_F  782     // ceil(200000/256)
#define NBIN_H  79      // ceil(20000/256)
#define NBIN_ALL (NBIN_F + NBIN_H)   // 861
#define BH_F    128     // flow-edge hist blocks
#define BH_H    32      // f2h hist blocks
#define EPB_F   9375    // 1200000/128
#define EPB_H   12500   // 400000/32

// persistent-wave aggregation geometry (quarter-per-dst)
#define AGG_CAP    768   // staged indices per wave (fallback to global beyond)
#define AGGF_DPW   24    // dsts per wave (multiple of 4)
#define AGGF_BLK   2084  // 2084 blk * 4 waves * 24 = 200064 >= 200000
#define AGGH_DPW   12
#define AGGH_BLK   417   // 417 * 4 * 12 = 20016 >= 20000

static inline int cdiv(long long a, long long b){ return (int)((a + b - 1) / b); }

__device__ __forceinline__ float bf2f(unsigned short u){
    return __uint_as_float(((unsigned)u) << 16);
}
__device__ __forceinline__ unsigned short f2bf(float f){
    unsigned u = __float_as_uint(f);
    unsigned r = u + 0x7FFFu + ((u >> 16) & 1u);   // RNE
    return (unsigned short)(r >> 16);
}
__device__ __forceinline__ float loadf(const void* p, size_t i, int isbf){
    return isbf ? bf2f(((const unsigned short*)p)[i]) : ((const float*)p)[i];
}
// unpack 8 bf16 (uint4) and accumulate into 8 f32
__device__ __forceinline__ void acc8(float* a, uint4 z){
    a[0] += __uint_as_float(z.x << 16);
    a[1] += __uint_as_float(z.x & 0xFFFF0000u);
    a[2] += __uint_as_float(z.y << 16);
    a[3] += __uint_as_float(z.y & 0xFFFF0000u);
    a[4] += __uint_as_float(z.z << 16);
    a[5] += __uint_as_float(z.z & 0xFFFF0000u);
    a[6] += __uint_as_float(z.w << 16);
    a[7] += __uint_as_float(z.w & 0xFFFF0000u);
}

// ---------------- dtype detection ----------------
__global__ void k_detect(const unsigned short* x, int* flag){
    __shared__ int bad;
    if (threadIdx.x == 0) bad = 0;
    __syncthreads();
    int b = 0;
    for (int i = threadIdx.x; i < 4096; i += 256) {
        unsigned e = (x[i] >> 7) & 0xFFu;
        if (e >= 0x90u) b++;
    }
    if (b) atomicAdd(&bad, b);
    __syncthreads();
    if (threadIdx.x == 0) *flag = (bad == 0) ? 1 : 0;   // 1 = bf16, 0 = f32
}

// ---------------- misc ----------------
__global__ void k_zero(float* p, size_t n){
    size_t i = (size_t)blockIdx.x * 256 + threadIdx.x;
    if (i < n) p[i] = 0.f;
}
__global__ void k_flag_us(unsigned short* out, int n, unsigned short val){
    int i = blockIdx.x * 256 + threadIdx.x;
    if (i < n) out[i] = val;
}
__global__ void k_gather_embed(const int* ids, const void* emb, float* out, const int* flagp){
    int i = blockIdx.x * 256 + threadIdx.x;
    if (i >= N_HOSTN * HH) return;
    int isbf = *flagp;
    int node = i >> 7, f = i & 127;
    out[i] = loadf(emb, (size_t)ids[node] * HH + f, isbf);
}
// flow_x [N,97] (flag dtype) -> bf16 padded [N,128]; 8 output cols per thread
__global__ void k_pad_cast(const void* x, unsigned short* o, const int* flagp){
    int i = blockIdx.x * 256 + threadIdx.x;           // 0 .. N_FLOWN*16
    if (i >= N_FLOWN * 16) return;
    int isbf = *flagp;
    int row = i >> 4, c0 = (i & 15) * 8;
    unsigned short v[8];
    #pragma unroll
    for (int j = 0; j < 8; ++j) {
        int c = c0 + j;
        v[j] = (c < FIN) ? f2bf(loadf(x, (size_t)row * FIN + c, isbf)) : (unsigned short)0;
    }
    uint4 ov;
    ov.x = (unsigned)v[0] | ((unsigned)v[1] << 16);
    ov.y = (unsigned)v[2] | ((unsigned)v[3] << 16);
    ov.z = (unsigned)v[4] | ((unsigned)v[5] << 16);
    ov.w = (unsigned)v[6] | ((unsigned)v[7] << 16);
    *(uint4*)(o + (size_t)row * 128 + c0) = ov;
}

// ---------------- one-shot weight prep (833 blocks, region dispatch) ----------------
__global__ __launch_bounds__(256) void k_wprep_all(
    const void* Wr0_h2f, const void* br0_h2f, const void* Wo0_h2f,
    const void* Wr0_f2h, const void* br0_f2h, const void* Wo0_f2h,
    const void* Wr0_rel, const void* br0_rel, const void* Wo0_rel,
    const void* Wr_all, const void* br_all, const void* Wo_all,
    unsigned short* WBT0, unsigned short* WBT1, unsigned short* WBT2,
    float* w_h2f0, float* w_h2f1, float* w_h2f2,
    float* w_f2h0, float* w_f2h1, float* w_of2h0, float* w_of2h1,
    float* b_comb0, float* b_comb1, float* b_comb2, float* b_f2h0, float* b_f2h1,
    const int* flagp)
{
    const int bb = blockIdx.x, t = threadIdx.x;
    const int isbf = *flagp;
    if (bb < 384) {
        int layer = bb >> 7;
        int i = ((bb & 127) << 8) + t;   // 0..32767
        int nn = i >> 7, k = i & 127;
        float v = 0.f;
        if (layer == 0) {
            if (k < FIN) {
                if (nn < 128) v = loadf(Wo0_h2f, (size_t)k*128+nn, isbf) + loadf(Wo0_rel, (size_t)k*128+nn, isbf);
                else          v = loadf(Wr0_rel, (size_t)k*128+(nn-128), isbf);
            }
        } else {
            size_t oW = (size_t)((layer - 1) * 3) * 16384;
            if (nn < 128) v = loadf(Wo_all, oW + (size_t)k*128+nn, isbf)
                            + loadf(Wo_all, oW + 2*16384 + (size_t)k*128+nn, isbf);
            else          v = loadf(Wr_all, oW + 2*16384 + (size_t)k*128+(nn-128), isbf);
        }
        unsigned short* W = (layer == 0) ? WBT0 : ((layer == 1) ? WBT1 : WBT2);
        W[(size_t)nn*128 + k] = f2bf(v);
    } else if (bb < 576) {
        int r = bb - 384; int layer = r >> 6; int i = ((r & 63) << 8) + t;
        float v;
        if (layer == 0) v = loadf(Wr0_h2f, (size_t)i, isbf);
        else            v = loadf(Wr_all, (size_t)((layer-1)*3)*16384 + i, isbf);
        ((layer == 0) ? w_h2f0 : ((layer == 1) ? w_h2f1 : w_h2f2))[i] = v;
    } else if (bb < 640) {
        // w_f2h0 padded to [128][128]: rows k>=97 zero
        int i = ((bb - 576) << 8) + t;
        int k = i >> 7;
        w_f2h0[i] = (k < FIN) ? loadf(Wr0_f2h, (size_t)i, isbf) : 0.f;
    } else if (bb < 704) {
        int i = ((bb - 640) << 8) + t;
        w_f2h1[i] = loadf(Wr_all, (size_t)1*16384 + i, isbf);
    } else if (bb < 768) {
        int i = ((bb - 704) << 8) + t;
        w_of2h0[i] = loadf(Wo0_f2h, (size_t)i, isbf);
    } else if (bb < 832) {
        int i = ((bb - 768) << 8) + t;
        w_of2h1[i] = loadf(Wo_all, (size_t)1*16384 + i, isbf);
    } else {
        if (t < 128) {
            b_comb0[t] = loadf(br0_h2f, t, isbf) + loadf(br0_rel, t, isbf);
            b_comb1[t] = loadf(br_all, 0*128 + t, isbf) + loadf(br_all, 2*128 + t, isbf);
            b_comb2[t] = loadf(br_all, 3*128 + t, isbf) + loadf(br_all, 5*128 + t, isbf);
            b_f2h0[t]  = loadf(br0_f2h, t, isbf);
            b_f2h1[t]  = loadf(br_all, 1*128 + t, isbf);
        }
    }
}

// ============ binned CSR build: NO scattered global atomics ============
// R9 showed 1.6M scattered global atomic-with-returns == ~67us (VALUBusy 0.45%,
// pure atomic throughput bound). This build uses only LDS atomics:
//  1) per-block LDS histogram over coarse bins (dst>>8), counts -> [bin][block]
//  2) per-bin scan over blocks + cross-bin scan -> (block,bin) bases
//  3) scatter edges bin-grouped via LDS cursors, packed (src | dstLow<<18)
//  4) one block per bin: LDS 256-hist + scan -> rp (all dsts, coalesced) + ei

// pass 1: per-block coarse-bin counts
__global__ __launch_bounds__(256) void k_binhist(
    const int* __restrict__ rel_dst, const int* __restrict__ h2f_dst,
    const int* __restrict__ f2h_dst, int* __restrict__ cntF, int* __restrict__ cntH)
{
    __shared__ int c[NBIN_F];
    const int t = threadIdx.x, bb = blockIdx.x;
    if (bb < BH_F) {
        for (int i = t; i < NBIN_F; i += 256) c[i] = 0;
        __syncthreads();
        const int e0 = bb * EPB_F;
        for (int i = t; i < EPB_F; i += 256) {
            const int e = e0 + i;
            const int d = (e < E_RELN) ? rel_dst[e] : h2f_dst[e - E_RELN];
            atomicAdd(&c[d >> 8], 1);
        }
        __syncthreads();
        for (int i = t; i < NBIN_F; i += 256) cntF[i * BH_F + bb] = c[i];
    } else {
        const int blk = bb - BH_F;
        for (int i = t; i < NBIN_H; i += 256) c[i] = 0;
        __syncthreads();
        const int e0 = blk * EPB_H;
        for (int i = t; i < EPB_H; i += 256)
            atomicAdd(&c[f2h_dst[e0 + i] >> 8], 1);
        __syncthreads();
        for (int i = t; i < NBIN_H; i += 256) cntH[i * BH_H + blk] = c[i];
    }
}
// pass 2a: per-bin exclusive scan across blocks (in place); bin totals out
__global__ __launch_bounds__(128) void k_binscan1(
    int* __restrict__ cntF, int* __restrict__ cntH,
    int* __restrict__ bintotF, int* __restrict__ bintotH)
{
    __shared__ int s[128];
    const int t = threadIdx.x, b = blockIdx.x;
    int v;
    if (b < NBIN_F) v = (t < BH_F) ? cntF[b * BH_F + t] : 0;
    else            v = (t < BH_H) ? cntH[(b - NBIN_F) * BH_H + t] : 0;
    s[t] = v; __syncthreads();
    for (int off = 1; off < 128; off <<= 1) {
        int x = (t >= off) ? s[t - off] : 0;
        __syncthreads();
        s[t] += x;
        __syncthreads();
    }
    if (b < NBIN_F) {
        if (t < BH_F) cntF[b * BH_F + t] = s[t] - v;
        if (t == 127) bintotF[b] = s[127];
    } else {
        if (t < BH_H) cntH[(b - NBIN_F) * BH_H + t] = s[t] - v;
        if (t == 127) bintotH[b - NBIN_F] = s[127];
    }
}
// pass 2b: exclusive scan across bins (in place: bintot -> binstart)
__global__ __launch_bounds__(256) void k_binscan2(int* aF, int* aH){
    __shared__ int s[256];
    __shared__ int carry;
    int* a; int n;
    if (blockIdx.x == 0) { a = aF; n = NBIN_F; } else { a = aH; n = NBIN_H; }
    const int t = threadIdx.x;
    if (t == 0) carry = 0;
    __syncthreads();
    for (int base = 0; base < n; base += 256) {
        const int i = base + t;
        int v = (i < n) ? a[i] : 0;
        s[t] = v; __syncthreads();
        for (int off = 1; off < 256; off <<= 1) {
            int x = (t >= off) ? s[t - off] : 0;
            __syncthreads();
            s[t] += x;
            __syncthreads();
        }
        int excl = s[t] - v + carry;
        if (i < n) a[i] = excl;
        __syncthreads();
        if (t == 255) carry += s[255];
        __syncthreads();
    }
}
// pass 3: scatter edges into bin-grouped scratch (LDS cursors only)
__global__ __launch_bounds__(256) void k_binscatter(
    const int* __restrict__ rel_src, const int* __restrict__ rel_dst,
    const int* __restrict__ h2f_src, const int* __restrict__ h2f_dst,
    const int* __restrict__ f2h_src, const int* __restrict__ f2h_dst,
    const int* __restrict__ pbF, const int* __restrict__ pbH,
    const int* __restrict__ bsF, const int* __restrict__ bsH,
    unsigned* __restrict__ ebinF, unsigned* __restrict__ ebinH)
{
    __shared__ int base[NBIN_F];
    const int t = threadIdx.x, bb = blockIdx.x;
    if (bb < BH_F) {
        for (int i = t; i < NBIN_F; i += 256) base[i] = bsF[i] + pbF[i * BH_F + bb];
        __syncthreads();
        const int e0 = bb * EPB_F;
        for (int i = t; i < EPB_F; i += 256) {
            const int e = e0 + i;
            int d, sv;
            if (e < E_RELN) { d = rel_dst[e]; sv = rel_src[e]; }
            else            { d = h2f_dst[e - E_RELN]; sv = h2f_src[e - E_RELN] + N_FLOWN; }
            const int pos = atomicAdd(&base[d >> 8], 1);
            ebinF[pos] = (unsigned)sv | ((unsigned)(d & 255) << 18);
        }
    } else {
        const int blk = bb - BH_F;
        for (int i = t; i < NBIN_H; i += 256) base[i] = bsH[i] + pbH[i * BH_H + blk];
        __syncthreads();
        const int e0 = blk * EPB_H;
        for (int i = t; i < EPB_H; i += 256) {
            const int e = e0 + i;
            const int d = f2h_dst[e];
            const int pos = atomicAdd(&base[d >> 8], 1);
            ebinH[pos] = (unsigned)f2h_src[e] | ((unsigned)(d & 255) << 18);
        }
    }
}
// pass 4: per-bin fine CSR (rp for ALL dsts incl. empty; ei scatter in-bin)
__global__ __launch_bounds__(256) void k_bincsr(
    const unsigned* __restrict__ ebinF, const unsigned* __restrict__ ebinH,
    const int* __restrict__ bsF, const int* __restrict__ bsH,
    int* __restrict__ rp_cmb, int* __restrict__ ei_cmb,
    int* __restrict__ rp_f2h, int* __restrict__ ei_f2h)
{
    __shared__ int c[256];
    __shared__ int off[256];
    const int t = threadIdx.x, b = blockIdx.x;
    const unsigned* ebin; int* rp; int* ei; int seg0, seg1, dstbase, ndst;
    if (b < NBIN_F) {
        ebin = ebinF; rp = rp_cmb; ei = ei_cmb;
        seg0 = bsF[b]; seg1 = (b == NBIN_F - 1) ? E_CMBN : bsF[b + 1];
        dstbase = b * 256; ndst = min(256, N_FLOWN - dstbase);
        if (b == 0 && t == 0) rp_cmb[N_FLOWN] = E_CMBN;
    } else {
        const int bh = b - NBIN_F;
        ebin = ebinH; rp = rp_f2h; ei = ei_f2h;
        seg0 = bsH[bh]; seg1 = (bh == NBIN_H - 1) ? E_HFN : bsH[bh + 1];
        dstbase = bh * 256; ndst = min(256, N_HOSTN - dstbase);
        if (bh == 0 && t == 0) rp_f2h[N_HOSTN] = E_HFN;
    }
    c[t] = 0;
    __syncthreads();
    for (int i = seg0 + t; i < seg1; i += 256)
        atomicAdd(&c[ebin[i] >> 18], 1);
    __syncthreads();
    const int v = c[t];
    for (int o = 1; o < 256; o <<= 1) {
        int x = (t >= o) ? c[t - o] : 0;
        __syncthreads();
        c[t] += x;
        __syncthreads();
    }
    const int excl = c[t] - v;
    if (t < ndst) rp[dstbase + t] = seg0 + excl;
    off[t] = seg0 + excl;
    __syncthreads();
    for (int i = seg0 + t; i < seg1; i += 256) {
        const unsigned u = ebin[i];
        const int pos = atomicAdd(&off[u >> 18], 1);
        ei[pos] = (int)(u & 0x3FFFFu);
    }
}

// ---------------- host-sized VALU GEMM: Y[M,128] (+)= X[M,K]@W[K,128]+b ---------
__global__ __launch_bounds__(256) void k_gemm128(
    const void* X, int xmode, const float* W, const float* bias,
    void* Y, int ybf, int M, int K, int accum, int dorelu, const int* flagp)
{
    const int isbf = (xmode == 2) ? *flagp : xmode;
    const int tid  = threadIdx.x;
    const int row0 = blockIdx.x * 16;
    __shared__ float sX[16][132];
    if (!isbf && (K & 3) == 0) {
        // vectorized f32 staging (all current call sites)
        const int kq = K >> 2;
        for (int i = tid; i < 16 * kq; i += 256) {
            int r = i / kq, c4 = (i - r * kq) * 4;
            int gr = row0 + r;
            float4 v = {0.f, 0.f, 0.f, 0.f};
            if (gr < M) v = *(const float4*)((const float*)X + (size_t)gr * K + c4);
            *(float4*)&sX[r][c4] = v;
        }
    } else {
        const int total = 16 * K;
        for (int i = tid; i < total; i += 256) {
            int r = i / K, c = i - r * K;
            int gr = row0 + r;
            sX[r][c] = (gr < M) ? loadf(X, (size_t)gr * K + c, isbf) : 0.f;
        }
    }
    __syncthreads();

    const int c4 = (tid & 31) * 4;
    const int rb = tid >> 5;
    float a0x=0,a0y=0,a0z=0,a0w=0, a1x=0,a1y=0,a1z=0,a1w=0;
    #pragma unroll 4
    for (int k = 0; k < K; ++k) {
        const float4 w = *(const float4*)(W + (size_t)k * 128 + c4);
        const float x0 = sX[rb][k];
        const float x1 = sX[rb + 8][k];
        a0x = fmaf(x0, w.x, a0x); a0y = fmaf(x0, w.y, a0y);
        a0z = fmaf(x0, w.z, a0z); a0w = fmaf(x0, w.w, a0w);
        a1x = fmaf(x1, w.x, a1x); a1y = fmaf(x1, w.y, a1y);
        a1z = fmaf(x1, w.z, a1z); a1w = fmaf(x1, w.w, a1w);
    }
    float bx=0, by=0, bz=0, bw=0;
    if (bias) { const float4 b = *(const float4*)(bias + c4); bx=b.x; by=b.y; bz=b.z; bw=b.w; }

    #pragma unroll
    for (int h = 0; h < 2; ++h) {
        const int rr = row0 + rb + (h ? 8 : 0);
        if (rr >= M) continue;
        float v0 = (h?a1x:a0x)+bx, v1 = (h?a1y:a0y)+by;
        float v2 = (h?a1z:a0z)+bz, v3 = (h?a1w:a0w)+bw;
        if (ybf) {
            unsigned short* p = (unsigned short*)Y + (size_t)rr * 128 + c4;
            ushort4 o; o.x=f2bf(v0); o.y=f2bf(v1); o.z=f2bf(v2); o.w=f2bf(v3);
            *(ushort4*)p = o;
        } else {
            float* p = (float*)Y + (size_t)rr * 128 + c4;
            if (accum) { v0+=p[0]; v1+=p[1]; v2+=p[2]; v3+=p[3]; }
            if (dorelu) { v0=fmaxf(v0,0.f); v1=fmaxf(v1,0.f); v2=fmaxf(v2,0.f); v3=fmaxf(v3,0.f); }
            float4 o; o.x=v0; o.y=v1; o.z=v2; o.w=v3;
            *(float4*)p = o;
        }
    }
}

// ---------------- fused dual-input host GEMM: Y = relu(X1@W1 + X2@W2 + b) ------
__global__ __launch_bounds__(256) void k_gemm2in(
    const float* __restrict__ X1, const float* __restrict__ X2,
    const float* __restrict__ W1, const float* __restrict__ W2,
    const float* __restrict__ bias, float* __restrict__ Y, int M)
{
    const int tid  = threadIdx.x;
    const int row0 = blockIdx.x * 16;
    __shared__ float sX1[16][132];
    __shared__ float sX2[16][132];
    for (int i = tid; i < 16 * 32; i += 256) {
        int r = i >> 5, c4 = (i & 31) * 4;
        int gr = row0 + r;
        float4 v1 = {0.f, 0.f, 0.f, 0.f}, v2 = {0.f, 0.f, 0.f, 0.f};
        if (gr < M) {
            v1 = *(const float4*)(X1 + (size_t)gr * 128 + c4);
            v2 = *(const float4*)(X2 + (size_t)gr * 128 + c4);
        }
        *(float4*)&sX1[r][c4] = v1;
        *(float4*)&sX2[r][c4] = v2;
    }
    __syncthreads();

    const int c4 = (tid & 31) * 4;
    const int rb = tid >> 5;
    float a0x=0,a0y=0,a0z=0,a0w=0, a1x=0,a1y=0,a1z=0,a1w=0;
    #pragma unroll 4
    for (int k = 0; k < 128; ++k) {
        const float4 w = *(const float4*)(W1 + (size_t)k * 128 + c4);
        const float x0 = sX1[rb][k];
        const float x1 = sX1[rb + 8][k];
        a0x = fmaf(x0, w.x, a0x); a0y = fmaf(x0, w.y, a0y);
        a0z = fmaf(x0, w.z, a0z); a0w = fmaf(x0, w.w, a0w);
        a1x = fmaf(x1, w.x, a1x); a1y = fmaf(x1, w.y, a1y);
        a1z = fmaf(x1, w.z, a1z); a1w = fmaf(x1, w.w, a1w);
    }
    #pragma unroll 4
    for (int k = 0; k < 128; ++k) {
        const float4 w = *(const float4*)(W2 + (size_t)k * 128 + c4);
        const float x0 = sX2[rb][k];
        const float x1 = sX2[rb + 8][k];
        a0x = fmaf(x0, w.x, a0x); a0y = fmaf(x0, w.y, a0y);
        a0z = fmaf(x0, w.z, a0z); a0w = fmaf(x0, w.w, a0w);
        a1x = fmaf(x1, w.x, a1x); a1y = fmaf(x1, w.y, a1y);
        a1z = fmaf(x1, w.z, a1z); a1w = fmaf(x1, w.w, a1w);
    }
    const float4 b = *(const float4*)(bias + c4);
    #pragma unroll
    for (int h = 0; h < 2; ++h) {
        const int rr = row0 + rb + (h ? 8 : 0);
        if (rr >= M) continue;
        float4 o;
        o.x = fmaxf((h?a1x:a0x) + b.x, 0.f);
        o.y = fmaxf((h?a1y:a0y) + b.y, 0.f);
        o.z = fmaxf((h?a1z:a0z) + b.z, 0.f);
        o.w = fmaxf((h?a1w:a0w) + b.w, 0.f);
        *(float4*)(Y + (size_t)rr * 128 + c4) = o;
    }
}

// ---------------- MFMA dual flow GEMM: both outputs bf16, no bias ----------------
// All global traffic linearized: A staged once per block into XOR-swizzled LDS
// via linear uint4 loads; output bounced through LDS and stored with linear
// uint4 stores. 8 waves x 32 WBT rows (B = 8 bfrags in regs), LB(512,4).
typedef __attribute__((ext_vector_type(8))) short bfrag;
typedef __attribute__((ext_vector_type(4))) float f32x4;

#define GEMM_CHUNKS 4
#define GEMM_MROWS  (32 * GEMM_CHUNKS)   // 128 rows per block

__global__ __launch_bounds__(512, 4) void k_gemm_mfma(
    const unsigned short* __restrict__ Abf, const unsigned short* __restrict__ WBT,
    unsigned short* __restrict__ Y1, unsigned short* __restrict__ Y2, int M)
{
    __shared__ unsigned short sA[32 * 128];      // 8 KB, XOR-swizzled 16B units
    __shared__ unsigned short sO[2][32][136];    // 17.4 KB out-stage (pad 8 shorts)

    const int tid  = threadIdx.x;
    const int wave = tid >> 6;        // 0..7
    const int lane = tid & 63;
    const int quad = lane >> 4;
    const int l16  = lane & 15;
    const int nbase = wave * 32;      // 32 WBT rows per wave

    // B slice for this wave's 32 output cols: breg[c][j] (8 bfrags = 32 regs)
    bfrag breg[4][2];
    #pragma unroll
    for (int c = 0; c < 4; ++c)
        #pragma unroll
        for (int j = 0; j < 2; ++j)
            breg[c][j] = *(const bfrag*)(WBT + (size_t)(nbase + j * 16 + l16) * 128
                                              + c * 32 + quad * 8);

    const int ybuf = (nbase < 128) ? 0 : 1;
    const int colb = nbase & 127;
    const f32x4 zero = {0.f, 0.f, 0.f, 0.f};

    const int srow = tid >> 4;        // staging row 0..31
    const int su   = tid & 15;        // staging 16B unit 0..15

    for (int chunk = 0; chunk < GEMM_CHUNKS; ++chunk) {
        const int m0 = blockIdx.x * GEMM_MROWS + chunk * 32;
        if (m0 >= M) break;           // block-uniform (M % 32 == 0)

        // ---- stage A chunk (32x128 bf16 = 8KB): linear load, swizzled LDS ----
        {
            const uint4* gsrc = (const uint4*)(Abf + (size_t)m0 * 128);
            uint4* sdst = (uint4*)sA;
            sdst[srow * 16 + (su ^ (srow & 15))] = gsrc[tid];
        }
        __syncthreads();

        // ---- fragments from LDS + MFMA ----
        bfrag a0[4], a1[4];
        #pragma unroll
        for (int c = 0; c < 4; ++c) {
            const int un = (c * 4 + quad) ^ l16;
            a0[c] = *(const bfrag*)(sA + (size_t)(l16)      * 128 + un * 8);
            a1[c] = *(const bfrag*)(sA + (size_t)(16 + l16) * 128 + un * 8);
        }
        f32x4 acc[2][2];
        #pragma unroll
        for (int j = 0; j < 2; ++j) {
            acc[0][j] = __builtin_amdgcn_mfma_f32_16x16x32_bf16(breg[0][j], a0[0], zero, 0, 0, 0);
            acc[1][j] = __builtin_amdgcn_mfma_f32_16x16x32_bf16(breg[0][j], a1[0], zero, 0, 0, 0);
        }
        #pragma unroll
        for (int c = 1; c < 4; ++c)
            #pragma unroll
            for (int j = 0; j < 2; ++j) {
                acc[0][j] = __builtin_amdgcn_mfma_f32_16x16x32_bf16(breg[c][j], a0[c], acc[0][j], 0, 0, 0);
                acc[1][j] = __builtin_amdgcn_mfma_f32_16x16x32_bf16(breg[c][j], a1[c], acc[1][j], 0, 0, 0);
            }

        // ---- stage D' to LDS (D' layout: col(l16)=row m, row(quad*4+r)=col n) ----
        #pragma unroll
        for (int i = 0; i < 2; ++i) {
            const int row = i * 16 + l16;
            #pragma unroll
            for (int j = 0; j < 2; ++j) {
                const int col = colb + j * 16 + quad * 4;
                uint2 o;
                o.x = (unsigned)f2bf(acc[i][j][0]) | ((unsigned)f2bf(acc[i][j][1]) << 16);
                o.y = (unsigned)f2bf(acc[i][j][2]) | ((unsigned)f2bf(acc[i][j][3]) << 16);
                *(uint2*)&sO[ybuf][row][col] = o;
            }
        }
        __syncthreads();

        // ---- linear coalesced stores: 1KB-contiguous per wave instruction ----
        {
            const size_t goff = (size_t)(m0 + srow) * 128 + su * 8;
            *(uint4*)(Y1 + goff) = *(const uint4*)&sO[0][srow][su * 8];
            *(uint4*)(Y2 + goff) = *(const uint4*)&sO[1][srow][su * 8];
        }
        __syncthreads();
    }
}

// ---------------- persistent-wave combined CSR aggregation (flow dsts) ----------
// QUARTER-PER-DST: each 16-lane quarter owns one dst entirely (16 lanes x 8
// features = 128). Per outer iteration the wave processes 4 CONSECUTIVE dsts in
// parallel: no cross-quarter reduce, epilogue amortized 4x, root loads / stores
// are 4 consecutive rows = 1 KiB contiguous per instruction.
// Edge-index window staged to LDS once per wave (contiguous CSR range).
__global__ __launch_bounds__(256) void k_agg_flow(
    const unsigned short* __restrict__ Z,
    const int* __restrict__ rp, const int* __restrict__ ei,
    const unsigned short* __restrict__ root, const float* __restrict__ bias,
    unsigned short* __restrict__ Xout, int do_relu)
{
    __shared__ int sIdx[4][AGG_CAP];
    const int wave = threadIdx.x >> 6;
    const int lane = threadIdx.x & 63;
    const int q    = lane >> 4;
    const int l16  = lane & 15;
    const int f8   = l16 * 8;
    const int gw   = blockIdx.x * 4 + wave;
    const int d0   = gw * AGGF_DPW;
    const int nd   = min(AGGF_DPW, N_FLOWN - d0);   // may be <= 0 for tail waves

    int rpv = 0, W0 = 0, Wcap = 0;
    if (nd > 0) {
        rpv = (lane <= nd) ? rp[d0 + lane] : 0;
        W0 = __shfl(rpv, 0, 64);
        const int Wn = __shfl(rpv, nd, 64);
        const int cw = min(Wn - W0, AGG_CAP);
        for (int i = lane; i < cw; i += 64) sIdx[wave][i] = ei[W0 + i];
        Wcap = W0 + cw;
    }
    __syncthreads();
    if (nd <= 0) return;

    // loop-invariant bias slice
    const float4 bva = *(const float4*)(bias + f8);
    const float4 bvb = *(const float4*)(bias + f8 + 4);

    #pragma unroll 2
    for (int i = 0; i < AGGF_DPW / 4; ++i) {
        const int dqi = i * 4 + q;              // this quarter's dst offset
        const bool act = dqi < nd;
        const int srcl = act ? dqi : 0;
        const int b0 = __shfl(rpv, srcl, 64);
        const int b1 = __shfl(rpv, srcl + 1, 64);
        const int d  = d0 + dqi;

        uint4 rv = {0, 0, 0, 0};
        if (act) rv = *(const uint4*)(root + (size_t)d * 128 + f8);

        float a[8] = {0.f, 0.f, 0.f, 0.f, 0.f, 0.f, 0.f, 0.f};
        int n = act ? (b1 - b0) : 0;
        int e = b0;
        while (n >= 4) {
            const int s0 = (e     < Wcap) ? sIdx[wave][e     - W0] : ei[e];
            const int s1 = (e + 1 < Wcap) ? sIdx[wave][e + 1 - W0] : ei[e + 1];
            const int s2 = (e + 2 < Wcap) ? sIdx[wave][e + 2 - W0] : ei[e + 2];
            const int s3 = (e + 3 < Wcap) ? sIdx[wave][e + 3 - W0] : ei[e + 3];
            const uint4 z0 = *(const uint4*)(Z + (size_t)s0 * 128 + f8);
            const uint4 z1 = *(const uint4*)(Z + (size_t)s1 * 128 + f8);
            const uint4 z2 = *(const uint4*)(Z + (size_t)s2 * 128 + f8);
            const uint4 z3 = *(const uint4*)(Z + (size_t)s3 * 128 + f8);
            acc8(a, z0); acc8(a, z1); acc8(a, z2); acc8(a, z3);
            e += 4; n -= 4;
        }
        if (n & 2) {
            const int s0 = (e     < Wcap) ? sIdx[wave][e     - W0] : ei[e];
            const int s1 = (e + 1 < Wcap) ? sIdx[wave][e + 1 - W0] : ei[e + 1];
            const uint4 z0 = *(const uint4*)(Z + (size_t)s0 * 128 + f8);
            const uint4 z1 = *(const uint4*)(Z + (size_t)s1 * 128 + f8);
            acc8(a, z0); acc8(a, z1);
            e += 2;
        }
        if (n & 1) {
            const int s0 = (e < Wcap) ? sIdx[wave][e - W0] : ei[e];
            const uint4 z0 = *(const uint4*)(Z + (size_t)s0 * 128 + f8);
            acc8(a, z0);
        }

        if (act) {
            float v0 = a[0] + __uint_as_float(rv.x << 16)         + bva.x;
            float v1 = a[1] + __uint_as_float(rv.x & 0xFFFF0000u) + bva.y;
            float v2 = a[2] + __uint_as_float(rv.y << 16)         + bva.z;
            float v3 = a[3] + __uint_as_float(rv.y & 0xFFFF0000u) + bva.w;
            float v4 = a[4] + __uint_as_float(rv.z << 16)         + bvb.x;
            float v5 = a[5] + __uint_as_float(rv.z & 0xFFFF0000u) + bvb.y;
            float v6 = a[6] + __uint_as_float(rv.w << 16)         + bvb.z;
            float v7 = a[7] + __uint_as_float(rv.w & 0xFFFF0000u) + bvb.w;
            if (do_relu) {
                v0 = fmaxf(v0, 0.f); v1 = fmaxf(v1, 0.f); v2 = fmaxf(v2, 0.f); v3 = fmaxf(v3, 0.f);
                v4 = fmaxf(v4, 0.f); v5 = fmaxf(v5, 0.f); v6 = fmaxf(v6, 0.f); v7 = fmaxf(v7, 0.f);
            }
            uint4 o;
            o.x = (unsigned)f2bf(v0) | ((unsigned)f2bf(v1) << 16);
            o.y = (unsigned)f2bf(v2) | ((unsigned)f2bf(v3) << 16);
            o.z = (unsigned)f2bf(v4) | ((unsigned)f2bf(v5) << 16);
            o.w = (unsigned)f2bf(v6) | ((unsigned)f2bf(v7) << 16);
            *(uint4*)(Xout + (size_t)d * 128 + f8) = o;
        }
    }
}

// host dst: out[d][0:128] = sum f2h Z[src][0:128]  (f32 out)
// Same quarter-per-dst persistent structure.
__global__ __launch_bounds__(256) void k_agg_host(
    const unsigned short* __restrict__ Z, const int* __restrict__ rp,
    const int* __restrict__ ei, float* __restrict__ out)
{
    __shared__ int sIdx[4][AGG_CAP];
    const int wave = threadIdx.x >> 6;
    const int lane = threadIdx.x & 63;
    const int q    = lane >> 4;
    const int l16  = lane & 15;
    const int f8   = l16 * 8;
    const int gw   = blockIdx.x * 4 + wave;
    const int d0   = gw * AGGH_DPW;
    const int nd   = min(AGGH_DPW, N_HOSTN - d0);

    int rpv = 0, W0 = 0, Wcap = 0;
    if (nd > 0) {
        rpv = (lane <= nd) ? rp[d0 + lane] : 0;
        W0 = __shfl(rpv, 0, 64);
        const int Wn = __shfl(rpv, nd, 64);
        const int cw = min(Wn - W0, AGG_CAP);
        for (int i = lane; i < cw; i += 64) sIdx[wave][i] = ei[W0 + i];
        Wcap = W0 + cw;
    }
    __syncthreads();
    if (nd <= 0) return;

    #pragma unroll
    for (int i = 0; i < AGGH_DPW / 4; ++i) {
        const int dqi = i * 4 + q;
        const bool act = dqi < nd;
        const int srcl = act ? dqi : 0;
        const int b0 = __shfl(rpv, srcl, 64);
        const int b1 = __shfl(rpv, srcl + 1, 64);
        const int d  = d0 + dqi;

        float a[8] = {0.f, 0.f, 0.f, 0.f, 0.f, 0.f, 0.f, 0.f};
        int n = act ? (b1 - b0) : 0;
        int e = b0;
        while (n >= 4) {
            const int s0 = (e     < Wcap) ? sIdx[wave][e     - W0] : ei[e];
            const int s1 = (e + 1 < Wcap) ? sIdx[wave][e + 1 - W0] : ei[e + 1];
            const int s2 = (e + 2 < Wcap) ? sIdx[wave][e + 2 - W0] : ei[e + 2];
            const int s3 = (e + 3 < Wcap) ? sIdx[wave][e + 3 - W0] : ei[e + 3];
            const uint4 z0 = *(const uint4*)(Z + (size_t)s0 * 128 + f8);
            const uint4 z1 = *(const uint4*)(Z + (size_t)s1 * 128 + f8);
            const uint4 z2 = *(const uint4*)(Z + (size_t)s2 * 128 + f8);
            const uint4 z3 = *(const uint4*)(Z + (size_t)s3 * 128 + f8);
            acc8(a, z0); acc8(a, z1); acc8(a, z2); acc8(a, z3);
            e += 4; n -= 4;
        }
        if (n & 2) {
            const int s0 = (e     < Wcap) ? sIdx[wave][e     - W0] : ei[e];
            const int s1 = (e + 1 < Wcap) ? sIdx[wave][e + 1 - W0] : ei[e + 1];
            const uint4 z0 = *(const uint4*)(Z + (size_t)s0 * 128 + f8);
            const uint4 z1 = *(const uint4*)(Z + (size_t)s1 * 128 + f8);
            acc8(a, z0); acc8(a, z1);
            e += 2;
        }
        if (n & 1) {
            const int s0 = (e < Wcap) ? sIdx[wave][e - W0] : ei[e];
            const uint4 z0 = *(const uint4*)(Z + (size_t)s0 * 128 + f8);
            acc8(a, z0);
        }

        if (act) {
            float4 oa, ob;
            oa.x = a[0]; oa.y = a[1]; oa.z = a[2]; oa.w = a[3];
            ob.x = a[4]; ob.y = a[5]; ob.z = a[6]; ob.w = a[7];
            *(float4*)(out + (size_t)d * 128 + f8)     = oa;
            *(float4*)(out + (size_t)d * 128 + f8 + 4) = ob;
        }
    }
}

// ---------------- pooling over sorted batch (bf16 input) ----------------
#define PCHUNK 128
__global__ __launch_bounds__(128) void k_pool2(const unsigned short* xf, const int* batch,
                                               unsigned* bits){
    const int t = threadIdx.x;
    const int i0 = blockIdx.x * PCHUNK;
    const int iend = min(i0 + PCHUNK, N_FLOWN);
    if (i0 >= N_FLOWN) return;
    float cur = -3.4e38f;
    int curg = batch[i0];
    for (int i = i0; i < iend; ++i) {
        int g = batch[i];
        if (g != curg) {
            unsigned u = __float_as_uint(cur);
            unsigned ord = (u & 0x80000000u) ? ~u : (u | 0x80000000u);
            atomicMax(&bits[(size_t)curg * 128 + t], ord);
            cur = -3.4e38f; curg = g;
        }
        cur = fmaxf(cur, bf2f(xf[(size_t)i * 128 + t]));
    }
    unsigned u = __float_as_uint(cur);
    unsigned ord = (u & 0x80000000u) ? ~u : (u | 0x80000000u);
    atomicMax(&bits[(size_t)curg * 128 + t], ord);
}

// ---------------- classifier ----------------
__global__ __launch_bounds__(128) void k_classifier(
    const unsigned* bits,
    const void* Wc1, const void* bc1, const void* Wc2, const void* bc2,
    const void* Wc3, const void* bc3, void* out, const int* flagp)
{
    const int g = blockIdx.x, t = threadIdx.x;
    const int isbf = *flagp;
    __shared__ float sp[128], sh1[64], sh2[128];
    {
        unsigned ord = bits[(size_t)g * HH + t];
        unsigned u = (ord & 0x80000000u) ? (ord & 0x7FFFFFFFu) : ~ord;
        sp[t] = __uint_as_float(u);
    }
    __syncthreads();
    if (t < 64) {
        float a = loadf(bc1, t, isbf);
        #pragma unroll 4
        for (int k = 0; k < 128; ++k) a = fmaf(sp[k], loadf(Wc1, k * 64 + t, isbf), a);
        sh1[t] = fmaxf(a, 0.f);
    }
    __syncthreads();
    {
        float a = loadf(bc2, t, isbf);
        #pragma unroll 4
        for (int k = 0; k < 64; ++k) a = fmaf(sh1[k], loadf(Wc2, k * 128 + t, isbf), a);
        sh2[t] = fmaxf(a, 0.f);
    }
    __syncthreads();
    if (t < NCN) {
        float a = loadf(bc3, t, isbf);
        #pragma unroll 4
        for (int k = 0; k < 128; ++k) a = fmaf(sh2[k], loadf(Wc3, k * NCN + t, isbf), a);
        if (isbf) ((unsigned short*)out)[(size_t)g * NCN + t] = f2bf(a);
        else      ((float*)out)[(size_t)g * NCN + t] = a;
    }
}

extern "C" void kernel_launch(void* const* d_in, const int* in_sizes, int n_in,
                              void* d_out, int out_size, void* d_ws, size_t ws_size,
                              hipStream_t stream)
{
    const int*  host_ids   = (const int*) d_in[0];
    const void* flow_x     = d_in[1];
    const int*  h2f_src    = (const int*) d_in[2];
    const int*  h2f_dst    = (const int*) d_in[3];
    const int*  f2h_src    = (const int*) d_in[4];
    const int*  f2h_dst    = (const int*) d_in[5];
    const int*  rel_src    = (const int*) d_in[6];
    const int*  rel_dst    = (const int*) d_in[7];
    const int*  flow_batch = (const int*) d_in[8];
    const void* host_embed = d_in[9];
    const void* Wr0_h2f = d_in[10]; const void* br0_h2f = d_in[11]; const void* Wo0_h2f = d_in[12];
    const void* Wr0_f2h = d_in[13]; const void* br0_f2h = d_in[14]; const void* Wo0_f2h = d_in[15];
    const void* Wr0_rel = d_in[16]; const void* br0_rel = d_in[17]; const void* Wo0_rel = d_in[18];
    const void* Wr_all  = d_in[19];
    const void* br_all  = d_in[20];
    const void* Wo_all  = d_in[21];
    const void* Wc1 = d_in[22]; const void* bc1 = d_in[23];
    const void* Wc2 = d_in[24]; const void* bc2 = d_in[25];
    const void* Wc3 = d_in[26]; const void* bc3 = d_in[27];

    // -------- workspace (~198 MB; CSR scratch aliased onto HA/HB) --------
    size_t off = 0;
    auto alloc = [&](size_t bytes) -> char* {
        char* p = (char*)d_ws + off;
        off += (bytes + 255) & ~(size_t)255;
        return p;
    };
    unsigned short* F1bf  = (unsigned short*)alloc((size_t)N_FLOWN * HH * 2);  // state
    unsigned short* Froot = (unsigned short*)alloc((size_t)N_FLOWN * HH * 2);  // root term
    // ZALL: flow-transformed rows [0,200k) followed by host-transformed rows [200k,220k)
    unsigned short* ZALL  = (unsigned short*)alloc((size_t)(N_FLOWN + N_HOSTN) * HH * 2);
    unsigned short* F2bf  = ZALL;                                   // z_rel
    unsigned short* HCbf  = ZALL + (size_t)N_FLOWN * HH;            // z_h
    float* HA = (float*)alloc((size_t)N_HOSTN * HH * 4);
    float* HB = (float*)alloc((size_t)N_HOSTN * HH * 4);
    float* HD = (float*)alloc((size_t)N_HOSTN * HH * 4);
    unsigned short* WBT0 = (unsigned short*)alloc(256 * 128 * 2);
    unsigned short* WBT1 = (unsigned short*)alloc(256 * 128 * 2);
    unsigned short* WBT2 = (unsigned short*)alloc(256 * 128 * 2);
    float* w_h2f0  = (float*)alloc(128 * 128 * 4);
    float* w_h2f1  = (float*)alloc(128 * 128 * 4);
    float* w_h2f2  = (float*)alloc(128 * 128 * 4);
    float* w_f2h0  = (float*)alloc(128 * 128 * 4);
    float* w_f2h1  = (float*)alloc(128 * 128 * 4);
    float* w_of2h0 = (float*)alloc(128 * 128 * 4);
    float* w_of2h1 = (float*)alloc(128 * 128 * 4);
    float* b_comb0 = (float*)alloc(128 * 4);
    float* b_comb1 = (float*)alloc(128 * 4);
    float* b_comb2 = (float*)alloc(128 * 4);
    float* b_f2h0  = (float*)alloc(128 * 4);
    float* b_f2h1  = (float*)alloc(128 * 4);
    unsigned* poolbits = (unsigned*)alloc(GG * HH * 4);
    int* flagp = (int*)alloc(256);
    int* rp_cmb = (int*)alloc((N_FLOWN + 1) * 4);
    int* ei_cmb = (int*)alloc((size_t)E_CMBN * 4);
    int* rp_f2h = (int*)alloc((N_HOSTN + 1) * 4);
    int* ei_f2h = (int*)alloc((size_t)E_HFN * 4);
    // CSR-build scratch aliased onto buffers first written AFTER the build
    // (stream-ordered): ebin arrays (6.4 MB) live in HA (10.24 MB, first write =
    // k_gather_embed); count/prefix matrices (~420 KB) live in HB (first write =
    // k_gemm2in).
    unsigned* ebinF = (unsigned*)HA;          // E_CMBN uints = 4.8 MB
    unsigned* ebinH = ebinF + E_CMBN;         // E_HFN uints = 1.6 MB (total 6.4)
    int* cntF    = (int*)HB;                  // NBIN_F*BH_F = 100096 ints
    int* cntH    = cntF + NBIN_F * BH_F;      // NBIN_H*BH_H = 2528 ints
    int* bintotF = cntH + NBIN_H * BH_H;      // NBIN_F ints
    int* bintotH = bintotF + NBIN_F;          // NBIN_H ints  (total ~412 KB)

    const int T = 256;
    #define GRID1(n) dim3(cdiv((long long)(n), T)), dim3(T), 0, stream

    if (off > ws_size) {
        k_flag_us<<<GRID1(out_size)>>>((unsigned short*)d_out, out_size, (unsigned short)0x4000);
        return;
    }

    k_detect<<<dim3(1), dim3(256), 0, stream>>>((const unsigned short*)flow_x, flagp);

    // -------- binned CSR build (no scattered global atomics) --------
    k_binhist   <<<dim3(BH_F + BH_H), dim3(256), 0, stream>>>(rel_dst, h2f_dst, f2h_dst, cntF, cntH);
    k_binscan1  <<<dim3(NBIN_ALL), dim3(128), 0, stream>>>(cntF, cntH, bintotF, bintotH);
    k_binscan2  <<<dim3(2), dim3(256), 0, stream>>>(bintotF, bintotH);   // -> binstarts
    k_binscatter<<<dim3(BH_F + BH_H), dim3(256), 0, stream>>>(
        rel_src, rel_dst, h2f_src, h2f_dst, f2h_src, f2h_dst,
        cntF, cntH, bintotF, bintotH, ebinF, ebinH);
    k_bincsr    <<<dim3(NBIN_ALL), dim3(256), 0, stream>>>(
        ebinF, ebinH, bintotF, bintotH, rp_cmb, ei_cmb, rp_f2h, ei_f2h);

    // -------- weight prep (1 launch) --------
    k_wprep_all<<<dim3(833), dim3(256), 0, stream>>>(
        Wr0_h2f, br0_h2f, Wo0_h2f, Wr0_f2h, br0_f2h, Wo0_f2h, Wr0_rel, br0_rel, Wo0_rel,
        Wr_all, br_all, Wo_all,
        WBT0, WBT1, WBT2, w_h2f0, w_h2f1, w_h2f2,
        w_f2h0, w_f2h1, w_of2h0, w_of2h1,
        b_comb0, b_comb1, b_comb2, b_f2h0, b_f2h1, flagp);

    // ================= layer 0 =================
    k_gather_embed<<<GRID1(N_HOSTN * HH)>>>(host_ids, host_embed, HA, flagp);
    k_pad_cast<<<GRID1(N_FLOWN * 16)>>>(flow_x, F1bf, flagp);
    // host path: gather bf16 input features (K padded to 128); fused dual GEMM + relu
    k_agg_host<<<dim3(AGGH_BLK), dim3(256), 0, stream>>>(F1bf, rp_f2h, ei_f2h, HD);
    k_gemm2in<<<dim3(cdiv(N_HOSTN,16)), dim3(256), 0, stream>>>(HD, HA, w_f2h0, w_of2h0, b_f2h0, HB, N_HOSTN);
    // flow path
    k_gemm128<<<dim3(cdiv(N_HOSTN,16)), dim3(256), 0, stream>>>(HA, 0, w_h2f0, nullptr, HCbf, 1, N_HOSTN, 128, 0, 0, flagp);
    k_gemm_mfma<<<dim3(cdiv(N_FLOWN, GEMM_MROWS)), dim3(512), 0, stream>>>(F1bf, WBT0, Froot, F2bf, N_FLOWN);
    k_agg_flow<<<dim3(AGGF_BLK), dim3(256), 0, stream>>>(ZALL, rp_cmb, ei_cmb,
                                                         Froot, b_comb0, F1bf, 1);

    // ================= stacked layer 0 =================
    k_agg_host<<<dim3(AGGH_BLK), dim3(256), 0, stream>>>(F1bf, rp_f2h, ei_f2h, HD);
    k_gemm128<<<dim3(cdiv(N_HOSTN,16)), dim3(256), 0, stream>>>(HB, 0, w_h2f1, nullptr, HCbf, 1, N_HOSTN, 128, 0, 0, flagp);
    k_gemm_mfma<<<dim3(cdiv(N_FLOWN, GEMM_MROWS)), dim3(512), 0, stream>>>(F1bf, WBT1, Froot, F2bf, N_FLOWN);
    k_agg_flow<<<dim3(AGGF_BLK), dim3(256), 0, stream>>>(ZALL, rp_cmb, ei_cmb,
                                                         Froot, b_comb1, F1bf, 1);
    k_gemm2in<<<dim3(cdiv(N_HOSTN,16)), dim3(256), 0, stream>>>(HD, HB, w_f2h1, w_of2h1, b_f2h1, HA, N_HOSTN);

    // ================= stacked layer 1 (last; no host update, no relu) =================
    k_gemm128<<<dim3(cdiv(N_HOSTN,16)), dim3(256), 0, stream>>>(HA, 0, w_h2f2, nullptr, HCbf, 1, N_HOSTN, 128, 0, 0, flagp);
    k_gemm_mfma<<<dim3(cdiv(N_FLOWN, GEMM_MROWS)), dim3(512), 0, stream>>>(F1bf, WBT2, Froot, F2bf, N_FLOWN);
    k_agg_flow<<<dim3(AGGF_BLK), dim3(256), 0, stream>>>(ZALL, rp_cmb, ei_cmb,
                                                         Froot, b_comb2, F1bf, 0);

    // ================= pool + classifier =================
    k_zero<<<GRID1(GG * HH)>>>((float*)poolbits, (size_t)GG * HH);
    k_pool2<<<dim3(cdiv(N_FLOWN, PCHUNK)), dim3(128), 0, stream>>>(F1bf, flow_batch, poolbits);
    k_classifier<<<dim3(GG), dim3(128), 0, stream>>>(poolbits, Wc1, bc1, Wc2, bc2, Wc3, bc3,
                                                     d_out, flagp);
    #undef GRID1
}

// Round 11
// 839.477 us; speedup vs baseline: 1.2857x; 1.0545x over previous
//
#include <hip/hip_runtime.h>
#include <hip/hip_bf16.h>

using bf16 = __hip_bfloat16;

#define N_HOSTN 20000
#define N_FLOWN 200000
#define E_HFN   400000
#define E_RELN  800000
#define E_CMBN  1200000  // rel + h2f combined
#define GG      64
#define HH      128
#define FIN     97
#define NCN     10

// binned CSR build geometry (bins of 256 dsts)
#define NBIN_F  782     // ceil(200000/256)
#define NBIN_H  79      // ceil(20000/256)
#define NBIN_ALL (NBIN_F + NBIN_H)   // 861
#define BH_F    128     // flow-edge hist blocks
#define BH_H    32      // f2h hist blocks
#define EPB_F   9375    // 1200000/128
#define EPB_H   12500   // 400000/32

// persistent-wave aggregation geometry (quarter-per-dst)
#define AGG_CAP    768   // staged indices per wave (fallback to global beyond)
#define AGGF_DPW   24    // dsts per wave (multiple of 4)
#define AGGF_BLK   2084  // 2084 blk * 4 waves * 24 = 200064 >= 200000
#define AGGH_DPW   12
#define AGGH_BLK   417   // 417 * 4 * 12 = 20016 >= 20000

static inline int cdiv(long long a, long long b){ return (int)((a + b - 1) / b); }

__device__ __forceinline__ float bf2f(unsigned short u){
    return __uint_as_float(((unsigned)u) << 16);
}
__device__ __forceinline__ unsigned short f2bf(float f){
    unsigned u = __float_as_uint(f);
    unsigned r = u + 0x7FFFu + ((u >> 16) & 1u);   // RNE
    return (unsigned short)(r >> 16);
}
__device__ __forceinline__ float loadf(const void* p, size_t i, int isbf){
    return isbf ? bf2f(((const unsigned short*)p)[i]) : ((const float*)p)[i];
}
// unpack 8 bf16 (uint4) and accumulate into 8 f32
__device__ __forceinline__ void acc8(float* a, uint4 z){
    a[0] += __uint_as_float(z.x << 16);
    a[1] += __uint_as_float(z.x & 0xFFFF0000u);
    a[2] += __uint_as_float(z.y << 16);
    a[3] += __uint_as_float(z.y & 0xFFFF0000u);
    a[4] += __uint_as_float(z.z << 16);
    a[5] += __uint_as_float(z.z & 0xFFFF0000u);
    a[6] += __uint_as_float(z.w << 16);
    a[7] += __uint_as_float(z.w & 0xFFFF0000u);
}
// unpack 8 bf16 (uint4) and max into 8 f32
__device__ __forceinline__ void max8(float* m, uint4 z){
    m[0] = fmaxf(m[0], __uint_as_float(z.x << 16));
    m[1] = fmaxf(m[1], __uint_as_float(z.x & 0xFFFF0000u));
    m[2] = fmaxf(m[2], __uint_as_float(z.y << 16));
    m[3] = fmaxf(m[3], __uint_as_float(z.y & 0xFFFF0000u));
    m[4] = fmaxf(m[4], __uint_as_float(z.z << 16));
    m[5] = fmaxf(m[5], __uint_as_float(z.z & 0xFFFF0000u));
    m[6] = fmaxf(m[6], __uint_as_float(z.w << 16));
    m[7] = fmaxf(m[7], __uint_as_float(z.w & 0xFFFF0000u));
}
__device__ __forceinline__ unsigned f2ord(float f){
    unsigned u = __float_as_uint(f);
    return (u & 0x80000000u) ? ~u : (u | 0x80000000u);
}

// ---------------- dtype detection ----------------
__global__ void k_detect(const unsigned short* x, int* flag){
    __shared__ int bad;
    if (threadIdx.x == 0) bad = 0;
    __syncthreads();
    int b = 0;
    for (int i = threadIdx.x; i < 4096; i += 256) {
        unsigned e = (x[i] >> 7) & 0xFFu;
        if (e >= 0x90u) b++;
    }
    if (b) atomicAdd(&bad, b);
    __syncthreads();
    if (threadIdx.x == 0) *flag = (bad == 0) ? 1 : 0;   // 1 = bf16, 0 = f32
}

// ---------------- misc ----------------
__global__ void k_zero(float* p, size_t n){
    size_t i = (size_t)blockIdx.x * 256 + threadIdx.x;
    if (i < n) p[i] = 0.f;
}
__global__ void k_flag_us(unsigned short* out, int n, unsigned short val){
    int i = blockIdx.x * 256 + threadIdx.x;
    if (i < n) out[i] = val;
}
__global__ void k_gather_embed(const int* ids, const void* emb, float* out, const int* flagp){
    int i = blockIdx.x * 256 + threadIdx.x;
    if (i >= N_HOSTN * HH) return;
    int isbf = *flagp;
    int node = i >> 7, f = i & 127;
    out[i] = loadf(emb, (size_t)ids[node] * HH + f, isbf);
}
// flow_x [N,97] (flag dtype) -> bf16 padded [N,128]; 8 output cols per thread
__global__ void k_pad_cast(const void* x, unsigned short* o, const int* flagp){
    int i = blockIdx.x * 256 + threadIdx.x;           // 0 .. N_FLOWN*16
    if (i >= N_FLOWN * 16) return;
    int isbf = *flagp;
    int row = i >> 4, c0 = (i & 15) * 8;
    unsigned short v[8];
    #pragma unroll
    for (int j = 0; j < 8; ++j) {
        int c = c0 + j;
        v[j] = (c < FIN) ? f2bf(loadf(x, (size_t)row * FIN + c, isbf)) : (unsigned short)0;
    }
    uint4 ov;
    ov.x = (unsigned)v[0] | ((unsigned)v[1] << 16);
    ov.y = (unsigned)v[2] | ((unsigned)v[3] << 16);
    ov.z = (unsigned)v[4] | ((unsigned)v[5] << 16);
    ov.w = (unsigned)v[6] | ((unsigned)v[7] << 16);
    *(uint4*)(o + (size_t)row * 128 + c0) = ov;
}

// ---------------- one-shot weight prep (833 blocks, region dispatch) ----------------
__global__ __launch_bounds__(256) void k_wprep_all(
    const void* Wr0_h2f, const void* br0_h2f, const void* Wo0_h2f,
    const void* Wr0_f2h, const void* br0_f2h, const void* Wo0_f2h,
    const void* Wr0_rel, const void* br0_rel, const void* Wo0_rel,
    const void* Wr_all, const void* br_all, const void* Wo_all,
    unsigned short* WBT0, unsigned short* WBT1, unsigned short* WBT2,
    float* w_h2f0, float* w_h2f1, float* w_h2f2,
    float* w_f2h0, float* w_f2h1, float* w_of2h0, float* w_of2h1,
    float* b_comb0, float* b_comb1, float* b_comb2, float* b_f2h0, float* b_f2h1,
    const int* flagp)
{
    const int bb = blockIdx.x, t = threadIdx.x;
    const int isbf = *flagp;
    if (bb < 384) {
        int layer = bb >> 7;
        int i = ((bb & 127) << 8) + t;   // 0..32767
        int nn = i >> 7, k = i & 127;
        float v = 0.f;
        if (layer == 0) {
            if (k < FIN) {
                if (nn < 128) v = loadf(Wo0_h2f, (size_t)k*128+nn, isbf) + loadf(Wo0_rel, (size_t)k*128+nn, isbf);
                else          v = loadf(Wr0_rel, (size_t)k*128+(nn-128), isbf);
            }
        } else {
            size_t oW = (size_t)((layer - 1) * 3) * 16384;
            if (nn < 128) v = loadf(Wo_all, oW + (size_t)k*128+nn, isbf)
                            + loadf(Wo_all, oW + 2*16384 + (size_t)k*128+nn, isbf);
            else          v = loadf(Wr_all, oW + 2*16384 + (size_t)k*128+(nn-128), isbf);
        }
        unsigned short* W = (layer == 0) ? WBT0 : ((layer == 1) ? WBT1 : WBT2);
        W[(size_t)nn*128 + k] = f2bf(v);
    } else if (bb < 576) {
        int r = bb - 384; int layer = r >> 6; int i = ((r & 63) << 8) + t;
        float v;
        if (layer == 0) v = loadf(Wr0_h2f, (size_t)i, isbf);
        else            v = loadf(Wr_all, (size_t)((layer-1)*3)*16384 + i, isbf);
        ((layer == 0) ? w_h2f0 : ((layer == 1) ? w_h2f1 : w_h2f2))[i] = v;
    } else if (bb < 640) {
        // w_f2h0 padded to [128][128]: rows k>=97 zero
        int i = ((bb - 576) << 8) + t;
        int k = i >> 7;
        w_f2h0[i] = (k < FIN) ? loadf(Wr0_f2h, (size_t)i, isbf) : 0.f;
    } else if (bb < 704) {
        int i = ((bb - 640) << 8) + t;
        w_f2h1[i] = loadf(Wr_all, (size_t)1*16384 + i, isbf);
    } else if (bb < 768) {
        int i = ((bb - 704) << 8) + t;
        w_of2h0[i] = loadf(Wo0_f2h, (size_t)i, isbf);
    } else if (bb < 832) {
        int i = ((bb - 768) << 8) + t;
        w_of2h1[i] = loadf(Wo_all, (size_t)1*16384 + i, isbf);
    } else {
        if (t < 128) {
            b_comb0[t] = loadf(br0_h2f, t, isbf) + loadf(br0_rel, t, isbf);
            b_comb1[t] = loadf(br_all, 0*128 + t, isbf) + loadf(br_all, 2*128 + t, isbf);
            b_comb2[t] = loadf(br_all, 3*128 + t, isbf) + loadf(br_all, 5*128 + t, isbf);
            b_f2h0[t]  = loadf(br0_f2h, t, isbf);
            b_f2h1[t]  = loadf(br_all, 1*128 + t, isbf);
        }
    }
}

// ============ binned CSR build: NO scattered global atomics ============
//  1) per-block LDS histogram over coarse bins (dst>>8), counts -> [bin][block]
//  2) per-bin scan over blocks + cross-bin scan -> (block,bin) bases
//  3) scatter edges bin-grouped via LDS cursors, packed (src | dstLow<<18)
//  4) one block per bin: LDS 256-hist + scan -> rp (all dsts, coalesced) + ei

// pass 1: per-block coarse-bin counts
__global__ __launch_bounds__(256) void k_binhist(
    const int* __restrict__ rel_dst, const int* __restrict__ h2f_dst,
    const int* __restrict__ f2h_dst, int* __restrict__ cntF, int* __restrict__ cntH)
{
    __shared__ int c[NBIN_F];
    const int t = threadIdx.x, bb = blockIdx.x;
    if (bb < BH_F) {
        for (int i = t; i < NBIN_F; i += 256) c[i] = 0;
        __syncthreads();
        const int e0 = bb * EPB_F;
        for (int i = t; i < EPB_F; i += 256) {
            const int e = e0 + i;
            const int d = (e < E_RELN) ? rel_dst[e] : h2f_dst[e - E_RELN];
            atomicAdd(&c[d >> 8], 1);
        }
        __syncthreads();
        for (int i = t; i < NBIN_F; i += 256) cntF[i * BH_F + bb] = c[i];
    } else {
        const int blk = bb - BH_F;
        for (int i = t; i < NBIN_H; i += 256) c[i] = 0;
        __syncthreads();
        const int e0 = blk * EPB_H;
        for (int i = t; i < EPB_H; i += 256)
            atomicAdd(&c[f2h_dst[e0 + i] >> 8], 1);
        __syncthreads();
        for (int i = t; i < NBIN_H; i += 256) cntH[i * BH_H + blk] = c[i];
    }
}
// pass 2a: per-bin exclusive scan across blocks (in place); bin totals out
__global__ __launch_bounds__(128) void k_binscan1(
    int* __restrict__ cntF, int* __restrict__ cntH,
    int* __restrict__ bintotF, int* __restrict__ bintotH)
{
    __shared__ int s[128];
    const int t = threadIdx.x, b = blockIdx.x;
    int v;
    if (b < NBIN_F) v = (t < BH_F) ? cntF[b * BH_F + t] : 0;
    else            v = (t < BH_H) ? cntH[(b - NBIN_F) * BH_H + t] : 0;
    s[t] = v; __syncthreads();
    for (int off = 1; off < 128; off <<= 1) {
        int x = (t >= off) ? s[t - off] : 0;
        __syncthreads();
        s[t] += x;
        __syncthreads();
    }
    if (b < NBIN_F) {
        if (t < BH_F) cntF[b * BH_F + t] = s[t] - v;
        if (t == 127) bintotF[b] = s[127];
    } else {
        if (t < BH_H) cntH[(b - NBIN_F) * BH_H + t] = s[t] - v;
        if (t == 127) bintotH[b - NBIN_F] = s[127];
    }
}
// pass 2b: exclusive scan across bins (in place: bintot -> binstart)
__global__ __launch_bounds__(256) void k_binscan2(int* aF, int* aH){
    __shared__ int s[256];
    __shared__ int carry;
    int* a; int n;
    if (blockIdx.x == 0) { a = aF; n = NBIN_F; } else { a = aH; n = NBIN_H; }
    const int t = threadIdx.x;
    if (t == 0) carry = 0;
    __syncthreads();
    for (int base = 0; base < n; base += 256) {
        const int i = base + t;
        int v = (i < n) ? a[i] : 0;
        s[t] = v; __syncthreads();
        for (int off = 1; off < 256; off <<= 1) {
            int x = (t >= off) ? s[t - off] : 0;
            __syncthreads();
            s[t] += x;
            __syncthreads();
        }
        int excl = s[t] - v + carry;
        if (i < n) a[i] = excl;
        __syncthreads();
        if (t == 255) carry += s[255];
        __syncthreads();
    }
}
// pass 3: scatter edges into bin-grouped scratch (LDS cursors only)
__global__ __launch_bounds__(256) void k_binscatter(
    const int* __restrict__ rel_src, const int* __restrict__ rel_dst,
    const int* __restrict__ h2f_src, const int* __restrict__ h2f_dst,
    const int* __restrict__ f2h_src, const int* __restrict__ f2h_dst,
    const int* __restrict__ pbF, const int* __restrict__ pbH,
    const int* __restrict__ bsF, const int* __restrict__ bsH,
    unsigned* __restrict__ ebinF, unsigned* __restrict__ ebinH)
{
    __shared__ int base[NBIN_F];
    const int t = threadIdx.x, bb = blockIdx.x;
    if (bb < BH_F) {
        for (int i = t; i < NBIN_F; i += 256) base[i] = bsF[i] + pbF[i * BH_F + bb];
        __syncthreads();
        const int e0 = bb * EPB_F;
        for (int i = t; i < EPB_F; i += 256) {
            const int e = e0 + i;
            int d, sv;
            if (e < E_RELN) { d = rel_dst[e]; sv = rel_src[e]; }
            else            { d = h2f_dst[e - E_RELN]; sv = h2f_src[e - E_RELN] + N_FLOWN; }
            const int pos = atomicAdd(&base[d >> 8], 1);
            ebinF[pos] = (unsigned)sv | ((unsigned)(d & 255) << 18);
        }
    } else {
        const int blk = bb - BH_F;
        for (int i = t; i < NBIN_H; i += 256) base[i] = bsH[i] + pbH[i * BH_H + blk];
        __syncthreads();
        const int e0 = blk * EPB_H;
        for (int i = t; i < EPB_H; i += 256) {
            const int e = e0 + i;
            const int d = f2h_dst[e];
            const int pos = atomicAdd(&base[d >> 8], 1);
            ebinH[pos] = (unsigned)f2h_src[e] | ((unsigned)(d & 255) << 18);
        }
    }
}
// pass 4: per-bin fine CSR (rp for ALL dsts incl. empty; ei scatter in-bin)
__global__ __launch_bounds__(256) void k_bincsr(
    const unsigned* __restrict__ ebinF, const unsigned* __restrict__ ebinH,
    const int* __restrict__ bsF, const int* __restrict__ bsH,
    int* __restrict__ rp_cmb, int* __restrict__ ei_cmb,
    int* __restrict__ rp_f2h, int* __restrict__ ei_f2h)
{
    __shared__ int c[256];
    __shared__ int off[256];
    const int t = threadIdx.x, b = blockIdx.x;
    const unsigned* ebin; int* rp; int* ei; int seg0, seg1, dstbase, ndst;
    if (b < NBIN_F) {
        ebin = ebinF; rp = rp_cmb; ei = ei_cmb;
        seg0 = bsF[b]; seg1 = (b == NBIN_F - 1) ? E_CMBN : bsF[b + 1];
        dstbase = b * 256; ndst = min(256, N_FLOWN - dstbase);
        if (b == 0 && t == 0) rp_cmb[N_FLOWN] = E_CMBN;
    } else {
        const int bh = b - NBIN_F;
        ebin = ebinH; rp = rp_f2h; ei = ei_f2h;
        seg0 = bsH[bh]; seg1 = (bh == NBIN_H - 1) ? E_HFN : bsH[bh + 1];
        dstbase = bh * 256; ndst = min(256, N_HOSTN - dstbase);
        if (bh == 0 && t == 0) rp_f2h[N_HOSTN] = E_HFN;
    }
    c[t] = 0;
    __syncthreads();
    for (int i = seg0 + t; i < seg1; i += 256)
        atomicAdd(&c[ebin[i] >> 18], 1);
    __syncthreads();
    const int v = c[t];
    for (int o = 1; o < 256; o <<= 1) {
        int x = (t >= o) ? c[t - o] : 0;
        __syncthreads();
        c[t] += x;
        __syncthreads();
    }
    const int excl = c[t] - v;
    if (t < ndst) rp[dstbase + t] = seg0 + excl;
    off[t] = seg0 + excl;
    __syncthreads();
    for (int i = seg0 + t; i < seg1; i += 256) {
        const unsigned u = ebin[i];
        const int pos = atomicAdd(&off[u >> 18], 1);
        ei[pos] = (int)(u & 0x3FFFFu);
    }
}

// ---------------- host-sized VALU GEMM: Y[M,128] (+)= X[M,K]@W[K,128]+b ---------
__global__ __launch_bounds__(256) void k_gemm128(
    const void* X, int xmode, const float* W, const float* bias,
    void* Y, int ybf, int M, int K, int accum, int dorelu, const int* flagp)
{
    const int isbf = (xmode == 2) ? *flagp : xmode;
    const int tid  = threadIdx.x;
    const int row0 = blockIdx.x * 16;
    __shared__ float sX[16][132];
    if (!isbf && (K & 3) == 0) {
        // vectorized f32 staging (all current call sites)
        const int kq = K >> 2;
        for (int i = tid; i < 16 * kq; i += 256) {
            int r = i / kq, c4 = (i - r * kq) * 4;
            int gr = row0 + r;
            float4 v = {0.f, 0.f, 0.f, 0.f};
            if (gr < M) v = *(const float4*)((const float*)X + (size_t)gr * K + c4);
            *(float4*)&sX[r][c4] = v;
        }
    } else {
        const int total = 16 * K;
        for (int i = tid; i < total; i += 256) {
            int r = i / K, c = i - r * K;
            int gr = row0 + r;
            sX[r][c] = (gr < M) ? loadf(X, (size_t)gr * K + c, isbf) : 0.f;
        }
    }
    __syncthreads();

    const int c4 = (tid & 31) * 4;
    const int rb = tid >> 5;
    float a0x=0,a0y=0,a0z=0,a0w=0, a1x=0,a1y=0,a1z=0,a1w=0;
    #pragma unroll 4
    for (int k = 0; k < K; ++k) {
        const float4 w = *(const float4*)(W + (size_t)k * 128 + c4);
        const float x0 = sX[rb][k];
        const float x1 = sX[rb + 8][k];
        a0x = fmaf(x0, w.x, a0x); a0y = fmaf(x0, w.y, a0y);
        a0z = fmaf(x0, w.z, a0z); a0w = fmaf(x0, w.w, a0w);
        a1x = fmaf(x1, w.x, a1x); a1y = fmaf(x1, w.y, a1y);
        a1z = fmaf(x1, w.z, a1z); a1w = fmaf(x1, w.w, a1w);
    }
    float bx=0, by=0, bz=0, bw=0;
    if (bias) { const float4 b = *(const float4*)(bias + c4); bx=b.x; by=b.y; bz=b.z; bw=b.w; }

    #pragma unroll
    for (int h = 0; h < 2; ++h) {
        const int rr = row0 + rb + (h ? 8 : 0);
        if (rr >= M) continue;
        float v0 = (h?a1x:a0x)+bx, v1 = (h?a1y:a0y)+by;
        float v2 = (h?a1z:a0z)+bz, v3 = (h?a1w:a0w)+bw;
        if (ybf) {
            unsigned short* p = (unsigned short*)Y + (size_t)rr * 128 + c4;
            ushort4 o; o.x=f2bf(v0); o.y=f2bf(v1); o.z=f2bf(v2); o.w=f2bf(v3);
            *(ushort4*)p = o;
        } else {
            float* p = (float*)Y + (size_t)rr * 128 + c4;
            if (accum) { v0+=p[0]; v1+=p[1]; v2+=p[2]; v3+=p[3]; }
            if (dorelu) { v0=fmaxf(v0,0.f); v1=fmaxf(v1,0.f); v2=fmaxf(v2,0.f); v3=fmaxf(v3,0.f); }
            float4 o; o.x=v0; o.y=v1; o.z=v2; o.w=v3;
            *(float4*)p = o;
        }
    }
}

// ---------------- fused dual-input host GEMM: Y = relu(X1@W1 + X2@W2 + b) ------
__global__ __launch_bounds__(256) void k_gemm2in(
    const float* __restrict__ X1, const float* __restrict__ X2,
    const float* __restrict__ W1, const float* __restrict__ W2,
    const float* __restrict__ bias, float* __restrict__ Y, int M)
{
    const int tid  = threadIdx.x;
    const int row0 = blockIdx.x * 16;
    __shared__ float sX1[16][132];
    __shared__ float sX2[16][132];
    for (int i = tid; i < 16 * 32; i += 256) {
        int r = i >> 5, c4 = (i & 31) * 4;
        int gr = row0 + r;
        float4 v1 = {0.f, 0.f, 0.f, 0.f}, v2 = {0.f, 0.f, 0.f, 0.f};
        if (gr < M) {
            v1 = *(const float4*)(X1 + (size_t)gr * 128 + c4);
            v2 = *(const float4*)(X2 + (size_t)gr * 128 + c4);
        }
        *(float4*)&sX1[r][c4] = v1;
        *(float4*)&sX2[r][c4] = v2;
    }
    __syncthreads();

    const int c4 = (tid & 31) * 4;
    const int rb = tid >> 5;
    float a0x=0,a0y=0,a0z=0,a0w=0, a1x=0,a1y=0,a1z=0,a1w=0;
    #pragma unroll 4
    for (int k = 0; k < 128; ++k) {
        const float4 w = *(const float4*)(W1 + (size_t)k * 128 + c4);
        const float x0 = sX1[rb][k];
        const float x1 = sX1[rb + 8][k];
        a0x = fmaf(x0, w.x, a0x); a0y = fmaf(x0, w.y, a0y);
        a0z = fmaf(x0, w.z, a0z); a0w = fmaf(x0, w.w, a0w);
        a1x = fmaf(x1, w.x, a1x); a1y = fmaf(x1, w.y, a1y);
        a1z = fmaf(x1, w.z, a1z); a1w = fmaf(x1, w.w, a1w);
    }
    #pragma unroll 4
    for (int k = 0; k < 128; ++k) {
        const float4 w = *(const float4*)(W2 + (size_t)k * 128 + c4);
        const float x0 = sX2[rb][k];
        const float x1 = sX2[rb + 8][k];
        a0x = fmaf(x0, w.x, a0x); a0y = fmaf(x0, w.y, a0y);
        a0z = fmaf(x0, w.z, a0z); a0w = fmaf(x0, w.w, a0w);
        a1x = fmaf(x1, w.x, a1x); a1y = fmaf(x1, w.y, a1y);
        a1z = fmaf(x1, w.z, a1z); a1w = fmaf(x1, w.w, a1w);
    }
    const float4 b = *(const float4*)(bias + c4);
    #pragma unroll
    for (int h = 0; h < 2; ++h) {
        const int rr = row0 + rb + (h ? 8 : 0);
        if (rr >= M) continue;
        float4 o;
        o.x = fmaxf((h?a1x:a0x) + b.x, 0.f);
        o.y = fmaxf((h?a1y:a0y) + b.y, 0.f);
        o.z = fmaxf((h?a1z:a0z) + b.z, 0.f);
        o.w = fmaxf((h?a1w:a0w) + b.w, 0.f);
        *(float4*)(Y + (size_t)rr * 128 + c4) = o;
    }
}

// ---------------- MFMA dual flow GEMM: both outputs bf16, no bias ----------------
// All global traffic linearized: A staged once per block into XOR-swizzled LDS
// via linear uint4 loads; output bounced through LDS and stored with linear
// uint4 stores. 8 waves x 32 WBT rows (B = 8 bfrags in regs), LB(512,4).
typedef __attribute__((ext_vector_type(8))) short bfrag;
typedef __attribute__((ext_vector_type(4))) float f32x4;

#define GEMM_CHUNKS 4
#define GEMM_MROWS  (32 * GEMM_CHUNKS)   // 128 rows per block

__global__ __launch_bounds__(512, 4) void k_gemm_mfma(
    const unsigned short* __restrict__ Abf, const unsigned short* __restrict__ WBT,
    unsigned short* __restrict__ Y1, unsigned short* __restrict__ Y2, int M)
{
    __shared__ unsigned short sA[32 * 128];      // 8 KB, XOR-swizzled 16B units
    __shared__ unsigned short sO[2][32][136];    // 17.4 KB out-stage (pad 8 shorts)

    const int tid  = threadIdx.x;
    const int wave = tid >> 6;        // 0..7
    const int lane = tid & 63;
    const int quad = lane >> 4;
    const int l16  = lane & 15;
    const int nbase = wave * 32;      // 32 WBT rows per wave

    // B slice for this wave's 32 output cols: breg[c][j] (8 bfrags = 32 regs)
    bfrag breg[4][2];
    #pragma unroll
    for (int c = 0; c < 4; ++c)
        #pragma unroll
        for (int j = 0; j < 2; ++j)
            breg[c][j] = *(const bfrag*)(WBT + (size_t)(nbase + j * 16 + l16) * 128
                                              + c * 32 + quad * 8);

    const int ybuf = (nbase < 128) ? 0 : 1;
    const int colb = nbase & 127;
    const f32x4 zero = {0.f, 0.f, 0.f, 0.f};

    const int srow = tid >> 4;        // staging row 0..31
    const int su   = tid & 15;        // staging 16B unit 0..15

    for (int chunk = 0; chunk < GEMM_CHUNKS; ++chunk) {
        const int m0 = blockIdx.x * GEMM_MROWS + chunk * 32;
        if (m0 >= M) break;           // block-uniform (M % 32 == 0)

        // ---- stage A chunk (32x128 bf16 = 8KB): linear load, swizzled LDS ----
        {
            const uint4* gsrc = (const uint4*)(Abf + (size_t)m0 * 128);
            uint4* sdst = (uint4*)sA;
            sdst[srow * 16 + (su ^ (srow & 15))] = gsrc[tid];
        }
        __syncthreads();

        // ---- fragments from LDS + MFMA ----
        bfrag a0[4], a1[4];
        #pragma unroll
        for (int c = 0; c < 4; ++c) {
            const int un = (c * 4 + quad) ^ l16;
            a0[c] = *(const bfrag*)(sA + (size_t)(l16)      * 128 + un * 8);
            a1[c] = *(const bfrag*)(sA + (size_t)(16 + l16) * 128 + un * 8);
        }
        f32x4 acc[2][2];
        #pragma unroll
        for (int j = 0; j < 2; ++j) {
            acc[0][j] = __builtin_amdgcn_mfma_f32_16x16x32_bf16(breg[0][j], a0[0], zero, 0, 0, 0);
            acc[1][j] = __builtin_amdgcn_mfma_f32_16x16x32_bf16(breg[0][j], a1[0], zero, 0, 0, 0);
        }
        #pragma unroll
        for (int c = 1; c < 4; ++c)
            #pragma unroll
            for (int j = 0; j < 2; ++j) {
                acc[0][j] = __builtin_amdgcn_mfma_f32_16x16x32_bf16(breg[c][j], a0[c], acc[0][j], 0, 0, 0);
                acc[1][j] = __builtin_amdgcn_mfma_f32_16x16x32_bf16(breg[c][j], a1[c], acc[1][j], 0, 0, 0);
            }

        // ---- stage D' to LDS (D' layout: col(l16)=row m, row(quad*4+r)=col n) ----
        #pragma unroll
        for (int i = 0; i < 2; ++i) {
            const int row = i * 16 + l16;
            #pragma unroll
            for (int j = 0; j < 2; ++j) {
                const int col = colb + j * 16 + quad * 4;
                uint2 o;
                o.x = (unsigned)f2bf(acc[i][j][0]) | ((unsigned)f2bf(acc[i][j][1]) << 16);
                o.y = (unsigned)f2bf(acc[i][j][2]) | ((unsigned)f2bf(acc[i][j][3]) << 16);
                *(uint2*)&sO[ybuf][row][col] = o;
            }
        }
        __syncthreads();

        // ---- linear coalesced stores: 1KB-contiguous per wave instruction ----
        {
            const size_t goff = (size_t)(m0 + srow) * 128 + su * 8;
            *(uint4*)(Y1 + goff) = *(const uint4*)&sO[0][srow][su * 8];
            *(uint4*)(Y2 + goff) = *(const uint4*)&sO[1][srow][su * 8];
        }
        __syncthreads();
    }
}

// ---------------- persistent-wave combined CSR aggregation (flow dsts) ----------
// QUARTER-PER-DST: each 16-lane quarter owns one dst entirely (16 lanes x 8
// features = 128). Per outer iteration the wave processes 4 CONSECUTIVE dsts in
// parallel: no cross-quarter reduce, epilogue amortized 4x, root loads / stores
// are 4 consecutive rows = 1 KiB contiguous per instruction.
// Edge-index window staged to LDS once per wave (contiguous CSR range).
__global__ __launch_bounds__(256) void k_agg_flow(
    const unsigned short* __restrict__ Z,
    const int* __restrict__ rp, const int* __restrict__ ei,
    const unsigned short* __restrict__ root, const float* __restrict__ bias,
    unsigned short* __restrict__ Xout, int do_relu)
{
    __shared__ int sIdx[4][AGG_CAP];
    const int wave = threadIdx.x >> 6;
    const int lane = threadIdx.x & 63;
    const int q    = lane >> 4;
    const int l16  = lane & 15;
    const int f8   = l16 * 8;
    const int gw   = blockIdx.x * 4 + wave;
    const int d0   = gw * AGGF_DPW;
    const int nd   = min(AGGF_DPW, N_FLOWN - d0);   // may be <= 0 for tail waves

    int rpv = 0, W0 = 0, Wcap = 0;
    if (nd > 0) {
        rpv = (lane <= nd) ? rp[d0 + lane] : 0;
        W0 = __shfl(rpv, 0, 64);
        const int Wn = __shfl(rpv, nd, 64);
        const int cw = min(Wn - W0, AGG_CAP);
        for (int i = lane; i < cw; i += 64) sIdx[wave][i] = ei[W0 + i];
        Wcap = W0 + cw;
    }
    __syncthreads();
    if (nd <= 0) return;

    // loop-invariant bias slice
    const float4 bva = *(const float4*)(bias + f8);
    const float4 bvb = *(const float4*)(bias + f8 + 4);

    #pragma unroll 2
    for (int i = 0; i < AGGF_DPW / 4; ++i) {
        const int dqi = i * 4 + q;              // this quarter's dst offset
        const bool act = dqi < nd;
        const int srcl = act ? dqi : 0;
        const int b0 = __shfl(rpv, srcl, 64);
        const int b1 = __shfl(rpv, srcl + 1, 64);
        const int d  = d0 + dqi;

        uint4 rv = {0, 0, 0, 0};
        if (act) rv = *(const uint4*)(root + (size_t)d * 128 + f8);

        float a[8] = {0.f, 0.f, 0.f, 0.f, 0.f, 0.f, 0.f, 0.f};
        int n = act ? (b1 - b0) : 0;
        int e = b0;
        while (n >= 4) {
            const int s0 = (e     < Wcap) ? sIdx[wave][e     - W0] : ei[e];
            const int s1 = (e + 1 < Wcap) ? sIdx[wave][e + 1 - W0] : ei[e + 1];
            const int s2 = (e + 2 < Wcap) ? sIdx[wave][e + 2 - W0] : ei[e + 2];
            const int s3 = (e + 3 < Wcap) ? sIdx[wave][e + 3 - W0] : ei[e + 3];
            const uint4 z0 = *(const uint4*)(Z + (size_t)s0 * 128 + f8);
            const uint4 z1 = *(const uint4*)(Z + (size_t)s1 * 128 + f8);
            const uint4 z2 = *(const uint4*)(Z + (size_t)s2 * 128 + f8);
            const uint4 z3 = *(const uint4*)(Z + (size_t)s3 * 128 + f8);
            acc8(a, z0); acc8(a, z1); acc8(a, z2); acc8(a, z3);
            e += 4; n -= 4;
        }
        if (n & 2) {
            const int s0 = (e     < Wcap) ? sIdx[wave][e     - W0] : ei[e];
            const int s1 = (e + 1 < Wcap) ? sIdx[wave][e + 1 - W0] : ei[e + 1];
            const uint4 z0 = *(const uint4*)(Z + (size_t)s0 * 128 + f8);
            const uint4 z1 = *(const uint4*)(Z + (size_t)s1 * 128 + f8);
            acc8(a, z0); acc8(a, z1);
            e += 2;
        }
        if (n & 1) {
            const int s0 = (e < Wcap) ? sIdx[wave][e - W0] : ei[e];
            const uint4 z0 = *(const uint4*)(Z + (size_t)s0 * 128 + f8);
            acc8(a, z0);
        }

        if (act) {
            float v0 = a[0] + __uint_as_float(rv.x << 16)         + bva.x;
            float v1 = a[1] + __uint_as_float(rv.x & 0xFFFF0000u) + bva.y;
            float v2 = a[2] + __uint_as_float(rv.y << 16)         + bva.z;
            float v3 = a[3] + __uint_as_float(rv.y & 0xFFFF0000u) + bva.w;
            float v4 = a[4] + __uint_as_float(rv.z << 16)         + bvb.x;
            float v5 = a[5] + __uint_as_float(rv.z & 0xFFFF0000u) + bvb.y;
            float v6 = a[6] + __uint_as_float(rv.w << 16)         + bvb.z;
            float v7 = a[7] + __uint_as_float(rv.w & 0xFFFF0000u) + bvb.w;
            if (do_relu) {
                v0 = fmaxf(v0, 0.f); v1 = fmaxf(v1, 0.f); v2 = fmaxf(v2, 0.f); v3 = fmaxf(v3, 0.f);
                v4 = fmaxf(v4, 0.f); v5 = fmaxf(v5, 0.f); v6 = fmaxf(v6, 0.f); v7 = fmaxf(v7, 0.f);
            }
            uint4 o;
            o.x = (unsigned)f2bf(v0) | ((unsigned)f2bf(v1) << 16);
            o.y = (unsigned)f2bf(v2) | ((unsigned)f2bf(v3) << 16);
            o.z = (unsigned)f2bf(v4) | ((unsigned)f2bf(v5) << 16);
            o.w = (unsigned)f2bf(v6) | ((unsigned)f2bf(v7) << 16);
            *(uint4*)(Xout + (size_t)d * 128 + f8) = o;
        }
    }
}

// host dst: out[d][0:128] = sum f2h Z[src][0:128]  (f32 out)
// Same quarter-per-dst persistent structure.
__global__ __launch_bounds__(256) void k_agg_host(
    const unsigned short* __restrict__ Z, const int* __restrict__ rp,
    const int* __restrict__ ei, float* __restrict__ out)
{
    __shared__ int sIdx[4][AGG_CAP];
    const int wave = threadIdx.x >> 6;
    const int lane = threadIdx.x & 63;
    const int q    = lane >> 4;
    const int l16  = lane & 15;
    const int f8   = l16 * 8;
    const int gw   = blockIdx.x * 4 + wave;
    const int d0   = gw * AGGH_DPW;
    const int nd   = min(AGGH_DPW, N_HOSTN - d0);

    int rpv = 0, W0 = 0, Wcap = 0;
    if (nd > 0) {
        rpv = (lane <= nd) ? rp[d0 + lane] : 0;
        W0 = __shfl(rpv, 0, 64);
        const int Wn = __shfl(rpv, nd, 64);
        const int cw = min(Wn - W0, AGG_CAP);
        for (int i = lane; i < cw; i += 64) sIdx[wave][i] = ei[W0 + i];
        Wcap = W0 + cw;
    }
    __syncthreads();
    if (nd <= 0) return;

    #pragma unroll
    for (int i = 0; i < AGGH_DPW / 4; ++i) {
        const int dqi = i * 4 + q;
        const bool act = dqi < nd;
        const int srcl = act ? dqi : 0;
        const int b0 = __shfl(rpv, srcl, 64);
        const int b1 = __shfl(rpv, srcl + 1, 64);
        const int d  = d0 + dqi;

        float a[8] = {0.f, 0.f, 0.f, 0.f, 0.f, 0.f, 0.f, 0.f};
        int n = act ? (b1 - b0) : 0;
        int e = b0;
        while (n >= 4) {
            const int s0 = (e     < Wcap) ? sIdx[wave][e     - W0] : ei[e];
            const int s1 = (e + 1 < Wcap) ? sIdx[wave][e + 1 - W0] : ei[e + 1];
            const int s2 = (e + 2 < Wcap) ? sIdx[wave][e + 2 - W0] : ei[e + 2];
            const int s3 = (e + 3 < Wcap) ? sIdx[wave][e + 3 - W0] : ei[e + 3];
            const uint4 z0 = *(const uint4*)(Z + (size_t)s0 * 128 + f8);
            const uint4 z1 = *(const uint4*)(Z + (size_t)s1 * 128 + f8);
            const uint4 z2 = *(const uint4*)(Z + (size_t)s2 * 128 + f8);
            const uint4 z3 = *(const uint4*)(Z + (size_t)s3 * 128 + f8);
            acc8(a, z0); acc8(a, z1); acc8(a, z2); acc8(a, z3);
            e += 4; n -= 4;
        }
        if (n & 2) {
            const int s0 = (e     < Wcap) ? sIdx[wave][e     - W0] : ei[e];
            const int s1 = (e + 1 < Wcap) ? sIdx[wave][e + 1 - W0] : ei[e + 1];
            const uint4 z0 = *(const uint4*)(Z + (size_t)s0 * 128 + f8);
            const uint4 z1 = *(const uint4*)(Z + (size_t)s1 * 128 + f8);
            acc8(a, z0); acc8(a, z1);
            e += 2;
        }
        if (n & 1) {
            const int s0 = (e < Wcap) ? sIdx[wave][e - W0] : ei[e];
            const uint4 z0 = *(const uint4*)(Z + (size_t)s0 * 128 + f8);
            acc8(a, z0);
        }

        if (act) {
            float4 oa, ob;
            oa.x = a[0]; oa.y = a[1]; oa.z = a[2]; oa.w = a[3];
            ob.x = a[4]; ob.y = a[5]; ob.z = a[6]; ob.w = a[7];
            *(float4*)(out + (size_t)d * 128 + f8)     = oa;
            *(float4*)(out + (size_t)d * 128 + f8 + 4) = ob;
        }
    }
}

// ---------------- pooling over sorted batch (bf16 input) ----------------
// v11: R10 counters (dur 65us, HBM 5%, VALU 6%) exposed a scalar 2B-load
// 128-iteration serial walk. Now: 256 thr/block, thread = (row-slot, 8 cols),
// uint4 loads (8 bf16/instr), 8 rows/thread. Fast path (block entirely in one
// batch group, ~96% of blocks): LDS atomicMax combine then 128 coalesced
// global atomicMax. Slow path (group boundary in block): per-slot sequential
// walk with group tracking, direct flushes (rare).
#define PCHUNK 128
__global__ __launch_bounds__(256) void k_pool2(const unsigned short* __restrict__ xf,
                                               const int* __restrict__ batch,
                                               unsigned* __restrict__ bits){
    const int t  = threadIdx.x;
    const int i0 = blockIdx.x * PCHUNK;
    if (i0 >= N_FLOWN) return;
    const int nrows = min(PCHUNK, N_FLOWN - i0);
    const int slot = t >> 4;           // 16 slots of 8 contiguous rows
    const int c0   = (t & 15) * 8;     // 8 columns per thread
    const int r0   = i0 + slot * 8;
    const int rend = i0 + nrows;

    const int gfirst = batch[i0];
    const int glast  = batch[rend - 1];

    if (gfirst == glast) {
        // ---- fast path: whole chunk in one group ----
        __shared__ unsigned smb[128];
        if (t < 128) smb[t] = 0u;
        __syncthreads();
        float m[8];
        #pragma unroll
        for (int k = 0; k < 8; ++k) m[k] = -3.4e38f;
        #pragma unroll
        for (int j = 0; j < 8; ++j) {
            const int r = r0 + j;
            if (r < rend) {
                const uint4 z = *(const uint4*)(xf + (size_t)r * 128 + c0);
                max8(m, z);
            }
        }
        #pragma unroll
        for (int k = 0; k < 8; ++k) atomicMax(&smb[c0 + k], f2ord(m[k]));
        __syncthreads();
        if (t < 128) {
            const unsigned v = smb[t];
            if (v) atomicMax(&bits[(size_t)gfirst * 128 + t], v);
        }
    } else {
        // ---- slow path: group boundary inside chunk (rare) ----
        float m[8];
        #pragma unroll
        for (int k = 0; k < 8; ++k) m[k] = -3.4e38f;
        int curg = (r0 < rend) ? batch[r0] : -1;
        for (int j = 0; j < 8; ++j) {
            const int r = r0 + j;
            if (r >= rend) break;
            const int g = batch[r];
            if (g != curg) {
                #pragma unroll
                for (int k = 0; k < 8; ++k) {
                    atomicMax(&bits[(size_t)curg * 128 + c0 + k], f2ord(m[k]));
                    m[k] = -3.4e38f;
                }
                curg = g;
            }
            const uint4 z = *(const uint4*)(xf + (size_t)r * 128 + c0);
            max8(m, z);
        }
        if (curg >= 0) {
            #pragma unroll
            for (int k = 0; k < 8; ++k)
                atomicMax(&bits[(size_t)curg * 128 + c0 + k], f2ord(m[k]));
        }
    }
}

// ---------------- classifier ----------------
__global__ __launch_bounds__(128) void k_classifier(
    const unsigned* bits,
    const void* Wc1, const void* bc1, const void* Wc2, const void* bc2,
    const void* Wc3, const void* bc3, void* out, const int* flagp)
{
    const int g = blockIdx.x, t = threadIdx.x;
    const int isbf = *flagp;
    __shared__ float sp[128], sh1[64], sh2[128];
    {
        unsigned ord = bits[(size_t)g * HH + t];
        unsigned u = (ord & 0x80000000u) ? (ord & 0x7FFFFFFFu) : ~ord;
        sp[t] = __uint_as_float(u);
    }
    __syncthreads();
    if (t < 64) {
        float a = loadf(bc1, t, isbf);
        #pragma unroll 4
        for (int k = 0; k < 128; ++k) a = fmaf(sp[k], loadf(Wc1, k * 64 + t, isbf), a);
        sh1[t] = fmaxf(a, 0.f);
    }
    __syncthreads();
    {
        float a = loadf(bc2, t, isbf);
        #pragma unroll 4
        for (int k = 0; k < 64; ++k) a = fmaf(sh1[k], loadf(Wc2, k * 128 + t, isbf), a);
        sh2[t] = fmaxf(a, 0.f);
    }
    __syncthreads();
    if (t < NCN) {
        float a = loadf(bc3, t, isbf);
        #pragma unroll 4
        for (int k = 0; k < 128; ++k) a = fmaf(sh2[k], loadf(Wc3, k * NCN + t, isbf), a);
        if (isbf) ((unsigned short*)out)[(size_t)g * NCN + t] = f2bf(a);
        else      ((float*)out)[(size_t)g * NCN + t] = a;
    }
}

extern "C" void kernel_launch(void* const* d_in, const int* in_sizes, int n_in,
                              void* d_out, int out_size, void* d_ws, size_t ws_size,
                              hipStream_t stream)
{
    const int*  host_ids   = (const int*) d_in[0];
    const void* flow_x     = d_in[1];
    const int*  h2f_src    = (const int*) d_in[2];
    const int*  h2f_dst    = (const int*) d_in[3];
    const int*  f2h_src    = (const int*) d_in[4];
    const int*  f2h_dst    = (const int*) d_in[5];
    const int*  rel_src    = (const int*) d_in[6];
    const int*  rel_dst    = (const int*) d_in[7];
    const int*  flow_batch = (const int*) d_in[8];
    const void* host_embed = d_in[9];
    const void* Wr0_h2f = d_in[10]; const void* br0_h2f = d_in[11]; const void* Wo0_h2f = d_in[12];
    const void* Wr0_f2h = d_in[13]; const void* br0_f2h = d_in[14]; const void* Wo0_f2h = d_in[15];
    const void* Wr0_rel = d_in[16]; const void* br0_rel = d_in[17]; const void* Wo0_rel = d_in[18];
    const void* Wr_all  = d_in[19];
    const void* br_all  = d_in[20];
    const void* Wo_all  = d_in[21];
    const void* Wc1 = d_in[22]; const void* bc1 = d_in[23];
    const void* Wc2 = d_in[24]; const void* bc2 = d_in[25];
    const void* Wc3 = d_in[26]; const void* bc3 = d_in[27];

    // -------- workspace (~198 MB; CSR scratch aliased onto HA/HB) --------
    size_t off = 0;
    auto alloc = [&](size_t bytes) -> char* {
        char* p = (char*)d_ws + off;
        off += (bytes + 255) & ~(size_t)255;
        return p;
    };
    unsigned short* F1bf  = (unsigned short*)alloc((size_t)N_FLOWN * HH * 2);  // state
    unsigned short* Froot = (unsigned short*)alloc((size_t)N_FLOWN * HH * 2);  // root term
    // ZALL: flow-transformed rows [0,200k) followed by host-transformed rows [200k,220k)
    unsigned short* ZALL  = (unsigned short*)alloc((size_t)(N_FLOWN + N_HOSTN) * HH * 2);
    unsigned short* F2bf  = ZALL;                                   // z_rel
    unsigned short* HCbf  = ZALL + (size_t)N_FLOWN * HH;            // z_h
    float* HA = (float*)alloc((size_t)N_HOSTN * HH * 4);
    float* HB = (float*)alloc((size_t)N_HOSTN * HH * 4);
    float* HD = (float*)alloc((size_t)N_HOSTN * HH * 4);
    unsigned short* WBT0 = (unsigned short*)alloc(256 * 128 * 2);
    unsigned short* WBT1 = (unsigned short*)alloc(256 * 128 * 2);
    unsigned short* WBT2 = (unsigned short*)alloc(256 * 128 * 2);
    float* w_h2f0  = (float*)alloc(128 * 128 * 4);
    float* w_h2f1  = (float*)alloc(128 * 128 * 4);
    float* w_h2f2  = (float*)alloc(128 * 128 * 4);
    float* w_f2h0  = (float*)alloc(128 * 128 * 4);
    float* w_f2h1  = (float*)alloc(128 * 128 * 4);
    float* w_of2h0 = (float*)alloc(128 * 128 * 4);
    float* w_of2h1 = (float*)alloc(128 * 128 * 4);
    float* b_comb0 = (float*)alloc(128 * 4);
    float* b_comb1 = (float*)alloc(128 * 4);
    float* b_comb2 = (float*)alloc(128 * 4);
    float* b_f2h0  = (float*)alloc(128 * 4);
    float* b_f2h1  = (float*)alloc(128 * 4);
    unsigned* poolbits = (unsigned*)alloc(GG * HH * 4);
    int* flagp = (int*)alloc(256);
    int* rp_cmb = (int*)alloc((N_FLOWN + 1) * 4);
    int* ei_cmb = (int*)alloc((size_t)E_CMBN * 4);
    int* rp_f2h = (int*)alloc((N_HOSTN + 1) * 4);
    int* ei_f2h = (int*)alloc((size_t)E_HFN * 4);
    // CSR-build scratch aliased onto buffers first written AFTER the build
    // (stream-ordered): ebin arrays (6.4 MB) live in HA (10.24 MB, first write =
    // k_gather_embed); count/prefix matrices (~412 KB) live in HB (first write =
    // k_gemm2in).
    unsigned* ebinF = (unsigned*)HA;          // E_CMBN uints = 4.8 MB
    unsigned* ebinH = ebinF + E_CMBN;         // E_HFN uints = 1.6 MB (total 6.4)
    int* cntF    = (int*)HB;                  // NBIN_F*BH_F = 100096 ints
    int* cntH    = cntF + NBIN_F * BH_F;      // NBIN_H*BH_H = 2528 ints
    int* bintotF = cntH + NBIN_H * BH_H;      // NBIN_F ints
    int* bintotH = bintotF + NBIN_F;          // NBIN_H ints

    const int T = 256;
    #define GRID1(n) dim3(cdiv((long long)(n), T)), dim3(T), 0, stream

    if (off > ws_size) {
        k_flag_us<<<GRID1(out_size)>>>((unsigned short*)d_out, out_size, (unsigned short)0x4000);
        return;
    }

    k_detect<<<dim3(1), dim3(256), 0, stream>>>((const unsigned short*)flow_x, flagp);

    // -------- binned CSR build (no scattered global atomics) --------
    k_binhist   <<<dim3(BH_F + BH_H), dim3(256), 0, stream>>>(rel_dst, h2f_dst, f2h_dst, cntF, cntH);
    k_binscan1  <<<dim3(NBIN_ALL), dim3(128), 0, stream>>>(cntF, cntH, bintotF, bintotH);
    k_binscan2  <<<dim3(2), dim3(256), 0, stream>>>(bintotF, bintotH);   // -> binstarts
    k_binscatter<<<dim3(BH_F + BH_H), dim3(256), 0, stream>>>(
        rel_src, rel_dst, h2f_src, h2f_dst, f2h_src, f2h_dst,
        cntF, cntH, bintotF, bintotH, ebinF, ebinH);
    k_bincsr    <<<dim3(NBIN_ALL), dim3(256), 0, stream>>>(
        ebinF, ebinH, bintotF, bintotH, rp_cmb, ei_cmb, rp_f2h, ei_f2h);

    // -------- weight prep (1 launch) --------
    k_wprep_all<<<dim3(833), dim3(256), 0, stream>>>(
        Wr0_h2f, br0_h2f, Wo0_h2f, Wr0_f2h, br0_f2h, Wo0_f2h, Wr0_rel, br0_rel, Wo0_rel,
        Wr_all, br_all, Wo_all,
        WBT0, WBT1, WBT2, w_h2f0, w_h2f1, w_h2f2,
        w_f2h0, w_f2h1, w_of2h0, w_of2h1,
        b_comb0, b_comb1, b_comb2, b_f2h0, b_f2h1, flagp);

    // ================= layer 0 =================
    k_gather_embed<<<GRID1(N_HOSTN * HH)>>>(host_ids, host_embed, HA, flagp);
    k_pad_cast<<<GRID1(N_FLOWN * 16)>>>(flow_x, F1bf, flagp);
    // host path: gather bf16 input features (K padded to 128); fused dual GEMM + relu
    k_agg_host<<<dim3(AGGH_BLK), dim3(256), 0, stream>>>(F1bf, rp_f2h, ei_f2h, HD);
    k_gemm2in<<<dim3(cdiv(N_HOSTN,16)), dim3(256), 0, stream>>>(HD, HA, w_f2h0, w_of2h0, b_f2h0, HB, N_HOSTN);
    // flow path
    k_gemm128<<<dim3(cdiv(N_HOSTN,16)), dim3(256), 0, stream>>>(HA, 0, w_h2f0, nullptr, HCbf, 1, N_HOSTN, 128, 0, 0, flagp);
    k_gemm_mfma<<<dim3(cdiv(N_FLOWN, GEMM_MROWS)), dim3(512), 0, stream>>>(F1bf, WBT0, Froot, F2bf, N_FLOWN);
    k_agg_flow<<<dim3(AGGF_BLK), dim3(256), 0, stream>>>(ZALL, rp_cmb, ei_cmb,
                                                         Froot, b_comb0, F1bf, 1);

    // ================= stacked layer 0 =================
    k_agg_host<<<dim3(AGGH_BLK), dim3(256), 0, stream>>>(F1bf, rp_f2h, ei_f2h, HD);
    k_gemm128<<<dim3(cdiv(N_HOSTN,16)), dim3(256), 0, stream>>>(HB, 0, w_h2f1, nullptr, HCbf, 1, N_HOSTN, 128, 0, 0, flagp);
    k_gemm_mfma<<<dim3(cdiv(N_FLOWN, GEMM_MROWS)), dim3(512), 0, stream>>>(F1bf, WBT1, Froot, F2bf, N_FLOWN);
    k_agg_flow<<<dim3(AGGF_BLK), dim3(256), 0, stream>>>(ZALL, rp_cmb, ei_cmb,
                                                         Froot, b_comb1, F1bf, 1);
    k_gemm2in<<<dim3(cdiv(N_HOSTN,16)), dim3(256), 0, stream>>>(HD, HB, w_f2h1, w_of2h1, b_f2h1, HA, N_HOSTN);

    // ================= stacked layer 1 (last; no host update, no relu) =================
    k_gemm128<<<dim3(cdiv(N_HOSTN,16)), dim3(256), 0, stream>>>(HA, 0, w_h2f2, nullptr, HCbf, 1, N_HOSTN, 128, 0, 0, flagp);
    k_gemm_mfma<<<dim3(cdiv(N_FLOWN, GEMM_MROWS)), dim3(512), 0, stream>>>(F1bf, WBT2, Froot, F2bf, N_FLOWN);
    k_agg_flow<<<dim3(AGGF_BLK), dim3(256), 0, stream>>>(ZALL, rp_cmb, ei_cmb,
                                                         Froot, b_comb2, F1bf, 0);

    // ================= pool + classifier =================
    k_zero<<<GRID1(GG * HH)>>>((float*)poolbits, (size_t)GG * HH);
    k_pool2<<<dim3(cdiv(N_FLOWN, PCHUNK)), dim3(256), 0, stream>>>(F1bf, flow_batch, poolbits);
    k_classifier<<<dim3(GG), dim3(128), 0, stream>>>(poolbits, Wc1, bc1, Wc2, bc2, Wc3, bc3,
                                                     d_out, flagp);
    #undef GRID1
}

// Round 12
// 835.331 us; speedup vs baseline: 1.2921x; 1.0050x over previous
//
#include <hip/hip_runtime.h>
#include <hip/hip_bf16.h>

using bf16 = __hip_bfloat16;

#define N_HOSTN 20000
#define N_FLOWN 200000
#define E_HFN   400000
#define E_RELN  800000
#define E_CMBN  1200000  // rel + h2f combined
#define GG      64
#define HH      128
#define FIN     97
#define NCN     10

// binned CSR build geometry (bins of 256 dsts)
#define NBIN_F  782     // ceil(200000/256)
#define NBIN_H  79      // ceil(20000/256)
#define NBIN_ALL (NBIN_F + NBIN_H)   // 861
#define BH_F    128     // flow-edge hist blocks
#define BH_H    32      // f2h hist blocks
#define EPB_F   9375    // 1200000/128
#define EPB_H   12500   // 400000/32

// persistent-wave aggregation geometry (quarter-per-dst, no LDS staging)
#define AGGF_DPW   12    // dsts per wave (multiple of 4)
#define AGGF_BLK   4167  // 4167 blk * 4 waves * 12 = 200016 >= 200000
#define AGGH_DPW   8
#define AGGH_BLK   625   // 625 * 4 * 8 = 20000

static inline int cdiv(long long a, long long b){ return (int)((a + b - 1) / b); }

__device__ __forceinline__ float bf2f(unsigned short u){
    return __uint_as_float(((unsigned)u) << 16);
}
__device__ __forceinline__ unsigned short f2bf(float f){
    unsigned u = __float_as_uint(f);
    unsigned r = u + 0x7FFFu + ((u >> 16) & 1u);   // RNE
    return (unsigned short)(r >> 16);
}
__device__ __forceinline__ float loadf(const void* p, size_t i, int isbf){
    return isbf ? bf2f(((const unsigned short*)p)[i]) : ((const float*)p)[i];
}
// unpack 8 bf16 (uint4) and accumulate into 8 f32
__device__ __forceinline__ void acc8(float* a, uint4 z){
    a[0] += __uint_as_float(z.x << 16);
    a[1] += __uint_as_float(z.x & 0xFFFF0000u);
    a[2] += __uint_as_float(z.y << 16);
    a[3] += __uint_as_float(z.y & 0xFFFF0000u);
    a[4] += __uint_as_float(z.z << 16);
    a[5] += __uint_as_float(z.z & 0xFFFF0000u);
    a[6] += __uint_as_float(z.w << 16);
    a[7] += __uint_as_float(z.w & 0xFFFF0000u);
}
// unpack 8 bf16 (uint4) and max into 8 f32
__device__ __forceinline__ void max8(float* m, uint4 z){
    m[0] = fmaxf(m[0], __uint_as_float(z.x << 16));
    m[1] = fmaxf(m[1], __uint_as_float(z.x & 0xFFFF0000u));
    m[2] = fmaxf(m[2], __uint_as_float(z.y << 16));
    m[3] = fmaxf(m[3], __uint_as_float(z.y & 0xFFFF0000u));
    m[4] = fmaxf(m[4], __uint_as_float(z.z << 16));
    m[5] = fmaxf(m[5], __uint_as_float(z.z & 0xFFFF0000u));
    m[6] = fmaxf(m[6], __uint_as_float(z.w << 16));
    m[7] = fmaxf(m[7], __uint_as_float(z.w & 0xFFFF0000u));
}
__device__ __forceinline__ unsigned f2ord(float f){
    unsigned u = __float_as_uint(f);
    return (u & 0x80000000u) ? ~u : (u | 0x80000000u);
}

// ---------------- dtype detection ----------------
__global__ void k_detect(const unsigned short* x, int* flag){
    __shared__ int bad;
    if (threadIdx.x == 0) bad = 0;
    __syncthreads();
    int b = 0;
    for (int i = threadIdx.x; i < 4096; i += 256) {
        unsigned e = (x[i] >> 7) & 0xFFu;
        if (e >= 0x90u) b++;
    }
    if (b) atomicAdd(&bad, b);
    __syncthreads();
    if (threadIdx.x == 0) *flag = (bad == 0) ? 1 : 0;   // 1 = bf16, 0 = f32
}

// ---------------- misc ----------------
__global__ void k_zero(float* p, size_t n){
    size_t i = (size_t)blockIdx.x * 256 + threadIdx.x;
    if (i < n) p[i] = 0.f;
}
__global__ void k_flag_us(unsigned short* out, int n, unsigned short val){
    int i = blockIdx.x * 256 + threadIdx.x;
    if (i < n) out[i] = val;
}
__global__ void k_gather_embed(const int* ids, const void* emb, float* out, const int* flagp){
    int i = blockIdx.x * 256 + threadIdx.x;
    if (i >= N_HOSTN * HH) return;
    int isbf = *flagp;
    int node = i >> 7, f = i & 127;
    out[i] = loadf(emb, (size_t)ids[node] * HH + f, isbf);
}
// flow_x [N,97] (flag dtype) -> bf16 padded [N,128]; 8 output cols per thread
__global__ void k_pad_cast(const void* x, unsigned short* o, const int* flagp){
    int i = blockIdx.x * 256 + threadIdx.x;           // 0 .. N_FLOWN*16
    if (i >= N_FLOWN * 16) return;
    int isbf = *flagp;
    int row = i >> 4, c0 = (i & 15) * 8;
    unsigned short v[8];
    #pragma unroll
    for (int j = 0; j < 8; ++j) {
        int c = c0 + j;
        v[j] = (c < FIN) ? f2bf(loadf(x, (size_t)row * FIN + c, isbf)) : (unsigned short)0;
    }
    uint4 ov;
    ov.x = (unsigned)v[0] | ((unsigned)v[1] << 16);
    ov.y = (unsigned)v[2] | ((unsigned)v[3] << 16);
    ov.z = (unsigned)v[4] | ((unsigned)v[5] << 16);
    ov.w = (unsigned)v[6] | ((unsigned)v[7] << 16);
    *(uint4*)(o + (size_t)row * 128 + c0) = ov;
}

// ---------------- one-shot weight prep (833 blocks, region dispatch) ----------------
__global__ __launch_bounds__(256) void k_wprep_all(
    const void* Wr0_h2f, const void* br0_h2f, const void* Wo0_h2f,
    const void* Wr0_f2h, const void* br0_f2h, const void* Wo0_f2h,
    const void* Wr0_rel, const void* br0_rel, const void* Wo0_rel,
    const void* Wr_all, const void* br_all, const void* Wo_all,
    unsigned short* WBT0, unsigned short* WBT1, unsigned short* WBT2,
    float* w_h2f0, float* w_h2f1, float* w_h2f2,
    float* w_f2h0, float* w_f2h1, float* w_of2h0, float* w_of2h1,
    float* b_comb0, float* b_comb1, float* b_comb2, float* b_f2h0, float* b_f2h1,
    const int* flagp)
{
    const int bb = blockIdx.x, t = threadIdx.x;
    const int isbf = *flagp;
    if (bb < 384) {
        int layer = bb >> 7;
        int i = ((bb & 127) << 8) + t;   // 0..32767
        int nn = i >> 7, k = i & 127;
        float v = 0.f;
        if (layer == 0) {
            if (k < FIN) {
                if (nn < 128) v = loadf(Wo0_h2f, (size_t)k*128+nn, isbf) + loadf(Wo0_rel, (size_t)k*128+nn, isbf);
                else          v = loadf(Wr0_rel, (size_t)k*128+(nn-128), isbf);
            }
        } else {
            size_t oW = (size_t)((layer - 1) * 3) * 16384;
            if (nn < 128) v = loadf(Wo_all, oW + (size_t)k*128+nn, isbf)
                            + loadf(Wo_all, oW + 2*16384 + (size_t)k*128+nn, isbf);
            else          v = loadf(Wr_all, oW + 2*16384 + (size_t)k*128+(nn-128), isbf);
        }
        unsigned short* W = (layer == 0) ? WBT0 : ((layer == 1) ? WBT1 : WBT2);
        W[(size_t)nn*128 + k] = f2bf(v);
    } else if (bb < 576) {
        int r = bb - 384; int layer = r >> 6; int i = ((r & 63) << 8) + t;
        float v;
        if (layer == 0) v = loadf(Wr0_h2f, (size_t)i, isbf);
        else            v = loadf(Wr_all, (size_t)((layer-1)*3)*16384 + i, isbf);
        ((layer == 0) ? w_h2f0 : ((layer == 1) ? w_h2f1 : w_h2f2))[i] = v;
    } else if (bb < 640) {
        // w_f2h0 padded to [128][128]: rows k>=97 zero
        int i = ((bb - 576) << 8) + t;
        int k = i >> 7;
        w_f2h0[i] = (k < FIN) ? loadf(Wr0_f2h, (size_t)i, isbf) : 0.f;
    } else if (bb < 704) {
        int i = ((bb - 640) << 8) + t;
        w_f2h1[i] = loadf(Wr_all, (size_t)1*16384 + i, isbf);
    } else if (bb < 768) {
        int i = ((bb - 704) << 8) + t;
        w_of2h0[i] = loadf(Wo0_f2h, (size_t)i, isbf);
    } else if (bb < 832) {
        int i = ((bb - 768) << 8) + t;
        w_of2h1[i] = loadf(Wo_all, (size_t)1*16384 + i, isbf);
    } else {
        if (t < 128) {
            b_comb0[t] = loadf(br0_h2f, t, isbf) + loadf(br0_rel, t, isbf);
            b_comb1[t] = loadf(br_all, 0*128 + t, isbf) + loadf(br_all, 2*128 + t, isbf);
            b_comb2[t] = loadf(br_all, 3*128 + t, isbf) + loadf(br_all, 5*128 + t, isbf);
            b_f2h0[t]  = loadf(br0_f2h, t, isbf);
            b_f2h1[t]  = loadf(br_all, 1*128 + t, isbf);
        }
    }
}

// ============ binned CSR build: NO scattered global atomics ============
//  1) per-block LDS histogram over coarse bins (dst>>8), counts -> [bin][block]
//  2) per-bin scan over blocks + cross-bin scan -> (block,bin) bases
//  3) scatter edges bin-grouped via LDS cursors, packed (src | dstLow<<18)
//  4) one block per bin: LDS 256-hist + scan -> rp (all dsts, coalesced) + ei

// pass 1: per-block coarse-bin counts
__global__ __launch_bounds__(256) void k_binhist(
    const int* __restrict__ rel_dst, const int* __restrict__ h2f_dst,
    const int* __restrict__ f2h_dst, int* __restrict__ cntF, int* __restrict__ cntH)
{
    __shared__ int c[NBIN_F];
    const int t = threadIdx.x, bb = blockIdx.x;
    if (bb < BH_F) {
        for (int i = t; i < NBIN_F; i += 256) c[i] = 0;
        __syncthreads();
        const int e0 = bb * EPB_F;
        for (int i = t; i < EPB_F; i += 256) {
            const int e = e0 + i;
            const int d = (e < E_RELN) ? rel_dst[e] : h2f_dst[e - E_RELN];
            atomicAdd(&c[d >> 8], 1);
        }
        __syncthreads();
        for (int i = t; i < NBIN_F; i += 256) cntF[i * BH_F + bb] = c[i];
    } else {
        const int blk = bb - BH_F;
        for (int i = t; i < NBIN_H; i += 256) c[i] = 0;
        __syncthreads();
        const int e0 = blk * EPB_H;
        for (int i = t; i < EPB_H; i += 256)
            atomicAdd(&c[f2h_dst[e0 + i] >> 8], 1);
        __syncthreads();
        for (int i = t; i < NBIN_H; i += 256) cntH[i * BH_H + blk] = c[i];
    }
}
// pass 2a: per-bin exclusive scan across blocks (in place); bin totals out
__global__ __launch_bounds__(128) void k_binscan1(
    int* __restrict__ cntF, int* __restrict__ cntH,
    int* __restrict__ bintotF, int* __restrict__ bintotH)
{
    __shared__ int s[128];
    const int t = threadIdx.x, b = blockIdx.x;
    int v;
    if (b < NBIN_F) v = (t < BH_F) ? cntF[b * BH_F + t] : 0;
    else            v = (t < BH_H) ? cntH[(b - NBIN_F) * BH_H + t] : 0;
    s[t] = v; __syncthreads();
    for (int off = 1; off < 128; off <<= 1) {
        int x = (t >= off) ? s[t - off] : 0;
        __syncthreads();
        s[t] += x;
        __syncthreads();
    }
    if (b < NBIN_F) {
        if (t < BH_F) cntF[b * BH_F + t] = s[t] - v;
        if (t == 127) bintotF[b] = s[127];
    } else {
        if (t < BH_H) cntH[(b - NBIN_F) * BH_H + t] = s[t] - v;
        if (t == 127) bintotH[b - NBIN_F] = s[127];
    }
}
// pass 2b: exclusive scan across bins (in place: bintot -> binstart)
__global__ __launch_bounds__(256) void k_binscan2(int* aF, int* aH){
    __shared__ int s[256];
    __shared__ int carry;
    int* a; int n;
    if (blockIdx.x == 0) { a = aF; n = NBIN_F; } else { a = aH; n = NBIN_H; }
    const int t = threadIdx.x;
    if (t == 0) carry = 0;
    __syncthreads();
    for (int base = 0; base < n; base += 256) {
        const int i = base + t;
        int v = (i < n) ? a[i] : 0;
        s[t] = v; __syncthreads();
        for (int off = 1; off < 256; off <<= 1) {
            int x = (t >= off) ? s[t - off] : 0;
            __syncthreads();
            s[t] += x;
            __syncthreads();
        }
        int excl = s[t] - v + carry;
        if (i < n) a[i] = excl;
        __syncthreads();
        if (t == 255) carry += s[255];
        __syncthreads();
    }
}
// pass 3: scatter edges into bin-grouped scratch (LDS cursors only)
__global__ __launch_bounds__(256) void k_binscatter(
    const int* __restrict__ rel_src, const int* __restrict__ rel_dst,
    const int* __restrict__ h2f_src, const int* __restrict__ h2f_dst,
    const int* __restrict__ f2h_src, const int* __restrict__ f2h_dst,
    const int* __restrict__ pbF, const int* __restrict__ pbH,
    const int* __restrict__ bsF, const int* __restrict__ bsH,
    unsigned* __restrict__ ebinF, unsigned* __restrict__ ebinH)
{
    __shared__ int base[NBIN_F];
    const int t = threadIdx.x, bb = blockIdx.x;
    if (bb < BH_F) {
        for (int i = t; i < NBIN_F; i += 256) base[i] = bsF[i] + pbF[i * BH_F + bb];
        __syncthreads();
        const int e0 = bb * EPB_F;
        for (int i = t; i < EPB_F; i += 256) {
            const int e = e0 + i;
            int d, sv;
            if (e < E_RELN) { d = rel_dst[e]; sv = rel_src[e]; }
            else            { d = h2f_dst[e - E_RELN]; sv = h2f_src[e - E_RELN] + N_FLOWN; }
            const int pos = atomicAdd(&base[d >> 8], 1);
            ebinF[pos] = (unsigned)sv | ((unsigned)(d & 255) << 18);
        }
    } else {
        const int blk = bb - BH_F;
        for (int i = t; i < NBIN_H; i += 256) base[i] = bsH[i] + pbH[i * BH_H + blk];
        __syncthreads();
        const int e0 = blk * EPB_H;
        for (int i = t; i < EPB_H; i += 256) {
            const int e = e0 + i;
            const int d = f2h_dst[e];
            const int pos = atomicAdd(&base[d >> 8], 1);
            ebinH[pos] = (unsigned)f2h_src[e] | ((unsigned)(d & 255) << 18);
        }
    }
}
// pass 4: per-bin fine CSR (rp for ALL dsts incl. empty; ei scatter in-bin)
__global__ __launch_bounds__(256) void k_bincsr(
    const unsigned* __restrict__ ebinF, const unsigned* __restrict__ ebinH,
    const int* __restrict__ bsF, const int* __restrict__ bsH,
    int* __restrict__ rp_cmb, int* __restrict__ ei_cmb,
    int* __restrict__ rp_f2h, int* __restrict__ ei_f2h)
{
    __shared__ int c[256];
    __shared__ int off[256];
    const int t = threadIdx.x, b = blockIdx.x;
    const unsigned* ebin; int* rp; int* ei; int seg0, seg1, dstbase, ndst;
    if (b < NBIN_F) {
        ebin = ebinF; rp = rp_cmb; ei = ei_cmb;
        seg0 = bsF[b]; seg1 = (b == NBIN_F - 1) ? E_CMBN : bsF[b + 1];
        dstbase = b * 256; ndst = min(256, N_FLOWN - dstbase);
        if (b == 0 && t == 0) rp_cmb[N_FLOWN] = E_CMBN;
    } else {
        const int bh = b - NBIN_F;
        ebin = ebinH; rp = rp_f2h; ei = ei_f2h;
        seg0 = bsH[bh]; seg1 = (bh == NBIN_H - 1) ? E_HFN : bsH[bh + 1];
        dstbase = bh * 256; ndst = min(256, N_HOSTN - dstbase);
        if (bh == 0 && t == 0) rp_f2h[N_HOSTN] = E_HFN;
    }
    c[t] = 0;
    __syncthreads();
    for (int i = seg0 + t; i < seg1; i += 256)
        atomicAdd(&c[ebin[i] >> 18], 1);
    __syncthreads();
    const int v = c[t];
    for (int o = 1; o < 256; o <<= 1) {
        int x = (t >= o) ? c[t - o] : 0;
        __syncthreads();
        c[t] += x;
        __syncthreads();
    }
    const int excl = c[t] - v;
    if (t < ndst) rp[dstbase + t] = seg0 + excl;
    off[t] = seg0 + excl;
    __syncthreads();
    for (int i = seg0 + t; i < seg1; i += 256) {
        const unsigned u = ebin[i];
        const int pos = atomicAdd(&off[u >> 18], 1);
        ei[pos] = (int)(u & 0x3FFFFu);
    }
}

// ---------------- host-sized VALU GEMM: Y[M,128] (+)= X[M,K]@W[K,128]+b ---------
__global__ __launch_bounds__(256) void k_gemm128(
    const void* X, int xmode, const float* W, const float* bias,
    void* Y, int ybf, int M, int K, int accum, int dorelu, const int* flagp)
{
    const int isbf = (xmode == 2) ? *flagp : xmode;
    const int tid  = threadIdx.x;
    const int row0 = blockIdx.x * 16;
    __shared__ float sX[16][132];
    if (!isbf && (K & 3) == 0) {
        // vectorized f32 staging (all current call sites)
        const int kq = K >> 2;
        for (int i = tid; i < 16 * kq; i += 256) {
            int r = i / kq, c4 = (i - r * kq) * 4;
            int gr = row0 + r;
            float4 v = {0.f, 0.f, 0.f, 0.f};
            if (gr < M) v = *(const float4*)((const float*)X + (size_t)gr * K + c4);
            *(float4*)&sX[r][c4] = v;
        }
    } else {
        const int total = 16 * K;
        for (int i = tid; i < total; i += 256) {
            int r = i / K, c = i - r * K;
            int gr = row0 + r;
            sX[r][c] = (gr < M) ? loadf(X, (size_t)gr * K + c, isbf) : 0.f;
        }
    }
    __syncthreads();

    const int c4 = (tid & 31) * 4;
    const int rb = tid >> 5;
    float a0x=0,a0y=0,a0z=0,a0w=0, a1x=0,a1y=0,a1z=0,a1w=0;
    #pragma unroll 4
    for (int k = 0; k < K; ++k) {
        const float4 w = *(const float4*)(W + (size_t)k * 128 + c4);
        const float x0 = sX[rb][k];
        const float x1 = sX[rb + 8][k];
        a0x = fmaf(x0, w.x, a0x); a0y = fmaf(x0, w.y, a0y);
        a0z = fmaf(x0, w.z, a0z); a0w = fmaf(x0, w.w, a0w);
        a1x = fmaf(x1, w.x, a1x); a1y = fmaf(x1, w.y, a1y);
        a1z = fmaf(x1, w.z, a1z); a1w = fmaf(x1, w.w, a1w);
    }
    float bx=0, by=0, bz=0, bw=0;
    if (bias) { const float4 b = *(const float4*)(bias + c4); bx=b.x; by=b.y; bz=b.z; bw=b.w; }

    #pragma unroll
    for (int h = 0; h < 2; ++h) {
        const int rr = row0 + rb + (h ? 8 : 0);
        if (rr >= M) continue;
        float v0 = (h?a1x:a0x)+bx, v1 = (h?a1y:a0y)+by;
        float v2 = (h?a1z:a0z)+bz, v3 = (h?a1w:a0w)+bw;
        if (ybf) {
            unsigned short* p = (unsigned short*)Y + (size_t)rr * 128 + c4;
            ushort4 o; o.x=f2bf(v0); o.y=f2bf(v1); o.z=f2bf(v2); o.w=f2bf(v3);
            *(ushort4*)p = o;
        } else {
            float* p = (float*)Y + (size_t)rr * 128 + c4;
            if (accum) { v0+=p[0]; v1+=p[1]; v2+=p[2]; v3+=p[3]; }
            if (dorelu) { v0=fmaxf(v0,0.f); v1=fmaxf(v1,0.f); v2=fmaxf(v2,0.f); v3=fmaxf(v3,0.f); }
            float4 o; o.x=v0; o.y=v1; o.z=v2; o.w=v3;
            *(float4*)p = o;
        }
    }
}

// ---------------- fused dual-input host GEMM: Y = relu(X1@W1 + X2@W2 + b) ------
__global__ __launch_bounds__(256) void k_gemm2in(
    const float* __restrict__ X1, const float* __restrict__ X2,
    const float* __restrict__ W1, const float* __restrict__ W2,
    const float* __restrict__ bias, float* __restrict__ Y, int M)
{
    const int tid  = threadIdx.x;
    const int row0 = blockIdx.x * 16;
    __shared__ float sX1[16][132];
    __shared__ float sX2[16][132];
    for (int i = tid; i < 16 * 32; i += 256) {
        int r = i >> 5, c4 = (i & 31) * 4;
        int gr = row0 + r;
        float4 v1 = {0.f, 0.f, 0.f, 0.f}, v2 = {0.f, 0.f, 0.f, 0.f};
        if (gr < M) {
            v1 = *(const float4*)(X1 + (size_t)gr * 128 + c4);
            v2 = *(const float4*)(X2 + (size_t)gr * 128 + c4);
        }
        *(float4*)&sX1[r][c4] = v1;
        *(float4*)&sX2[r][c4] = v2;
    }
    __syncthreads();

    const int c4 = (tid & 31) * 4;
    const int rb = tid >> 5;
    float a0x=0,a0y=0,a0z=0,a0w=0, a1x=0,a1y=0,a1z=0,a1w=0;
    #pragma unroll 4
    for (int k = 0; k < 128; ++k) {
        const float4 w = *(const float4*)(W1 + (size_t)k * 128 + c4);
        const float x0 = sX1[rb][k];
        const float x1 = sX1[rb + 8][k];
        a0x = fmaf(x0, w.x, a0x); a0y = fmaf(x0, w.y, a0y);
        a0z = fmaf(x0, w.z, a0z); a0w = fmaf(x0, w.w, a0w);
        a1x = fmaf(x1, w.x, a1x); a1y = fmaf(x1, w.y, a1y);
        a1z = fmaf(x1, w.z, a1z); a1w = fmaf(x1, w.w, a1w);
    }
    #pragma unroll 4
    for (int k = 0; k < 128; ++k) {
        const float4 w = *(const float4*)(W2 + (size_t)k * 128 + c4);
        const float x0 = sX2[rb][k];
        const float x1 = sX2[rb + 8][k];
        a0x = fmaf(x0, w.x, a0x); a0y = fmaf(x0, w.y, a0y);
        a0z = fmaf(x0, w.z, a0z); a0w = fmaf(x0, w.w, a0w);
        a1x = fmaf(x1, w.x, a1x); a1y = fmaf(x1, w.y, a1y);
        a1z = fmaf(x1, w.z, a1z); a1w = fmaf(x1, w.w, a1w);
    }
    const float4 b = *(const float4*)(bias + c4);
    #pragma unroll
    for (int h = 0; h < 2; ++h) {
        const int rr = row0 + rb + (h ? 8 : 0);
        if (rr >= M) continue;
        float4 o;
        o.x = fmaxf((h?a1x:a0x) + b.x, 0.f);
        o.y = fmaxf((h?a1y:a0y) + b.y, 0.f);
        o.z = fmaxf((h?a1z:a0z) + b.z, 0.f);
        o.w = fmaxf((h?a1w:a0w) + b.w, 0.f);
        *(float4*)(Y + (size_t)rr * 128 + c4) = o;
    }
}

// ---------------- MFMA dual flow GEMM: both outputs bf16, no bias ----------------
// All global traffic linearized: A staged once per block into XOR-swizzled LDS
// via linear uint4 loads; output bounced through LDS and stored with linear
// uint4 stores. 8 waves x 32 WBT rows (B = 8 bfrags in regs), LB(512,4).
typedef __attribute__((ext_vector_type(8))) short bfrag;
typedef __attribute__((ext_vector_type(4))) float f32x4;

#define GEMM_CHUNKS 4
#define GEMM_MROWS  (32 * GEMM_CHUNKS)   // 128 rows per block

__global__ __launch_bounds__(512, 4) void k_gemm_mfma(
    const unsigned short* __restrict__ Abf, const unsigned short* __restrict__ WBT,
    unsigned short* __restrict__ Y1, unsigned short* __restrict__ Y2, int M)
{
    __shared__ unsigned short sA[32 * 128];      // 8 KB, XOR-swizzled 16B units
    __shared__ unsigned short sO[2][32][136];    // 17.4 KB out-stage (pad 8 shorts)

    const int tid  = threadIdx.x;
    const int wave = tid >> 6;        // 0..7
    const int lane = tid & 63;
    const int quad = lane >> 4;
    const int l16  = lane & 15;
    const int nbase = wave * 32;      // 32 WBT rows per wave

    // B slice for this wave's 32 output cols: breg[c][j] (8 bfrags = 32 regs)
    bfrag breg[4][2];
    #pragma unroll
    for (int c = 0; c < 4; ++c)
        #pragma unroll
        for (int j = 0; j < 2; ++j)
            breg[c][j] = *(const bfrag*)(WBT + (size_t)(nbase + j * 16 + l16) * 128
                                              + c * 32 + quad * 8);

    const int ybuf = (nbase < 128) ? 0 : 1;
    const int colb = nbase & 127;
    const f32x4 zero = {0.f, 0.f, 0.f, 0.f};

    const int srow = tid >> 4;        // staging row 0..31
    const int su   = tid & 15;        // staging 16B unit 0..15

    for (int chunk = 0; chunk < GEMM_CHUNKS; ++chunk) {
        const int m0 = blockIdx.x * GEMM_MROWS + chunk * 32;
        if (m0 >= M) break;           // block-uniform (M % 32 == 0)

        // ---- stage A chunk (32x128 bf16 = 8KB): linear load, swizzled LDS ----
        {
            const uint4* gsrc = (const uint4*)(Abf + (size_t)m0 * 128);
            uint4* sdst = (uint4*)sA;
            sdst[srow * 16 + (su ^ (srow & 15))] = gsrc[tid];
        }
        __syncthreads();

        // ---- fragments from LDS + MFMA ----
        bfrag a0[4], a1[4];
        #pragma unroll
        for (int c = 0; c < 4; ++c) {
            const int un = (c * 4 + quad) ^ l16;
            a0[c] = *(const bfrag*)(sA + (size_t)(l16)      * 128 + un * 8);
            a1[c] = *(const bfrag*)(sA + (size_t)(16 + l16) * 128 + un * 8);
        }
        f32x4 acc[2][2];
        #pragma unroll
        for (int j = 0; j < 2; ++j) {
            acc[0][j] = __builtin_amdgcn_mfma_f32_16x16x32_bf16(breg[0][j], a0[0], zero, 0, 0, 0);
            acc[1][j] = __builtin_amdgcn_mfma_f32_16x16x32_bf16(breg[0][j], a1[0], zero, 0, 0, 0);
        }
        #pragma unroll
        for (int c = 1; c < 4; ++c)
            #pragma unroll
            for (int j = 0; j < 2; ++j) {
                acc[0][j] = __builtin_amdgcn_mfma_f32_16x16x32_bf16(breg[c][j], a0[c], acc[0][j], 0, 0, 0);
                acc[1][j] = __builtin_amdgcn_mfma_f32_16x16x32_bf16(breg[c][j], a1[c], acc[1][j], 0, 0, 0);
            }

        // ---- stage D' to LDS (D' layout: col(l16)=row m, row(quad*4+r)=col n) ----
        #pragma unroll
        for (int i = 0; i < 2; ++i) {
            const int row = i * 16 + l16;
            #pragma unroll
            for (int j = 0; j < 2; ++j) {
                const int col = colb + j * 16 + quad * 4;
                uint2 o;
                o.x = (unsigned)f2bf(acc[i][j][0]) | ((unsigned)f2bf(acc[i][j][1]) << 16);
                o.y = (unsigned)f2bf(acc[i][j][2]) | ((unsigned)f2bf(acc[i][j][3]) << 16);
                *(uint2*)&sO[ybuf][row][col] = o;
            }
        }
        __syncthreads();

        // ---- linear coalesced stores: 1KB-contiguous per wave instruction ----
        {
            const size_t goff = (size_t)(m0 + srow) * 128 + su * 8;
            *(uint4*)(Y1 + goff) = *(const uint4*)&sO[0][srow][su * 8];
            *(uint4*)(Y2 + goff) = *(const uint4*)&sO[1][srow][su * 8];
        }
        __syncthreads();
    }
}

// ---------------- persistent-wave combined CSR aggregation (flow dsts) ----------
// v12: NO LDS index staging (R11: occupancy 44%, neither pipe saturated). ei is
// L2-resident (4.8 MB); 16-lane-uniform reads broadcast from L1. Removing the
// staging prologue + barrier + per-read Wcap selects lifts the occupancy cap to
// the VGPR limit (8 waves/SIMD) and starts gathers immediately. DPW 24->12
// (4167 blocks) for finer scheduling granularity / shorter tails.
// QUARTER-PER-DST: each 16-lane quarter owns one dst (16 lanes x 8 feats = 128).
__global__ __launch_bounds__(256) void k_agg_flow(
    const unsigned short* __restrict__ Z,
    const int* __restrict__ rp, const int* __restrict__ ei,
    const unsigned short* __restrict__ root, const float* __restrict__ bias,
    unsigned short* __restrict__ Xout, int do_relu)
{
    const int wave = threadIdx.x >> 6;
    const int lane = threadIdx.x & 63;
    const int q    = lane >> 4;
    const int l16  = lane & 15;
    const int f8   = l16 * 8;
    const int gw   = blockIdx.x * 4 + wave;
    const int d0   = gw * AGGF_DPW;
    const int nd   = min(AGGF_DPW, N_FLOWN - d0);
    if (nd <= 0) return;

    const int rpv = (lane <= nd) ? rp[d0 + lane] : 0;

    // loop-invariant bias slice
    const float4 bva = *(const float4*)(bias + f8);
    const float4 bvb = *(const float4*)(bias + f8 + 4);

    for (int i = 0; i < AGGF_DPW / 4; ++i) {
        const int dqi = i * 4 + q;              // this quarter's dst offset
        const bool act = dqi < nd;
        const int srcl = act ? dqi : 0;
        const int b0 = __shfl(rpv, srcl, 64);
        const int b1 = __shfl(rpv, srcl + 1, 64);
        const int d  = d0 + dqi;

        uint4 rv = {0, 0, 0, 0};
        if (act) rv = *(const uint4*)(root + (size_t)d * 128 + f8);

        float a[8] = {0.f, 0.f, 0.f, 0.f, 0.f, 0.f, 0.f, 0.f};
        int n = act ? (b1 - b0) : 0;
        int e = b0;
        while (n >= 4) {
            const int s0 = ei[e];
            const int s1 = ei[e + 1];
            const int s2 = ei[e + 2];
            const int s3 = ei[e + 3];
            const uint4 z0 = *(const uint4*)(Z + (size_t)s0 * 128 + f8);
            const uint4 z1 = *(const uint4*)(Z + (size_t)s1 * 128 + f8);
            const uint4 z2 = *(const uint4*)(Z + (size_t)s2 * 128 + f8);
            const uint4 z3 = *(const uint4*)(Z + (size_t)s3 * 128 + f8);
            acc8(a, z0); acc8(a, z1); acc8(a, z2); acc8(a, z3);
            e += 4; n -= 4;
        }
        if (n & 2) {
            const int s0 = ei[e];
            const int s1 = ei[e + 1];
            const uint4 z0 = *(const uint4*)(Z + (size_t)s0 * 128 + f8);
            const uint4 z1 = *(const uint4*)(Z + (size_t)s1 * 128 + f8);
            acc8(a, z0); acc8(a, z1);
            e += 2;
        }
        if (n & 1) {
            const int s0 = ei[e];
            const uint4 z0 = *(const uint4*)(Z + (size_t)s0 * 128 + f8);
            acc8(a, z0);
        }

        if (act) {
            float v0 = a[0] + __uint_as_float(rv.x << 16)         + bva.x;
            float v1 = a[1] + __uint_as_float(rv.x & 0xFFFF0000u) + bva.y;
            float v2 = a[2] + __uint_as_float(rv.y << 16)         + bva.z;
            float v3 = a[3] + __uint_as_float(rv.y & 0xFFFF0000u) + bva.w;
            float v4 = a[4] + __uint_as_float(rv.z << 16)         + bvb.x;
            float v5 = a[5] + __uint_as_float(rv.z & 0xFFFF0000u) + bvb.y;
            float v6 = a[6] + __uint_as_float(rv.w << 16)         + bvb.z;
            float v7 = a[7] + __uint_as_float(rv.w & 0xFFFF0000u) + bvb.w;
            if (do_relu) {
                v0 = fmaxf(v0, 0.f); v1 = fmaxf(v1, 0.f); v2 = fmaxf(v2, 0.f); v3 = fmaxf(v3, 0.f);
                v4 = fmaxf(v4, 0.f); v5 = fmaxf(v5, 0.f); v6 = fmaxf(v6, 0.f); v7 = fmaxf(v7, 0.f);
            }
            uint4 o;
            o.x = (unsigned)f2bf(v0) | ((unsigned)f2bf(v1) << 16);
            o.y = (unsigned)f2bf(v2) | ((unsigned)f2bf(v3) << 16);
            o.z = (unsigned)f2bf(v4) | ((unsigned)f2bf(v5) << 16);
            o.w = (unsigned)f2bf(v6) | ((unsigned)f2bf(v7) << 16);
            *(uint4*)(Xout + (size_t)d * 128 + f8) = o;
        }
    }
}

// host dst: out[d][0:128] = sum f2h Z[src][0:128]  (f32 out)
// Same no-staging quarter-per-dst structure, DPW=8.
__global__ __launch_bounds__(256) void k_agg_host(
    const unsigned short* __restrict__ Z, const int* __restrict__ rp,
    const int* __restrict__ ei, float* __restrict__ out)
{
    const int wave = threadIdx.x >> 6;
    const int lane = threadIdx.x & 63;
    const int q    = lane >> 4;
    const int l16  = lane & 15;
    const int f8   = l16 * 8;
    const int gw   = blockIdx.x * 4 + wave;
    const int d0   = gw * AGGH_DPW;
    const int nd   = min(AGGH_DPW, N_HOSTN - d0);
    if (nd <= 0) return;

    const int rpv = (lane <= nd) ? rp[d0 + lane] : 0;

    for (int i = 0; i < AGGH_DPW / 4; ++i) {
        const int dqi = i * 4 + q;
        const bool act = dqi < nd;
        const int srcl = act ? dqi : 0;
        const int b0 = __shfl(rpv, srcl, 64);
        const int b1 = __shfl(rpv, srcl + 1, 64);
        const int d  = d0 + dqi;

        float a[8] = {0.f, 0.f, 0.f, 0.f, 0.f, 0.f, 0.f, 0.f};
        int n = act ? (b1 - b0) : 0;
        int e = b0;
        while (n >= 4) {
            const int s0 = ei[e];
            const int s1 = ei[e + 1];
            const int s2 = ei[e + 2];
            const int s3 = ei[e + 3];
            const uint4 z0 = *(const uint4*)(Z + (size_t)s0 * 128 + f8);
            const uint4 z1 = *(const uint4*)(Z + (size_t)s1 * 128 + f8);
            const uint4 z2 = *(const uint4*)(Z + (size_t)s2 * 128 + f8);
            const uint4 z3 = *(const uint4*)(Z + (size_t)s3 * 128 + f8);
            acc8(a, z0); acc8(a, z1); acc8(a, z2); acc8(a, z3);
            e += 4; n -= 4;
        }
        if (n & 2) {
            const int s0 = ei[e];
            const int s1 = ei[e + 1];
            const uint4 z0 = *(const uint4*)(Z + (size_t)s0 * 128 + f8);
            const uint4 z1 = *(const uint4*)(Z + (size_t)s1 * 128 + f8);
            acc8(a, z0); acc8(a, z1);
            e += 2;
        }
        if (n & 1) {
            const int s0 = ei[e];
            const uint4 z0 = *(const uint4*)(Z + (size_t)s0 * 128 + f8);
            acc8(a, z0);
        }

        if (act) {
            float4 oa, ob;
            oa.x = a[0]; oa.y = a[1]; oa.z = a[2]; oa.w = a[3];
            ob.x = a[4]; ob.y = a[5]; ob.z = a[6]; ob.w = a[7];
            *(float4*)(out + (size_t)d * 128 + f8)     = oa;
            *(float4*)(out + (size_t)d * 128 + f8 + 4) = ob;
        }
    }
}

// ---------------- pooling over sorted batch (bf16 input) ----------------
// 256 thr/block, thread = (row-slot, 8 cols), uint4 loads, 8 rows/thread.
// Fast path (block in one batch group): LDS atomicMax combine + 128 coalesced
// global atomicMax. Slow path (group boundary): per-slot walk with flushes.
#define PCHUNK 128
__global__ __launch_bounds__(256) void k_pool2(const unsigned short* __restrict__ xf,
                                               const int* __restrict__ batch,
                                               unsigned* __restrict__ bits){
    const int t  = threadIdx.x;
    const int i0 = blockIdx.x * PCHUNK;
    if (i0 >= N_FLOWN) return;
    const int nrows = min(PCHUNK, N_FLOWN - i0);
    const int slot = t >> 4;           // 16 slots of 8 contiguous rows
    const int c0   = (t & 15) * 8;     // 8 columns per thread
    const int r0   = i0 + slot * 8;
    const int rend = i0 + nrows;

    const int gfirst = batch[i0];
    const int glast  = batch[rend - 1];

    if (gfirst == glast) {
        // ---- fast path: whole chunk in one group ----
        __shared__ unsigned smb[128];
        if (t < 128) smb[t] = 0u;
        __syncthreads();
        float m[8];
        #pragma unroll
        for (int k = 0; k < 8; ++k) m[k] = -3.4e38f;
        #pragma unroll
        for (int j = 0; j < 8; ++j) {
            const int r = r0 + j;
            if (r < rend) {
                const uint4 z = *(const uint4*)(xf + (size_t)r * 128 + c0);
                max8(m, z);
            }
        }
        #pragma unroll
        for (int k = 0; k < 8; ++k) atomicMax(&smb[c0 + k], f2ord(m[k]));
        __syncthreads();
        if (t < 128) {
            const unsigned v = smb[t];
            if (v) atomicMax(&bits[(size_t)gfirst * 128 + t], v);
        }
    } else {
        // ---- slow path: group boundary inside chunk (rare) ----
        float m[8];
        #pragma unroll
        for (int k = 0; k < 8; ++k) m[k] = -3.4e38f;
        int curg = (r0 < rend) ? batch[r0] : -1;
        for (int j = 0; j < 8; ++j) {
            const int r = r0 + j;
            if (r >= rend) break;
            const int g = batch[r];
            if (g != curg) {
                #pragma unroll
                for (int k = 0; k < 8; ++k) {
                    atomicMax(&bits[(size_t)curg * 128 + c0 + k], f2ord(m[k]));
                    m[k] = -3.4e38f;
                }
                curg = g;
            }
            const uint4 z = *(const uint4*)(xf + (size_t)r * 128 + c0);
            max8(m, z);
        }
        if (curg >= 0) {
            #pragma unroll
            for (int k = 0; k < 8; ++k)
                atomicMax(&bits[(size_t)curg * 128 + c0 + k], f2ord(m[k]));
        }
    }
}

// ---------------- classifier ----------------
__global__ __launch_bounds__(128) void k_classifier(
    const unsigned* bits,
    const void* Wc1, const void* bc1, const void* Wc2, const void* bc2,
    const void* Wc3, const void* bc3, void* out, const int* flagp)
{
    const int g = blockIdx.x, t = threadIdx.x;
    const int isbf = *flagp;
    __shared__ float sp[128], sh1[64], sh2[128];
    {
        unsigned ord = bits[(size_t)g * HH + t];
        unsigned u = (ord & 0x80000000u) ? (ord & 0x7FFFFFFFu) : ~ord;
        sp[t] = __uint_as_float(u);
    }
    __syncthreads();
    if (t < 64) {
        float a = loadf(bc1, t, isbf);
        #pragma unroll 4
        for (int k = 0; k < 128; ++k) a = fmaf(sp[k], loadf(Wc1, k * 64 + t, isbf), a);
        sh1[t] = fmaxf(a, 0.f);
    }
    __syncthreads();
    {
        float a = loadf(bc2, t, isbf);
        #pragma unroll 4
        for (int k = 0; k < 64; ++k) a = fmaf(sh1[k], loadf(Wc2, k * 128 + t, isbf), a);
        sh2[t] = fmaxf(a, 0.f);
    }
    __syncthreads();
    if (t < NCN) {
        float a = loadf(bc3, t, isbf);
        #pragma unroll 4
        for (int k = 0; k < 128; ++k) a = fmaf(sh2[k], loadf(Wc3, k * NCN + t, isbf), a);
        if (isbf) ((unsigned short*)out)[(size_t)g * NCN + t] = f2bf(a);
        else      ((float*)out)[(size_t)g * NCN + t] = a;
    }
}

extern "C" void kernel_launch(void* const* d_in, const int* in_sizes, int n_in,
                              void* d_out, int out_size, void* d_ws, size_t ws_size,
                              hipStream_t stream)
{
    const int*  host_ids   = (const int*) d_in[0];
    const void* flow_x     = d_in[1];
    const int*  h2f_src    = (const int*) d_in[2];
    const int*  h2f_dst    = (const int*) d_in[3];
    const int*  f2h_src    = (const int*) d_in[4];
    const int*  f2h_dst    = (const int*) d_in[5];
    const int*  rel_src    = (const int*) d_in[6];
    const int*  rel_dst    = (const int*) d_in[7];
    const int*  flow_batch = (const int*) d_in[8];
    const void* host_embed = d_in[9];
    const void* Wr0_h2f = d_in[10]; const void* br0_h2f = d_in[11]; const void* Wo0_h2f = d_in[12];
    const void* Wr0_f2h = d_in[13]; const void* br0_f2h = d_in[14]; const void* Wo0_f2h = d_in[15];
    const void* Wr0_rel = d_in[16]; const void* br0_rel = d_in[17]; const void* Wo0_rel = d_in[18];
    const void* Wr_all  = d_in[19];
    const void* br_all  = d_in[20];
    const void* Wo_all  = d_in[21];
    const void* Wc1 = d_in[22]; const void* bc1 = d_in[23];
    const void* Wc2 = d_in[24]; const void* bc2 = d_in[25];
    const void* Wc3 = d_in[26]; const void* bc3 = d_in[27];

    // -------- workspace (~198 MB; CSR scratch aliased onto HA/HB) --------
    size_t off = 0;
    auto alloc = [&](size_t bytes) -> char* {
        char* p = (char*)d_ws + off;
        off += (bytes + 255) & ~(size_t)255;
        return p;
    };
    unsigned short* F1bf  = (unsigned short*)alloc((size_t)N_FLOWN * HH * 2);  // state
    unsigned short* Froot = (unsigned short*)alloc((size_t)N_FLOWN * HH * 2);  // root term
    // ZALL: flow-transformed rows [0,200k) followed by host-transformed rows [200k,220k)
    unsigned short* ZALL  = (unsigned short*)alloc((size_t)(N_FLOWN + N_HOSTN) * HH * 2);
    unsigned short* F2bf  = ZALL;                                   // z_rel
    unsigned short* HCbf  = ZALL + (size_t)N_FLOWN * HH;            // z_h
    float* HA = (float*)alloc((size_t)N_HOSTN * HH * 4);
    float* HB = (float*)alloc((size_t)N_HOSTN * HH * 4);
    float* HD = (float*)alloc((size_t)N_HOSTN * HH * 4);
    unsigned short* WBT0 = (unsigned short*)alloc(256 * 128 * 2);
    unsigned short* WBT1 = (unsigned short*)alloc(256 * 128 * 2);
    unsigned short* WBT2 = (unsigned short*)alloc(256 * 128 * 2);
    float* w_h2f0  = (float*)alloc(128 * 128 * 4);
    float* w_h2f1  = (float*)alloc(128 * 128 * 4);
    float* w_h2f2  = (float*)alloc(128 * 128 * 4);
    float* w_f2h0  = (float*)alloc(128 * 128 * 4);
    float* w_f2h1  = (float*)alloc(128 * 128 * 4);
    float* w_of2h0 = (float*)alloc(128 * 128 * 4);
    float* w_of2h1 = (float*)alloc(128 * 128 * 4);
    float* b_comb0 = (float*)alloc(128 * 4);
    float* b_comb1 = (float*)alloc(128 * 4);
    float* b_comb2 = (float*)alloc(128 * 4);
    float* b_f2h0  = (float*)alloc(128 * 4);
    float* b_f2h1  = (float*)alloc(128 * 4);
    unsigned* poolbits = (unsigned*)alloc(GG * HH * 4);
    int* flagp = (int*)alloc(256);
    int* rp_cmb = (int*)alloc((N_FLOWN + 1) * 4);
    int* ei_cmb = (int*)alloc((size_t)E_CMBN * 4);
    int* rp_f2h = (int*)alloc((N_HOSTN + 1) * 4);
    int* ei_f2h = (int*)alloc((size_t)E_HFN * 4);
    // CSR-build scratch aliased onto buffers first written AFTER the build
    // (stream-ordered): ebin arrays (6.4 MB) live in HA (10.24 MB, first write =
    // k_gather_embed); count/prefix matrices (~412 KB) live in HB (first write =
    // k_gemm2in).
    unsigned* ebinF = (unsigned*)HA;          // E_CMBN uints = 4.8 MB
    unsigned* ebinH = ebinF + E_CMBN;         // E_HFN uints = 1.6 MB (total 6.4)
    int* cntF    = (int*)HB;                  // NBIN_F*BH_F = 100096 ints
    int* cntH    = cntF + NBIN_F * BH_F;      // NBIN_H*BH_H = 2528 ints
    int* bintotF = cntH + NBIN_H * BH_H;      // NBIN_F ints
    int* bintotH = bintotF + NBIN_F;          // NBIN_H ints

    const int T = 256;
    #define GRID1(n) dim3(cdiv((long long)(n), T)), dim3(T), 0, stream

    if (off > ws_size) {
        k_flag_us<<<GRID1(out_size)>>>((unsigned short*)d_out, out_size, (unsigned short)0x4000);
        return;
    }

    k_detect<<<dim3(1), dim3(256), 0, stream>>>((const unsigned short*)flow_x, flagp);

    // -------- binned CSR build (no scattered global atomics) --------
    k_binhist   <<<dim3(BH_F + BH_H), dim3(256), 0, stream>>>(rel_dst, h2f_dst, f2h_dst, cntF, cntH);
    k_binscan1  <<<dim3(NBIN_ALL), dim3(128), 0, stream>>>(cntF, cntH, bintotF, bintotH);
    k_binscan2  <<<dim3(2), dim3(256), 0, stream>>>(bintotF, bintotH);   // -> binstarts
    k_binscatter<<<dim3(BH_F + BH_H), dim3(256), 0, stream>>>(
        rel_src, rel_dst, h2f_src, h2f_dst, f2h_src, f2h_dst,
        cntF, cntH, bintotF, bintotH, ebinF, ebinH);
    k_bincsr    <<<dim3(NBIN_ALL), dim3(256), 0, stream>>>(
        ebinF, ebinH, bintotF, bintotH, rp_cmb, ei_cmb, rp_f2h, ei_f2h);

    // -------- weight prep (1 launch) --------
    k_wprep_all<<<dim3(833), dim3(256), 0, stream>>>(
        Wr0_h2f, br0_h2f, Wo0_h2f, Wr0_f2h, br0_f2h, Wo0_f2h, Wr0_rel, br0_rel, Wo0_rel,
        Wr_all, br_all, Wo_all,
        WBT0, WBT1, WBT2, w_h2f0, w_h2f1, w_h2f2,
        w_f2h0, w_f2h1, w_of2h0, w_of2h1,
        b_comb0, b_comb1, b_comb2, b_f2h0, b_f2h1, flagp);

    // ================= layer 0 =================
    k_gather_embed<<<GRID1(N_HOSTN * HH)>>>(host_ids, host_embed, HA, flagp);
    k_pad_cast<<<GRID1(N_FLOWN * 16)>>>(flow_x, F1bf, flagp);
    // host path: gather bf16 input features (K padded to 128); fused dual GEMM + relu
    k_agg_host<<<dim3(AGGH_BLK), dim3(256), 0, stream>>>(F1bf, rp_f2h, ei_f2h, HD);
    k_gemm2in<<<dim3(cdiv(N_HOSTN,16)), dim3(256), 0, stream>>>(HD, HA, w_f2h0, w_of2h0, b_f2h0, HB, N_HOSTN);
    // flow path
    k_gemm128<<<dim3(cdiv(N_HOSTN,16)), dim3(256), 0, stream>>>(HA, 0, w_h2f0, nullptr, HCbf, 1, N_HOSTN, 128, 0, 0, flagp);
    k_gemm_mfma<<<dim3(cdiv(N_FLOWN, GEMM_MROWS)), dim3(512), 0, stream>>>(F1bf, WBT0, Froot, F2bf, N_FLOWN);
    k_agg_flow<<<dim3(AGGF_BLK), dim3(256), 0, stream>>>(ZALL, rp_cmb, ei_cmb,
                                                         Froot, b_comb0, F1bf, 1);

    // ================= stacked layer 0 =================
    k_agg_host<<<dim3(AGGH_BLK), dim3(256), 0, stream>>>(F1bf, rp_f2h, ei_f2h, HD);
    k_gemm128<<<dim3(cdiv(N_HOSTN,16)), dim3(256), 0, stream>>>(HB, 0, w_h2f1, nullptr, HCbf, 1, N_HOSTN, 128, 0, 0, flagp);
    k_gemm_mfma<<<dim3(cdiv(N_FLOWN, GEMM_MROWS)), dim3(512), 0, stream>>>(F1bf, WBT1, Froot, F2bf, N_FLOWN);
    k_agg_flow<<<dim3(AGGF_BLK), dim3(256), 0, stream>>>(ZALL, rp_cmb, ei_cmb,
                                                         Froot, b_comb1, F1bf, 1);
    k_gemm2in<<<dim3(cdiv(N_HOSTN,16)), dim3(256), 0, stream>>>(HD, HB, w_f2h1, w_of2h1, b_f2h1, HA, N_HOSTN);

    // ================= stacked layer 1 (last; no host update, no relu) =================
    k_gemm128<<<dim3(cdiv(N_HOSTN,16)), dim3(256), 0, stream>>>(HA, 0, w_h2f2, nullptr, HCbf, 1, N_HOSTN, 128, 0, 0, flagp);
    k_gemm_mfma<<<dim3(cdiv(N_FLOWN, GEMM_MROWS)), dim3(512), 0, stream>>>(F1bf, WBT2, Froot, F2bf, N_FLOWN);
    k_agg_flow<<<dim3(AGGF_BLK), dim3(256), 0, stream>>>(ZALL, rp_cmb, ei_cmb,
                                                         Froot, b_comb2, F1bf, 0);

    // ================= pool + classifier =================
    k_zero<<<GRID1(GG * HH)>>>((float*)poolbits, (size_t)GG * HH);
    k_pool2<<<dim3(cdiv(N_FLOWN, PCHUNK)), dim3(256), 0, stream>>>(F1bf, flow_batch, poolbits);
    k_classifier<<<dim3(GG), dim3(128), 0, stream>>>(poolbits, Wc1, bc1, Wc2, bc2, Wc3, bc3,
                                                     d_out, flagp);
    #undef GRID1
}

// Round 13
// 831.549 us; speedup vs baseline: 1.2980x; 1.0045x over previous
//
#include <hip/hip_runtime.h>
#include <hip/hip_bf16.h>

using bf16 = __hip_bfloat16;

#define N_HOSTN 20000
#define N_FLOWN 200000
#define E_HFN   400000
#define E_RELN  800000
#define E_CMBN  1200000  // rel + h2f combined
#define GG      64
#define HH      128
#define FIN     97
#define NCN     10

// binned CSR build geometry (bins of 256 dsts)
#define NBIN_F  782     // ceil(200000/256)
#define NBIN_H  79      // ceil(20000/256)
#define NBIN_ALL (NBIN_F + NBIN_H)   // 861
#define BH_F    128     // flow-edge hist blocks
#define BH_H    32      // f2h hist blocks
#define EPB_F   9375    // 1200000/128
#define EPB_H   12500   // 400000/32

// persistent-wave aggregation geometry (quarter-per-dst, no LDS staging)
#define AGGF_DPW   12    // dsts per wave (multiple of 4)
#define AGGF_BLK   4167  // 4167 blk * 4 waves * 12 = 200016 >= 200000
#define AGGH_DPW   8
#define AGGH_BLK   625   // 625 * 4 * 8 = 20000

// pad_cast geometry: 32 rows/block; 32*97 bf16 = 6208 B (16B-aligned window)
#define PCB_BLK 6250     // 6250 * 32 = 200000

static inline int cdiv(long long a, long long b){ return (int)((a + b - 1) / b); }

__device__ __forceinline__ float bf2f(unsigned short u){
    return __uint_as_float(((unsigned)u) << 16);
}
__device__ __forceinline__ unsigned short f2bf(float f){
    unsigned u = __float_as_uint(f);
    unsigned r = u + 0x7FFFu + ((u >> 16) & 1u);   // RNE
    return (unsigned short)(r >> 16);
}
__device__ __forceinline__ float loadf(const void* p, size_t i, int isbf){
    return isbf ? bf2f(((const unsigned short*)p)[i]) : ((const float*)p)[i];
}
// unpack 8 bf16 (uint4) and accumulate into 8 f32
__device__ __forceinline__ void acc8(float* a, uint4 z){
    a[0] += __uint_as_float(z.x << 16);
    a[1] += __uint_as_float(z.x & 0xFFFF0000u);
    a[2] += __uint_as_float(z.y << 16);
    a[3] += __uint_as_float(z.y & 0xFFFF0000u);
    a[4] += __uint_as_float(z.z << 16);
    a[5] += __uint_as_float(z.z & 0xFFFF0000u);
    a[6] += __uint_as_float(z.w << 16);
    a[7] += __uint_as_float(z.w & 0xFFFF0000u);
}
// unpack 8 bf16 (uint4) and max into 8 f32
__device__ __forceinline__ void max8(float* m, uint4 z){
    m[0] = fmaxf(m[0], __uint_as_float(z.x << 16));
    m[1] = fmaxf(m[1], __uint_as_float(z.x & 0xFFFF0000u));
    m[2] = fmaxf(m[2], __uint_as_float(z.y << 16));
    m[3] = fmaxf(m[3], __uint_as_float(z.y & 0xFFFF0000u));
    m[4] = fmaxf(m[4], __uint_as_float(z.z << 16));
    m[5] = fmaxf(m[5], __uint_as_float(z.z & 0xFFFF0000u));
    m[6] = fmaxf(m[6], __uint_as_float(z.w << 16));
    m[7] = fmaxf(m[7], __uint_as_float(z.w & 0xFFFF0000u));
}
__device__ __forceinline__ unsigned f2ord(float f){
    unsigned u = __float_as_uint(f);
    return (u & 0x80000000u) ? ~u : (u | 0x80000000u);
}

// ---------------- dtype detection ----------------
__global__ void k_detect(const unsigned short* x, int* flag){
    __shared__ int bad;
    if (threadIdx.x == 0) bad = 0;
    __syncthreads();
    int b = 0;
    for (int i = threadIdx.x; i < 4096; i += 256) {
        unsigned e = (x[i] >> 7) & 0xFFu;
        if (e >= 0x90u) b++;
    }
    if (b) atomicAdd(&bad, b);
    __syncthreads();
    if (threadIdx.x == 0) *flag = (bad == 0) ? 1 : 0;   // 1 = bf16, 0 = f32
}

// ---------------- misc ----------------
__global__ void k_zero(float* p, size_t n){
    size_t i = (size_t)blockIdx.x * 256 + threadIdx.x;
    if (i < n) p[i] = 0.f;
}
__global__ void k_flag_us(unsigned short* out, int n, unsigned short val){
    int i = blockIdx.x * 256 + threadIdx.x;
    if (i < n) out[i] = val;
}
// vectorized embed gather: thread = (node, 8 cols); uint4/float4 row reads
__global__ __launch_bounds__(256) void k_gather_embed(
    const int* __restrict__ ids, const void* __restrict__ emb,
    float* __restrict__ out, const int* __restrict__ flagp)
{
    int i = blockIdx.x * 256 + threadIdx.x;
    if (i >= N_HOSTN * 16) return;
    const int isbf = *flagp;
    const int node = i >> 4, c0 = (i & 15) * 8;
    const int id = ids[node];
    float4 oa, ob;
    if (isbf) {
        const uint4 z = *(const uint4*)((const unsigned short*)emb + (size_t)id * 128 + c0);
        oa.x = bf2f((unsigned short)(z.x & 0xFFFFu)); oa.y = bf2f((unsigned short)(z.x >> 16));
        oa.z = bf2f((unsigned short)(z.y & 0xFFFFu)); oa.w = bf2f((unsigned short)(z.y >> 16));
        ob.x = bf2f((unsigned short)(z.z & 0xFFFFu)); ob.y = bf2f((unsigned short)(z.z >> 16));
        ob.z = bf2f((unsigned short)(z.w & 0xFFFFu)); ob.w = bf2f((unsigned short)(z.w >> 16));
    } else {
        oa = *(const float4*)((const float*)emb + (size_t)id * 128 + c0);
        ob = *(const float4*)((const float*)emb + (size_t)id * 128 + c0 + 4);
    }
    *(float4*)(out + (size_t)node * 128 + c0)     = oa;
    *(float4*)(out + (size_t)node * 128 + c0 + 4) = ob;
}
// flow_x [N,97] -> bf16 padded [N,128].
// v13: R12 showed 60us @ 18% HBM -- issue-bound on 25.6M scalar 2B loads (odd
// row stride 97 defeats vectorization). bf16 case is a PURE REPACK (bf2f o f2bf
// = identity): 32-row window = 6208 B = 388 uint4, 16B-aligned for every block
// -> linear coalesced uint4 loads into LDS, repack from LDS shorts, coalesced
// uint4 stores. f32 input keeps scalar fallback.
__global__ __launch_bounds__(256) void k_pad_cast(const void* __restrict__ x,
                                                  unsigned short* __restrict__ o,
                                                  const int* __restrict__ flagp)
{
    const int t = threadIdx.x, b = blockIdx.x;    // PCB_BLK blocks, 32 rows each
    const int isbf = *flagp;
    if (isbf) {
        __shared__ unsigned short sb[32 * 97 + 8];
        {
            const uint4* src = (const uint4*)x + (size_t)b * 388;
            uint4* sdst = (uint4*)sb;
            sdst[t] = src[t];                      // t < 256
            if (t < 132) sdst[256 + t] = src[256 + t];
        }
        __syncthreads();
        #pragma unroll
        for (int p = 0; p < 2; ++p) {
            const int idx = p * 256 + t;           // 0..511
            const int row = idx >> 4, u = idx & 15;
            const int base = row * 97 + u * 8;
            unsigned short v[8];
            #pragma unroll
            for (int j = 0; j < 8; ++j)
                v[j] = (u * 8 + j < FIN) ? sb[base + j] : (unsigned short)0;
            uint4 ov;
            ov.x = (unsigned)v[0] | ((unsigned)v[1] << 16);
            ov.y = (unsigned)v[2] | ((unsigned)v[3] << 16);
            ov.z = (unsigned)v[4] | ((unsigned)v[5] << 16);
            ov.w = (unsigned)v[6] | ((unsigned)v[7] << 16);
            *(uint4*)(o + (size_t)(b * 32 + row) * 128 + u * 8) = ov;
        }
    } else {
        #pragma unroll
        for (int p = 0; p < 2; ++p) {
            const int idx = p * 256 + t;
            const int row = b * 32 + (idx >> 4), c0 = (idx & 15) * 8;
            unsigned short v[8];
            #pragma unroll
            for (int j = 0; j < 8; ++j) {
                const int c = c0 + j;
                v[j] = (c < FIN) ? f2bf(((const float*)x)[(size_t)row * FIN + c])
                                 : (unsigned short)0;
            }
            uint4 ov;
            ov.x = (unsigned)v[0] | ((unsigned)v[1] << 16);
            ov.y = (unsigned)v[2] | ((unsigned)v[3] << 16);
            ov.z = (unsigned)v[4] | ((unsigned)v[5] << 16);
            ov.w = (unsigned)v[6] | ((unsigned)v[7] << 16);
            *(uint4*)(o + (size_t)row * 128 + c0) = ov;
        }
    }
}

// ---------------- one-shot weight prep (833 blocks, region dispatch) ----------------
__global__ __launch_bounds__(256) void k_wprep_all(
    const void* Wr0_h2f, const void* br0_h2f, const void* Wo0_h2f,
    const void* Wr0_f2h, const void* br0_f2h, const void* Wo0_f2h,
    const void* Wr0_rel, const void* br0_rel, const void* Wo0_rel,
    const void* Wr_all, const void* br_all, const void* Wo_all,
    unsigned short* WBT0, unsigned short* WBT1, unsigned short* WBT2,
    float* w_h2f0, float* w_h2f1, float* w_h2f2,
    float* w_f2h0, float* w_f2h1, float* w_of2h0, float* w_of2h1,
    float* b_comb0, float* b_comb1, float* b_comb2, float* b_f2h0, float* b_f2h1,
    const int* flagp)
{
    const int bb = blockIdx.x, t = threadIdx.x;
    const int isbf = *flagp;
    if (bb < 384) {
        int layer = bb >> 7;
        int i = ((bb & 127) << 8) + t;   // 0..32767
        int nn = i >> 7, k = i & 127;
        float v = 0.f;
        if (layer == 0) {
            if (k < FIN) {
                if (nn < 128) v = loadf(Wo0_h2f, (size_t)k*128+nn, isbf) + loadf(Wo0_rel, (size_t)k*128+nn, isbf);
                else          v = loadf(Wr0_rel, (size_t)k*128+(nn-128), isbf);
            }
        } else {
            size_t oW = (size_t)((layer - 1) * 3) * 16384;
            if (nn < 128) v = loadf(Wo_all, oW + (size_t)k*128+nn, isbf)
                            + loadf(Wo_all, oW + 2*16384 + (size_t)k*128+nn, isbf);
            else          v = loadf(Wr_all, oW + 2*16384 + (size_t)k*128+(nn-128), isbf);
        }
        unsigned short* W = (layer == 0) ? WBT0 : ((layer == 1) ? WBT1 : WBT2);
        W[(size_t)nn*128 + k] = f2bf(v);
    } else if (bb < 576) {
        int r = bb - 384; int layer = r >> 6; int i = ((r & 63) << 8) + t;
        float v;
        if (layer == 0) v = loadf(Wr0_h2f, (size_t)i, isbf);
        else            v = loadf(Wr_all, (size_t)((layer-1)*3)*16384 + i, isbf);
        ((layer == 0) ? w_h2f0 : ((layer == 1) ? w_h2f1 : w_h2f2))[i] = v;
    } else if (bb < 640) {
        // w_f2h0 padded to [128][128]: rows k>=97 zero
        int i = ((bb - 576) << 8) + t;
        int k = i >> 7;
        w_f2h0[i] = (k < FIN) ? loadf(Wr0_f2h, (size_t)i, isbf) : 0.f;
    } else if (bb < 704) {
        int i = ((bb - 640) << 8) + t;
        w_f2h1[i] = loadf(Wr_all, (size_t)1*16384 + i, isbf);
    } else if (bb < 768) {
        int i = ((bb - 704) << 8) + t;
        w_of2h0[i] = loadf(Wo0_f2h, (size_t)i, isbf);
    } else if (bb < 832) {
        int i = ((bb - 768) << 8) + t;
        w_of2h1[i] = loadf(Wo_all, (size_t)1*16384 + i, isbf);
    } else {
        if (t < 128) {
            b_comb0[t] = loadf(br0_h2f, t, isbf) + loadf(br0_rel, t, isbf);
            b_comb1[t] = loadf(br_all, 0*128 + t, isbf) + loadf(br_all, 2*128 + t, isbf);
            b_comb2[t] = loadf(br_all, 3*128 + t, isbf) + loadf(br_all, 5*128 + t, isbf);
            b_f2h0[t]  = loadf(br0_f2h, t, isbf);
            b_f2h1[t]  = loadf(br_all, 1*128 + t, isbf);
        }
    }
}

// ============ binned CSR build: NO scattered global atomics ============
//  1) per-block LDS histogram over coarse bins (dst>>8), counts -> [bin][block]
//  2) per-bin scan over blocks + cross-bin scan -> (block,bin) bases
//  3) scatter edges bin-grouped via LDS cursors, packed (src | dstLow<<18)
//  4) one block per bin: LDS 256-hist + scan -> rp (all dsts, coalesced) + ei

// pass 1: per-block coarse-bin counts
__global__ __launch_bounds__(256) void k_binhist(
    const int* __restrict__ rel_dst, const int* __restrict__ h2f_dst,
    const int* __restrict__ f2h_dst, int* __restrict__ cntF, int* __restrict__ cntH)
{
    __shared__ int c[NBIN_F];
    const int t = threadIdx.x, bb = blockIdx.x;
    if (bb < BH_F) {
        for (int i = t; i < NBIN_F; i += 256) c[i] = 0;
        __syncthreads();
        const int e0 = bb * EPB_F;
        for (int i = t; i < EPB_F; i += 256) {
            const int e = e0 + i;
            const int d = (e < E_RELN) ? rel_dst[e] : h2f_dst[e - E_RELN];
            atomicAdd(&c[d >> 8], 1);
        }
        __syncthreads();
        for (int i = t; i < NBIN_F; i += 256) cntF[i * BH_F + bb] = c[i];
    } else {
        const int blk = bb - BH_F;
        for (int i = t; i < NBIN_H; i += 256) c[i] = 0;
        __syncthreads();
        const int e0 = blk * EPB_H;
        for (int i = t; i < EPB_H; i += 256)
            atomicAdd(&c[f2h_dst[e0 + i] >> 8], 1);
        __syncthreads();
        for (int i = t; i < NBIN_H; i += 256) cntH[i * BH_H + blk] = c[i];
    }
}
// pass 2a: per-bin exclusive scan across blocks (in place); bin totals out
__global__ __launch_bounds__(128) void k_binscan1(
    int* __restrict__ cntF, int* __restrict__ cntH,
    int* __restrict__ bintotF, int* __restrict__ bintotH)
{
    __shared__ int s[128];
    const int t = threadIdx.x, b = blockIdx.x;
    int v;
    if (b < NBIN_F) v = (t < BH_F) ? cntF[b * BH_F + t] : 0;
    else            v = (t < BH_H) ? cntH[(b - NBIN_F) * BH_H + t] : 0;
    s[t] = v; __syncthreads();
    for (int off = 1; off < 128; off <<= 1) {
        int x = (t >= off) ? s[t - off] : 0;
        __syncthreads();
        s[t] += x;
        __syncthreads();
    }
    if (b < NBIN_F) {
        if (t < BH_F) cntF[b * BH_F + t] = s[t] - v;
        if (t == 127) bintotF[b] = s[127];
    } else {
        if (t < BH_H) cntH[(b - NBIN_F) * BH_H + t] = s[t] - v;
        if (t == 127) bintotH[b - NBIN_F] = s[127];
    }
}
// pass 2b: exclusive scan across bins (in place: bintot -> binstart)
__global__ __launch_bounds__(256) void k_binscan2(int* aF, int* aH){
    __shared__ int s[256];
    __shared__ int carry;
    int* a; int n;
    if (blockIdx.x == 0) { a = aF; n = NBIN_F; } else { a = aH; n = NBIN_H; }
    const int t = threadIdx.x;
    if (t == 0) carry = 0;
    __syncthreads();
    for (int base = 0; base < n; base += 256) {
        const int i = base + t;
        int v = (i < n) ? a[i] : 0;
        s[t] = v; __syncthreads();
        for (int off = 1; off < 256; off <<= 1) {
            int x = (t >= off) ? s[t - off] : 0;
            __syncthreads();
            s[t] += x;
            __syncthreads();
        }
        int excl = s[t] - v + carry;
        if (i < n) a[i] = excl;
        __syncthreads();
        if (t == 255) carry += s[255];
        __syncthreads();
    }
}
// pass 3: scatter edges into bin-grouped scratch (LDS cursors only)
__global__ __launch_bounds__(256) void k_binscatter(
    const int* __restrict__ rel_src, const int* __restrict__ rel_dst,
    const int* __restrict__ h2f_src, const int* __restrict__ h2f_dst,
    const int* __restrict__ f2h_src, const int* __restrict__ f2h_dst,
    const int* __restrict__ pbF, const int* __restrict__ pbH,
    const int* __restrict__ bsF, const int* __restrict__ bsH,
    unsigned* __restrict__ ebinF, unsigned* __restrict__ ebinH)
{
    __shared__ int base[NBIN_F];
    const int t = threadIdx.x, bb = blockIdx.x;
    if (bb < BH_F) {
        for (int i = t; i < NBIN_F; i += 256) base[i] = bsF[i] + pbF[i * BH_F + bb];
        __syncthreads();
        const int e0 = bb * EPB_F;
        for (int i = t; i < EPB_F; i += 256) {
            const int e = e0 + i;
            int d, sv;
            if (e < E_RELN) { d = rel_dst[e]; sv = rel_src[e]; }
            else            { d = h2f_dst[e - E_RELN]; sv = h2f_src[e - E_RELN] + N_FLOWN; }
            const int pos = atomicAdd(&base[d >> 8], 1);
            ebinF[pos] = (unsigned)sv | ((unsigned)(d & 255) << 18);
        }
    } else {
        const int blk = bb - BH_F;
        for (int i = t; i < NBIN_H; i += 256) base[i] = bsH[i] + pbH[i * BH_H + blk];
        __syncthreads();
        const int e0 = blk * EPB_H;
        for (int i = t; i < EPB_H; i += 256) {
            const int e = e0 + i;
            const int d = f2h_dst[e];
            const int pos = atomicAdd(&base[d >> 8], 1);
            ebinH[pos] = (unsigned)f2h_src[e] | ((unsigned)(d & 255) << 18);
        }
    }
}
// pass 4: per-bin fine CSR (rp for ALL dsts incl. empty; ei scatter in-bin)
__global__ __launch_bounds__(256) void k_bincsr(
    const unsigned* __restrict__ ebinF, const unsigned* __restrict__ ebinH,
    const int* __restrict__ bsF, const int* __restrict__ bsH,
    int* __restrict__ rp_cmb, int* __restrict__ ei_cmb,
    int* __restrict__ rp_f2h, int* __restrict__ ei_f2h)
{
    __shared__ int c[256];
    __shared__ int off[256];
    const int t = threadIdx.x, b = blockIdx.x;
    const unsigned* ebin; int* rp; int* ei; int seg0, seg1, dstbase, ndst;
    if (b < NBIN_F) {
        ebin = ebinF; rp = rp_cmb; ei = ei_cmb;
        seg0 = bsF[b]; seg1 = (b == NBIN_F - 1) ? E_CMBN : bsF[b + 1];
        dstbase = b * 256; ndst = min(256, N_FLOWN - dstbase);
        if (b == 0 && t == 0) rp_cmb[N_FLOWN] = E_CMBN;
    } else {
        const int bh = b - NBIN_F;
        ebin = ebinH; rp = rp_f2h; ei = ei_f2h;
        seg0 = bsH[bh]; seg1 = (bh == NBIN_H - 1) ? E_HFN : bsH[bh + 1];
        dstbase = bh * 256; ndst = min(256, N_HOSTN - dstbase);
        if (bh == 0 && t == 0) rp_f2h[N_HOSTN] = E_HFN;
    }
    c[t] = 0;
    __syncthreads();
    for (int i = seg0 + t; i < seg1; i += 256)
        atomicAdd(&c[ebin[i] >> 18], 1);
    __syncthreads();
    const int v = c[t];
    for (int o = 1; o < 256; o <<= 1) {
        int x = (t >= o) ? c[t - o] : 0;
        __syncthreads();
        c[t] += x;
        __syncthreads();
    }
    const int excl = c[t] - v;
    if (t < ndst) rp[dstbase + t] = seg0 + excl;
    off[t] = seg0 + excl;
    __syncthreads();
    for (int i = seg0 + t; i < seg1; i += 256) {
        const unsigned u = ebin[i];
        const int pos = atomicAdd(&off[u >> 18], 1);
        ei[pos] = (int)(u & 0x3FFFFu);
    }
}

// ---------------- host-sized VALU GEMM: Y[M,128] (+)= X[M,K]@W[K,128]+b ---------
__global__ __launch_bounds__(256) void k_gemm128(
    const void* X, int xmode, const float* W, const float* bias,
    void* Y, int ybf, int M, int K, int accum, int dorelu, const int* flagp)
{
    const int isbf = (xmode == 2) ? *flagp : xmode;
    const int tid  = threadIdx.x;
    const int row0 = blockIdx.x * 16;
    __shared__ float sX[16][132];
    if (!isbf && (K & 3) == 0) {
        // vectorized f32 staging (all current call sites)
        const int kq = K >> 2;
        for (int i = tid; i < 16 * kq; i += 256) {
            int r = i / kq, c4 = (i - r * kq) * 4;
            int gr = row0 + r;
            float4 v = {0.f, 0.f, 0.f, 0.f};
            if (gr < M) v = *(const float4*)((const float*)X + (size_t)gr * K + c4);
            *(float4*)&sX[r][c4] = v;
        }
    } else {
        const int total = 16 * K;
        for (int i = tid; i < total; i += 256) {
            int r = i / K, c = i - r * K;
            int gr = row0 + r;
            sX[r][c] = (gr < M) ? loadf(X, (size_t)gr * K + c, isbf) : 0.f;
        }
    }
    __syncthreads();

    const int c4 = (tid & 31) * 4;
    const int rb = tid >> 5;
    float a0x=0,a0y=0,a0z=0,a0w=0, a1x=0,a1y=0,a1z=0,a1w=0;
    #pragma unroll 4
    for (int k = 0; k < K; ++k) {
        const float4 w = *(const float4*)(W + (size_t)k * 128 + c4);
        const float x0 = sX[rb][k];
        const float x1 = sX[rb + 8][k];
        a0x = fmaf(x0, w.x, a0x); a0y = fmaf(x0, w.y, a0y);
        a0z = fmaf(x0, w.z, a0z); a0w = fmaf(x0, w.w, a0w);
        a1x = fmaf(x1, w.x, a1x); a1y = fmaf(x1, w.y, a1y);
        a1z = fmaf(x1, w.z, a1z); a1w = fmaf(x1, w.w, a1w);
    }
    float bx=0, by=0, bz=0, bw=0;
    if (bias) { const float4 b = *(const float4*)(bias + c4); bx=b.x; by=b.y; bz=b.z; bw=b.w; }

    #pragma unroll
    for (int h = 0; h < 2; ++h) {
        const int rr = row0 + rb + (h ? 8 : 0);
        if (rr >= M) continue;
        float v0 = (h?a1x:a0x)+bx, v1 = (h?a1y:a0y)+by;
        float v2 = (h?a1z:a0z)+bz, v3 = (h?a1w:a0w)+bw;
        if (ybf) {
            unsigned short* p = (unsigned short*)Y + (size_t)rr * 128 + c4;
            ushort4 o; o.x=f2bf(v0); o.y=f2bf(v1); o.z=f2bf(v2); o.w=f2bf(v3);
            *(ushort4*)p = o;
        } else {
            float* p = (float*)Y + (size_t)rr * 128 + c4;
            if (accum) { v0+=p[0]; v1+=p[1]; v2+=p[2]; v3+=p[3]; }
            if (dorelu) { v0=fmaxf(v0,0.f); v1=fmaxf(v1,0.f); v2=fmaxf(v2,0.f); v3=fmaxf(v3,0.f); }
            float4 o; o.x=v0; o.y=v1; o.z=v2; o.w=v3;
            *(float4*)p = o;
        }
    }
}

// ---------------- fused dual-input host GEMM: Y = relu(X1@W1 + X2@W2 + b) ------
__global__ __launch_bounds__(256) void k_gemm2in(
    const float* __restrict__ X1, const float* __restrict__ X2,
    const float* __restrict__ W1, const float* __restrict__ W2,
    const float* __restrict__ bias, float* __restrict__ Y, int M)
{
    const int tid  = threadIdx.x;
    const int row0 = blockIdx.x * 16;
    __shared__ float sX1[16][132];
    __shared__ float sX2[16][132];
    for (int i = tid; i < 16 * 32; i += 256) {
        int r = i >> 5, c4 = (i & 31) * 4;
        int gr = row0 + r;
        float4 v1 = {0.f, 0.f, 0.f, 0.f}, v2 = {0.f, 0.f, 0.f, 0.f};
        if (gr < M) {
            v1 = *(const float4*)(X1 + (size_t)gr * 128 + c4);
            v2 = *(const float4*)(X2 + (size_t)gr * 128 + c4);
        }
        *(float4*)&sX1[r][c4] = v1;
        *(float4*)&sX2[r][c4] = v2;
    }
    __syncthreads();

    const int c4 = (tid & 31) * 4;
    const int rb = tid >> 5;
    float a0x=0,a0y=0,a0z=0,a0w=0, a1x=0,a1y=0,a1z=0,a1w=0;
    #pragma unroll 4
    for (int k = 0; k < 128; ++k) {
        const float4 w = *(const float4*)(W1 + (size_t)k * 128 + c4);
        const float x0 = sX1[rb][k];
        const float x1 = sX1[rb + 8][k];
        a0x = fmaf(x0, w.x, a0x); a0y = fmaf(x0, w.y, a0y);
        a0z = fmaf(x0, w.z, a0z); a0w = fmaf(x0, w.w, a0w);
        a1x = fmaf(x1, w.x, a1x); a1y = fmaf(x1, w.y, a1y);
        a1z = fmaf(x1, w.z, a1z); a1w = fmaf(x1, w.w, a1w);
    }
    #pragma unroll 4
    for (int k = 0; k < 128; ++k) {
        const float4 w = *(const float4*)(W2 + (size_t)k * 128 + c4);
        const float x0 = sX2[rb][k];
        const float x1 = sX2[rb + 8][k];
        a0x = fmaf(x0, w.x, a0x); a0y = fmaf(x0, w.y, a0y);
        a0z = fmaf(x0, w.z, a0z); a0w = fmaf(x0, w.w, a0w);
        a1x = fmaf(x1, w.x, a1x); a1y = fmaf(x1, w.y, a1y);
        a1z = fmaf(x1, w.z, a1z); a1w = fmaf(x1, w.w, a1w);
    }
    const float4 b = *(const float4*)(bias + c4);
    #pragma unroll
    for (int h = 0; h < 2; ++h) {
        const int rr = row0 + rb + (h ? 8 : 0);
        if (rr >= M) continue;
        float4 o;
        o.x = fmaxf((h?a1x:a0x) + b.x, 0.f);
        o.y = fmaxf((h?a1y:a0y) + b.y, 0.f);
        o.z = fmaxf((h?a1z:a0z) + b.z, 0.f);
        o.w = fmaxf((h?a1w:a0w) + b.w, 0.f);
        *(float4*)(Y + (size_t)rr * 128 + c4) = o;
    }
}

// ---------------- MFMA dual flow GEMM: both outputs bf16, no bias ----------------
// All global traffic linearized: A staged once per block into XOR-swizzled LDS
// via linear uint4 loads; output bounced through LDS and stored with linear
// uint4 stores. 8 waves x 32 WBT rows (B = 8 bfrags in regs), LB(512,4).
typedef __attribute__((ext_vector_type(8))) short bfrag;
typedef __attribute__((ext_vector_type(4))) float f32x4;

#define GEMM_CHUNKS 4
#define GEMM_MROWS  (32 * GEMM_CHUNKS)   // 128 rows per block

__global__ __launch_bounds__(512, 4) void k_gemm_mfma(
    const unsigned short* __restrict__ Abf, const unsigned short* __restrict__ WBT,
    unsigned short* __restrict__ Y1, unsigned short* __restrict__ Y2, int M)
{
    __shared__ unsigned short sA[32 * 128];      // 8 KB, XOR-swizzled 16B units
    __shared__ unsigned short sO[2][32][136];    // 17.4 KB out-stage (pad 8 shorts)

    const int tid  = threadIdx.x;
    const int wave = tid >> 6;        // 0..7
    const int lane = tid & 63;
    const int quad = lane >> 4;
    const int l16  = lane & 15;
    const int nbase = wave * 32;      // 32 WBT rows per wave

    // B slice for this wave's 32 output cols: breg[c][j] (8 bfrags = 32 regs)
    bfrag breg[4][2];
    #pragma unroll
    for (int c = 0; c < 4; ++c)
        #pragma unroll
        for (int j = 0; j < 2; ++j)
            breg[c][j] = *(const bfrag*)(WBT + (size_t)(nbase + j * 16 + l16) * 128
                                              + c * 32 + quad * 8);

    const int ybuf = (nbase < 128) ? 0 : 1;
    const int colb = nbase & 127;
    const f32x4 zero = {0.f, 0.f, 0.f, 0.f};

    const int srow = tid >> 4;        // staging row 0..31
    const int su   = tid & 15;        // staging 16B unit 0..15

    for (int chunk = 0; chunk < GEMM_CHUNKS; ++chunk) {
        const int m0 = blockIdx.x * GEMM_MROWS + chunk * 32;
        if (m0 >= M) break;           // block-uniform (M % 32 == 0)

        // ---- stage A chunk (32x128 bf16 = 8KB): linear load, swizzled LDS ----
        {
            const uint4* gsrc = (const uint4*)(Abf + (size_t)m0 * 128);
            uint4* sdst = (uint4*)sA;
            sdst[srow * 16 + (su ^ (srow & 15))] = gsrc[tid];
        }
        __syncthreads();

        // ---- fragments from LDS + MFMA ----
        bfrag a0[4], a1[4];
        #pragma unroll
        for (int c = 0; c < 4; ++c) {
            const int un = (c * 4 + quad) ^ l16;
            a0[c] = *(const bfrag*)(sA + (size_t)(l16)      * 128 + un * 8);
            a1[c] = *(const bfrag*)(sA + (size_t)(16 + l16) * 128 + un * 8);
        }
        f32x4 acc[2][2];
        #pragma unroll
        for (int j = 0; j < 2; ++j) {
            acc[0][j] = __builtin_amdgcn_mfma_f32_16x16x32_bf16(breg[0][j], a0[0], zero, 0, 0, 0);
            acc[1][j] = __builtin_amdgcn_mfma_f32_16x16x32_bf16(breg[0][j], a1[0], zero, 0, 0, 0);
        }
        #pragma unroll
        for (int c = 1; c < 4; ++c)
            #pragma unroll
            for (int j = 0; j < 2; ++j) {
                acc[0][j] = __builtin_amdgcn_mfma_f32_16x16x32_bf16(breg[c][j], a0[c], acc[0][j], 0, 0, 0);
                acc[1][j] = __builtin_amdgcn_mfma_f32_16x16x32_bf16(breg[c][j], a1[c], acc[1][j], 0, 0, 0);
            }

        // ---- stage D' to LDS (D' layout: col(l16)=row m, row(quad*4+r)=col n) ----
        #pragma unroll
        for (int i = 0; i < 2; ++i) {
            const int row = i * 16 + l16;
            #pragma unroll
            for (int j = 0; j < 2; ++j) {
                const int col = colb + j * 16 + quad * 4;
                uint2 o;
                o.x = (unsigned)f2bf(acc[i][j][0]) | ((unsigned)f2bf(acc[i][j][1]) << 16);
                o.y = (unsigned)f2bf(acc[i][j][2]) | ((unsigned)f2bf(acc[i][j][3]) << 16);
                *(uint2*)&sO[ybuf][row][col] = o;
            }
        }
        __syncthreads();

        // ---- linear coalesced stores: 1KB-contiguous per wave instruction ----
        {
            const size_t goff = (size_t)(m0 + srow) * 128 + su * 8;
            *(uint4*)(Y1 + goff) = *(const uint4*)&sO[0][srow][su * 8];
            *(uint4*)(Y2 + goff) = *(const uint4*)&sO[1][srow][su * 8];
        }
        __syncthreads();
    }
}

// ---------------- persistent-wave combined CSR aggregation (flow dsts) ----------
// No LDS index staging; ei is L2-resident, 16-lane-uniform reads broadcast.
// QUARTER-PER-DST: each 16-lane quarter owns one dst (16 lanes x 8 feats = 128).
__global__ __launch_bounds__(256) void k_agg_flow(
    const unsigned short* __restrict__ Z,
    const int* __restrict__ rp, const int* __restrict__ ei,
    const unsigned short* __restrict__ root, const float* __restrict__ bias,
    unsigned short* __restrict__ Xout, int do_relu)
{
    const int wave = threadIdx.x >> 6;
    const int lane = threadIdx.x & 63;
    const int q    = lane >> 4;
    const int l16  = lane & 15;
    const int f8   = l16 * 8;
    const int gw   = blockIdx.x * 4 + wave;
    const int d0   = gw * AGGF_DPW;
    const int nd   = min(AGGF_DPW, N_FLOWN - d0);
    if (nd <= 0) return;

    const int rpv = (lane <= nd) ? rp[d0 + lane] : 0;

    // loop-invariant bias slice
    const float4 bva = *(const float4*)(bias + f8);
    const float4 bvb = *(const float4*)(bias + f8 + 4);

    for (int i = 0; i < AGGF_DPW / 4; ++i) {
        const int dqi = i * 4 + q;              // this quarter's dst offset
        const bool act = dqi < nd;
        const int srcl = act ? dqi : 0;
        const int b0 = __shfl(rpv, srcl, 64);
        const int b1 = __shfl(rpv, srcl + 1, 64);
        const int d  = d0 + dqi;

        uint4 rv = {0, 0, 0, 0};
        if (act) rv = *(const uint4*)(root + (size_t)d * 128 + f8);

        float a[8] = {0.f, 0.f, 0.f, 0.f, 0.f, 0.f, 0.f, 0.f};
        int n = act ? (b1 - b0) : 0;
        int e = b0;
        while (n >= 4) {
            const int s0 = ei[e];
            const int s1 = ei[e + 1];
            const int s2 = ei[e + 2];
            const int s3 = ei[e + 3];
            const uint4 z0 = *(const uint4*)(Z + (size_t)s0 * 128 + f8);
            const uint4 z1 = *(const uint4*)(Z + (size_t)s1 * 128 + f8);
            const uint4 z2 = *(const uint4*)(Z + (size_t)s2 * 128 + f8);
            const uint4 z3 = *(const uint4*)(Z + (size_t)s3 * 128 + f8);
            acc8(a, z0); acc8(a, z1); acc8(a, z2); acc8(a, z3);
            e += 4; n -= 4;
        }
        if (n & 2) {
            const int s0 = ei[e];
            const int s1 = ei[e + 1];
            const uint4 z0 = *(const uint4*)(Z + (size_t)s0 * 128 + f8);
            const uint4 z1 = *(const uint4*)(Z + (size_t)s1 * 128 + f8);
            acc8(a, z0); acc8(a, z1);
            e += 2;
        }
        if (n & 1) {
            const int s0 = ei[e];
            const uint4 z0 = *(const uint4*)(Z + (size_t)s0 * 128 + f8);
            acc8(a, z0);
        }

        if (act) {
            float v0 = a[0] + __uint_as_float(rv.x << 16)         + bva.x;
            float v1 = a[1] + __uint_as_float(rv.x & 0xFFFF0000u) + bva.y;
            float v2 = a[2] + __uint_as_float(rv.y << 16)         + bva.z;
            float v3 = a[3] + __uint_as_float(rv.y & 0xFFFF0000u) + bva.w;
            float v4 = a[4] + __uint_as_float(rv.z << 16)         + bvb.x;
            float v5 = a[5] + __uint_as_float(rv.z & 0xFFFF0000u) + bvb.y;
            float v6 = a[6] + __uint_as_float(rv.w << 16)         + bvb.z;
            float v7 = a[7] + __uint_as_float(rv.w & 0xFFFF0000u) + bvb.w;
            if (do_relu) {
                v0 = fmaxf(v0, 0.f); v1 = fmaxf(v1, 0.f); v2 = fmaxf(v2, 0.f); v3 = fmaxf(v3, 0.f);
                v4 = fmaxf(v4, 0.f); v5 = fmaxf(v5, 0.f); v6 = fmaxf(v6, 0.f); v7 = fmaxf(v7, 0.f);
            }
            uint4 o;
            o.x = (unsigned)f2bf(v0) | ((unsigned)f2bf(v1) << 16);
            o.y = (unsigned)f2bf(v2) | ((unsigned)f2bf(v3) << 16);
            o.z = (unsigned)f2bf(v4) | ((unsigned)f2bf(v5) << 16);
            o.w = (unsigned)f2bf(v6) | ((unsigned)f2bf(v7) << 16);
            *(uint4*)(Xout + (size_t)d * 128 + f8) = o;
        }
    }
}

// host dst: out[d][0:128] = sum f2h Z[src][0:128]  (f32 out)
// Same no-staging quarter-per-dst structure, DPW=8.
__global__ __launch_bounds__(256) void k_agg_host(
    const unsigned short* __restrict__ Z, const int* __restrict__ rp,
    const int* __restrict__ ei, float* __restrict__ out)
{
    const int wave = threadIdx.x >> 6;
    const int lane = threadIdx.x & 63;
    const int q    = lane >> 4;
    const int l16  = lane & 15;
    const int f8   = l16 * 8;
    const int gw   = blockIdx.x * 4 + wave;
    const int d0   = gw * AGGH_DPW;
    const int nd   = min(AGGH_DPW, N_HOSTN - d0);
    if (nd <= 0) return;

    const int rpv = (lane <= nd) ? rp[d0 + lane] : 0;

    for (int i = 0; i < AGGH_DPW / 4; ++i) {
        const int dqi = i * 4 + q;
        const bool act = dqi < nd;
        const int srcl = act ? dqi : 0;
        const int b0 = __shfl(rpv, srcl, 64);
        const int b1 = __shfl(rpv, srcl + 1, 64);
        const int d  = d0 + dqi;

        float a[8] = {0.f, 0.f, 0.f, 0.f, 0.f, 0.f, 0.f, 0.f};
        int n = act ? (b1 - b0) : 0;
        int e = b0;
        while (n >= 4) {
            const int s0 = ei[e];
            const int s1 = ei[e + 1];
            const int s2 = ei[e + 2];
            const int s3 = ei[e + 3];
            const uint4 z0 = *(const uint4*)(Z + (size_t)s0 * 128 + f8);
            const uint4 z1 = *(const uint4*)(Z + (size_t)s1 * 128 + f8);
            const uint4 z2 = *(const uint4*)(Z + (size_t)s2 * 128 + f8);
            const uint4 z3 = *(const uint4*)(Z + (size_t)s3 * 128 + f8);
            acc8(a, z0); acc8(a, z1); acc8(a, z2); acc8(a, z3);
            e += 4; n -= 4;
        }
        if (n & 2) {
            const int s0 = ei[e];
            const int s1 = ei[e + 1];
            const uint4 z0 = *(const uint4*)(Z + (size_t)s0 * 128 + f8);
            const uint4 z1 = *(const uint4*)(Z + (size_t)s1 * 128 + f8);
            acc8(a, z0); acc8(a, z1);
            e += 2;
        }
        if (n & 1) {
            const int s0 = ei[e];
            const uint4 z0 = *(const uint4*)(Z + (size_t)s0 * 128 + f8);
            acc8(a, z0);
        }

        if (act) {
            float4 oa, ob;
            oa.x = a[0]; oa.y = a[1]; oa.z = a[2]; oa.w = a[3];
            ob.x = a[4]; ob.y = a[5]; ob.z = a[6]; ob.w = a[7];
            *(float4*)(out + (size_t)d * 128 + f8)     = oa;
            *(float4*)(out + (size_t)d * 128 + f8 + 4) = ob;
        }
    }
}

// ---------------- pooling over sorted batch (bf16 input) ----------------
// 256 thr/block, thread = (row-slot, 8 cols), uint4 loads, 8 rows/thread.
// Fast path (block in one batch group): LDS atomicMax combine + 128 coalesced
// global atomicMax. Slow path (group boundary): per-slot walk with flushes.
#define PCHUNK 128
__global__ __launch_bounds__(256) void k_pool2(const unsigned short* __restrict__ xf,
                                               const int* __restrict__ batch,
                                               unsigned* __restrict__ bits){
    const int t  = threadIdx.x;
    const int i0 = blockIdx.x * PCHUNK;
    if (i0 >= N_FLOWN) return;
    const int nrows = min(PCHUNK, N_FLOWN - i0);
    const int slot = t >> 4;           // 16 slots of 8 contiguous rows
    const int c0   = (t & 15) * 8;     // 8 columns per thread
    const int r0   = i0 + slot * 8;
    const int rend = i0 + nrows;

    const int gfirst = batch[i0];
    const int glast  = batch[rend - 1];

    if (gfirst == glast) {
        // ---- fast path: whole chunk in one group ----
        __shared__ unsigned smb[128];
        if (t < 128) smb[t] = 0u;
        __syncthreads();
        float m[8];
        #pragma unroll
        for (int k = 0; k < 8; ++k) m[k] = -3.4e38f;
        #pragma unroll
        for (int j = 0; j < 8; ++j) {
            const int r = r0 + j;
            if (r < rend) {
                const uint4 z = *(const uint4*)(xf + (size_t)r * 128 + c0);
                max8(m, z);
            }
        }
        #pragma unroll
        for (int k = 0; k < 8; ++k) atomicMax(&smb[c0 + k], f2ord(m[k]));
        __syncthreads();
        if (t < 128) {
            const unsigned v = smb[t];
            if (v) atomicMax(&bits[(size_t)gfirst * 128 + t], v);
        }
    } else {
        // ---- slow path: group boundary inside chunk (rare) ----
        float m[8];
        #pragma unroll
        for (int k = 0; k < 8; ++k) m[k] = -3.4e38f;
        int curg = (r0 < rend) ? batch[r0] : -1;
        for (int j = 0; j < 8; ++j) {
            const int r = r0 + j;
            if (r >= rend) break;
            const int g = batch[r];
            if (g != curg) {
                #pragma unroll
                for (int k = 0; k < 8; ++k) {
                    atomicMax(&bits[(size_t)curg * 128 + c0 + k], f2ord(m[k]));
                    m[k] = -3.4e38f;
                }
                curg = g;
            }
            const uint4 z = *(const uint4*)(xf + (size_t)r * 128 + c0);
            max8(m, z);
        }
        if (curg >= 0) {
            #pragma unroll
            for (int k = 0; k < 8; ++k)
                atomicMax(&bits[(size_t)curg * 128 + c0 + k], f2ord(m[k]));
        }
    }
}

// ---------------- classifier ----------------
__global__ __launch_bounds__(128) void k_classifier(
    const unsigned* bits,
    const void* Wc1, const void* bc1, const void* Wc2, const void* bc2,
    const void* Wc3, const void* bc3, void* out, const int* flagp)
{
    const int g = blockIdx.x, t = threadIdx.x;
    const int isbf = *flagp;
    __shared__ float sp[128], sh1[64], sh2[128];
    {
        unsigned ord = bits[(size_t)g * HH + t];
        unsigned u = (ord & 0x80000000u) ? (ord & 0x7FFFFFFFu) : ~ord;
        sp[t] = __uint_as_float(u);
    }
    __syncthreads();
    if (t < 64) {
        float a = loadf(bc1, t, isbf);
        #pragma unroll 4
        for (int k = 0; k < 128; ++k) a = fmaf(sp[k], loadf(Wc1, k * 64 + t, isbf), a);
        sh1[t] = fmaxf(a, 0.f);
    }
    __syncthreads();
    {
        float a = loadf(bc2, t, isbf);
        #pragma unroll 4
        for (int k = 0; k < 64; ++k) a = fmaf(sh1[k], loadf(Wc2, k * 128 + t, isbf), a);
        sh2[t] = fmaxf(a, 0.f);
    }
    __syncthreads();
    if (t < NCN) {
        float a = loadf(bc3, t, isbf);
        #pragma unroll 4
        for (int k = 0; k < 128; ++k) a = fmaf(sh2[k], loadf(Wc3, k * NCN + t, isbf), a);
        if (isbf) ((unsigned short*)out)[(size_t)g * NCN + t] = f2bf(a);
        else      ((float*)out)[(size_t)g * NCN + t] = a;
    }
}

extern "C" void kernel_launch(void* const* d_in, const int* in_sizes, int n_in,
                              void* d_out, int out_size, void* d_ws, size_t ws_size,
                              hipStream_t stream)
{
    const int*  host_ids   = (const int*) d_in[0];
    const void* flow_x     = d_in[1];
    const int*  h2f_src    = (const int*) d_in[2];
    const int*  h2f_dst    = (const int*) d_in[3];
    const int*  f2h_src    = (const int*) d_in[4];
    const int*  f2h_dst    = (const int*) d_in[5];
    const int*  rel_src    = (const int*) d_in[6];
    const int*  rel_dst    = (const int*) d_in[7];
    const int*  flow_batch = (const int*) d_in[8];
    const void* host_embed = d_in[9];
    const void* Wr0_h2f = d_in[10]; const void* br0_h2f = d_in[11]; const void* Wo0_h2f = d_in[12];
    const void* Wr0_f2h = d_in[13]; const void* br0_f2h = d_in[14]; const void* Wo0_f2h = d_in[15];
    const void* Wr0_rel = d_in[16]; const void* br0_rel = d_in[17]; const void* Wo0_rel = d_in[18];
    const void* Wr_all  = d_in[19];
    const void* br_all  = d_in[20];
    const void* Wo_all  = d_in[21];
    const void* Wc1 = d_in[22]; const void* bc1 = d_in[23];
    const void* Wc2 = d_in[24]; const void* bc2 = d_in[25];
    const void* Wc3 = d_in[26]; const void* bc3 = d_in[27];

    // -------- workspace (~198 MB; CSR scratch aliased onto HA/HB) --------
    size_t off = 0;
    auto alloc = [&](size_t bytes) -> char* {
        char* p = (char*)d_ws + off;
        off += (bytes + 255) & ~(size_t)255;
        return p;
    };
    unsigned short* F1bf  = (unsigned short*)alloc((size_t)N_FLOWN * HH * 2);  // state
    unsigned short* Froot = (unsigned short*)alloc((size_t)N_FLOWN * HH * 2);  // root term
    // ZALL: flow-transformed rows [0,200k) followed by host-transformed rows [200k,220k)
    unsigned short* ZALL  = (unsigned short*)alloc((size_t)(N_FLOWN + N_HOSTN) * HH * 2);
    unsigned short* F2bf  = ZALL;                                   // z_rel
    unsigned short* HCbf  = ZALL + (size_t)N_FLOWN * HH;            // z_h
    float* HA = (float*)alloc((size_t)N_HOSTN * HH * 4);
    float* HB = (float*)alloc((size_t)N_HOSTN * HH * 4);
    float* HD = (float*)alloc((size_t)N_HOSTN * HH * 4);
    unsigned short* WBT0 = (unsigned short*)alloc(256 * 128 * 2);
    unsigned short* WBT1 = (unsigned short*)alloc(256 * 128 * 2);
    unsigned short* WBT2 = (unsigned short*)alloc(256 * 128 * 2);
    float* w_h2f0  = (float*)alloc(128 * 128 * 4);
    float* w_h2f1  = (float*)alloc(128 * 128 * 4);
    float* w_h2f2  = (float*)alloc(128 * 128 * 4);
    float* w_f2h0  = (float*)alloc(128 * 128 * 4);
    float* w_f2h1  = (float*)alloc(128 * 128 * 4);
    float* w_of2h0 = (float*)alloc(128 * 128 * 4);
    float* w_of2h1 = (float*)alloc(128 * 128 * 4);
    float* b_comb0 = (float*)alloc(128 * 4);
    float* b_comb1 = (float*)alloc(128 * 4);
    float* b_comb2 = (float*)alloc(128 * 4);
    float* b_f2h0  = (float*)alloc(128 * 4);
    float* b_f2h1  = (float*)alloc(128 * 4);
    unsigned* poolbits = (unsigned*)alloc(GG * HH * 4);
    int* flagp = (int*)alloc(256);
    int* rp_cmb = (int*)alloc((N_FLOWN + 1) * 4);
    int* ei_cmb = (int*)alloc((size_t)E_CMBN * 4);
    int* rp_f2h = (int*)alloc((N_HOSTN + 1) * 4);
    int* ei_f2h = (int*)alloc((size_t)E_HFN * 4);
    // CSR-build scratch aliased onto buffers first written AFTER the build
    // (stream-ordered): ebin arrays (6.4 MB) live in HA (10.24 MB, first write =
    // k_gather_embed); count/prefix matrices (~412 KB) live in HB (first write =
    // k_gemm2in).
    unsigned* ebinF = (unsigned*)HA;          // E_CMBN uints = 4.8 MB
    unsigned* ebinH = ebinF + E_CMBN;         // E_HFN uints = 1.6 MB (total 6.4)
    int* cntF    = (int*)HB;                  // NBIN_F*BH_F = 100096 ints
    int* cntH    = cntF + NBIN_F * BH_F;      // NBIN_H*BH_H = 2528 ints
    int* bintotF = cntH + NBIN_H * BH_H;      // NBIN_F ints
    int* bintotH = bintotF + NBIN_F;          // NBIN_H ints

    const int T = 256;
    #define GRID1(n) dim3(cdiv((long long)(n), T)), dim3(T), 0, stream

    if (off > ws_size) {
        k_flag_us<<<GRID1(out_size)>>>((unsigned short*)d_out, out_size, (unsigned short)0x4000);
        return;
    }

    k_detect<<<dim3(1), dim3(256), 0, stream>>>((const unsigned short*)flow_x, flagp);

    // -------- binned CSR build (no scattered global atomics) --------
    k_binhist   <<<dim3(BH_F + BH_H), dim3(256), 0, stream>>>(rel_dst, h2f_dst, f2h_dst, cntF, cntH);
    k_binscan1  <<<dim3(NBIN_ALL), dim3(128), 0, stream>>>(cntF, cntH, bintotF, bintotH);
    k_binscan2  <<<dim3(2), dim3(256), 0, stream>>>(bintotF, bintotH);   // -> binstarts
    k_binscatter<<<dim3(BH_F + BH_H), dim3(256), 0, stream>>>(
        rel_src, rel_dst, h2f_src, h2f_dst, f2h_src, f2h_dst,
        cntF, cntH, bintotF, bintotH, ebinF, ebinH);
    k_bincsr    <<<dim3(NBIN_ALL), dim3(256), 0, stream>>>(
        ebinF, ebinH, bintotF, bintotH, rp_cmb, ei_cmb, rp_f2h, ei_f2h);

    // -------- weight prep (1 launch) --------
    k_wprep_all<<<dim3(833), dim3(256), 0, stream>>>(
        Wr0_h2f, br0_h2f, Wo0_h2f, Wr0_f2h, br0_f2h, Wo0_f2h, Wr0_rel, br0_rel, Wo0_rel,
        Wr_all, br_all, Wo_all,
        WBT0, WBT1, WBT2, w_h2f0, w_h2f1, w_h2f2,
        w_f2h0, w_f2h1, w_of2h0, w_of2h1,
        b_comb0, b_comb1, b_comb2, b_f2h0, b_f2h1, flagp);

    // ================= layer 0 =================
    k_gather_embed<<<GRID1(N_HOSTN * 16)>>>(host_ids, host_embed, HA, flagp);
    k_pad_cast<<<dim3(PCB_BLK), dim3(256), 0, stream>>>(flow_x, F1bf, flagp);
    // host path: gather bf16 input features (K padded to 128); fused dual GEMM + relu
    k_agg_host<<<dim3(AGGH_BLK), dim3(256), 0, stream>>>(F1bf, rp_f2h, ei_f2h, HD);
    k_gemm2in<<<dim3(cdiv(N_HOSTN,16)), dim3(256), 0, stream>>>(HD, HA, w_f2h0, w_of2h0, b_f2h0, HB, N_HOSTN);
    // flow path
    k_gemm128<<<dim3(cdiv(N_HOSTN,16)), dim3(256), 0, stream>>>(HA, 0, w_h2f0, nullptr, HCbf, 1, N_HOSTN, 128, 0, 0, flagp);
    k_gemm_mfma<<<dim3(cdiv(N_FLOWN, GEMM_MROWS)), dim3(512), 0, stream>>>(F1bf, WBT0, Froot, F2bf, N_FLOWN);
    k_agg_flow<<<dim3(AGGF_BLK), dim3(256), 0, stream>>>(ZALL, rp_cmb, ei_cmb,
                                                         Froot, b_comb0, F1bf, 1);

    // ================= stacked layer 0 =================
    k_agg_host<<<dim3(AGGH_BLK), dim3(256), 0, stream>>>(F1bf, rp_f2h, ei_f2h, HD);
    k_gemm128<<<dim3(cdiv(N_HOSTN,16)), dim3(256), 0, stream>>>(HB, 0, w_h2f1, nullptr, HCbf, 1, N_HOSTN, 128, 0, 0, flagp);
    k_gemm_mfma<<<dim3(cdiv(N_FLOWN, GEMM_MROWS)), dim3(512), 0, stream>>>(F1bf, WBT1, Froot, F2bf, N_FLOWN);
    k_agg_flow<<<dim3(AGGF_BLK), dim3(256), 0, stream>>>(ZALL, rp_cmb, ei_cmb,
                                                         Froot, b_comb1, F1bf, 1);
    k_gemm2in<<<dim3(cdiv(N_HOSTN,16)), dim3(256), 0, stream>>>(HD, HB, w_f2h1, w_of2h1, b_f2h1, HA, N_HOSTN);

    // ================= stacked layer 1 (last; no host update, no relu) =================
    k_gemm128<<<dim3(cdiv(N_HOSTN,16)), dim3(256), 0, stream>>>(HA, 0, w_h2f2, nullptr, HCbf, 1, N_HOSTN, 128, 0, 0, flagp);
    k_gemm_mfma<<<dim3(cdiv(N_FLOWN, GEMM_MROWS)), dim3(512), 0, stream>>>(F1bf, WBT2, Froot, F2bf, N_FLOWN);
    k_agg_flow<<<dim3(AGGF_BLK), dim3(256), 0, stream>>>(ZALL, rp_cmb, ei_cmb,
                                                         Froot, b_comb2, F1bf, 0);

    // ================= pool + classifier =================
    k_zero<<<GRID1(GG * HH)>>>((float*)poolbits, (size_t)GG * HH);
    k_pool2<<<dim3(cdiv(N_FLOWN, PCHUNK)), dim3(256), 0, stream>>>(F1bf, flow_batch, poolbits);
    k_classifier<<<dim3(GG), dim3(128), 0, stream>>>(poolbits, Wc1, bc1, Wc2, bc2, Wc3, bc3,
                                                     d_out, flagp);
    #undef GRID1
}